// Round 10
// baseline (497.567 us; speedup 1.0000x reference)
//
#include <hip/hip_runtime.h>
#include <math.h>

#define NELEM 8388608   // B*T*D*H*W = 2*16*64*64*64
#define HW    4096
#define DCH   64
#define TT    16
#define EPS   1e-5f

typedef __attribute__((ext_vector_type(8))) short bfrag;   // 8 bf16 = 4 VGPRs
typedef __attribute__((ext_vector_type(16))) float accv;   // 16 fp32 acc

__device__ __forceinline__ unsigned short f2b(float f) {
  union { float f; unsigned u; } v; v.f = f;
  unsigned r = (v.u + 0x7FFF + ((v.u >> 16) & 1)) >> 16;
  return (unsigned short)r;
}
__device__ __forceinline__ float b2f(unsigned short h) {
  union { unsigned u; float f; } v; v.u = ((unsigned)h) << 16;
  return v.f;
}
// base-4 digit reversal of a 6-bit index (3 digits)
__device__ __forceinline__ int rev4(int x) {
  return ((x & 3) << 4) | (x & 12) | ((x >> 4) & 3);
}
// XCD-locality swizzle: put consecutive logical tiles on the SAME XCD
// (dispatch is round-robin bid%8 -> XCD). NB must be divisible by 8.
__device__ __forceinline__ int xcd_swizzle(int bid, int nb) {
  return (bid & 7) * (nb >> 3) + (bid >> 3);
}

__device__ __forceinline__ float2 c_add(float2 a, float2 b) {
  return make_float2(a.x + b.x, a.y + b.y);
}
__device__ __forceinline__ float2 c_sub(float2 a, float2 b) {
  return make_float2(a.x - b.x, a.y - b.y);
}
// a * (w.x - i w.y)   [forward twiddle]
__device__ __forceinline__ float2 c_mul_conj(float2 a, float2 w) {
  return make_float2(a.x * w.x + a.y * w.y, a.y * w.x - a.x * w.y);
}
// a * (w.x + i w.y)   [inverse twiddle]
__device__ __forceinline__ float2 c_mul_pos(float2 a, float2 w) {
  return make_float2(a.x * w.x - a.y * w.y, a.y * w.x + a.x * w.y);
}
__device__ __forceinline__ float2 shfl_xor2(float2 v, int m) {
  return make_float2(__shfl_xor(v.x, m), __shfl_xor(v.y, m));
}
// tanh-form GELU: x*sigmoid(1.5958(x+0.044715x^3)); |err vs erf-gelu| < 1e-3,
// below bf16 rounding of the downstream f2b.
__device__ __forceinline__ float gelu_f(float v) {
  float y = -1.595769122f * (v + 0.044715f * v * v * v);
  return v * __builtin_amdgcn_rcpf(1.f + __expf(y));
}

// -------- Kernel W: weight prep -> MFMA-fragment order -----
// Wf[tap][half][ks][cb][t2][lane=lhi*32+l31][j]: the conv wave's A-fragment
// load becomes lane-consecutive 16 B (one coalesced 1 KB burst).
__global__ __launch_bounds__(256) void k_wprep(
    const float* __restrict__ cwr, const float* __restrict__ cwi,
    unsigned short* __restrict__ Wt) {
  int gid = blockIdx.x * 256 + threadIdx.x;
  if (gid >= 9 * 128 * 128) return;
  int j = gid & 7;
  int lane = (gid >> 3) & 63;
  int t2 = (gid >> 9) & 1;
  int cb = (gid >> 10) & 1;
  int ks = (gid >> 11) & 3;
  int half = (gid >> 13) & 1;
  int tap = gid >> 14;
  int l31 = lane & 31, lhi = lane >> 5;
  int co = cb * 64 + t2 * 32 + l31;
  int c = half * 64 + ks * 16 + lhi * 8 + j;
  int kh = tap / 3, kw = tap - kh * 3;
  int dout = co & 63, cin = c & 63;
  int widx = ((dout * 64 + cin) * 3 + kh) * 3 + kw;
  float v;
  if (co < 64) v = (c < 64) ? cwr[widx] : -cwi[widx];
  else         v = (c < 64) ? cwi[widx] :  cwr[widx];
  Wt[gid] = f2b(v);
}

// ------- Kernel V: temporal GEMM weights, MFMA-B layout [kg=16][n=128][8] --
__global__ __launch_bounds__(256) void k_vprep(
    const float* __restrict__ Vre, const float* __restrict__ Vim,
    const float* __restrict__ Vire, const float* __restrict__ Viim,
    unsigned short* __restrict__ Wt1, unsigned short* __restrict__ Wt2) {
  int gid = blockIdx.x * 256 + threadIdx.x;   // 0..16383
  int j = gid & 7, n = (gid >> 3) & 127, kg = gid >> 10;
  int k = kg * 8 + j;
  int d = k & 63, dp = n & 63;
  float v1, v2;
  if (k < 64) {
    v1 = (n < 64) ? Vire[dp * 64 + d] : Viim[dp * 64 + d];
    v2 = (n < 64) ? Vre[dp * 64 + d] : Vim[dp * 64 + d];
  } else {
    v1 = (n < 64) ? -Viim[dp * 64 + d] : Vire[dp * 64 + d];
    v2 = (n < 64) ? -Vim[dp * 64 + d] : Vre[dp * 64 + d];
  }
  Wt1[gid] = f2b(v1); Wt2[gid] = f2b(v2);
}

// ------- Kernel M: MLP weight prep -> Wm1[2h][16kg][128n][8], Wm2 same -----
__global__ __launch_bounds__(256) void k_mprep(
    const float* __restrict__ w1, const float* __restrict__ w2,
    unsigned short* __restrict__ Wm) {
  int gid = blockIdx.x * 256 + threadIdx.x;  // 0..65535
  int j = gid & 7, n = (gid >> 3) & 127, kgh = (gid >> 10) & 31;
  int hh = kgh >> 4, kg = kgh & 15;
  float v;
  if (gid < 32768) v = w1[(kg * 8 + j) * 256 + hh * 128 + n];
  else             v = w2[(hh * 128 + kg * 8 + j) * 128 + n];
  Wm[gid] = f2b(v);
}

// ------- Kernel S: spectral weight pre-gather into fft consumption order ---
// Ps[((ch*4 + p)*16 + j)*64 + cy] = (swr,swi)[ch*4096 + fr(j,kap(p))*64 +
// rev4(cy)]. Turns the fft's 64 scattered 4-B gathers/thread into 16 loads
// in 128-B lane-contiguous segments.
__global__ __launch_bounds__(256) void k_sprep(
    const float* __restrict__ swr, const float* __restrict__ swi,
    float2* __restrict__ Ps) {
  int gid = blockIdx.x * 256 + threadIdx.x;   // 0..262143
  int cy = gid & 63, j = (gid >> 6) & 15, p = (gid >> 10) & 3, ch = gid >> 12;
  int kap = ((p & 1) << 1) | (p >> 1);
  int fr = ((j & 3) << 4) | (((j >> 2) & 3) << 2) | kap;
  int addr = ch * 4096 + fr * 64 + rev4(cy);
  Ps[gid] = make_float2(swr[addr], swi[addr]);
}

// ---------------- Kernel A: spatial LN -> Xb[n][hw][c=128] bf16 ------------
__global__ __launch_bounds__(256) void k_ln_spatial(
    const float* __restrict__ xr, const float* __restrict__ xi,
    const float* __restrict__ w, const float* __restrict__ b,
    unsigned short* __restrict__ Xb) {
  int gid = blockIdx.x * 256 + threadIdx.x;   // 0..131071 = BT*HW
  int bt = gid >> 12;
  int hw = gid & 4095;
  size_t base = (size_t)bt * DCH * HW + hw;
  float vr[DCH], vi[DCH];
  float s = 0.f, s2 = 0.f;
#pragma unroll
  for (int d = 0; d < DCH; ++d) {
    float a = xr[base + d * HW];
    float c = xi[base + d * HW];
    vr[d] = a; vi[d] = c;
    s += a + c;
    s2 += a * a + c * c;
  }
  float mu = s * (1.f / 128.f);
  float var = s2 * (1.f / 128.f) - mu * mu;
  float rs = rsqrtf(var + EPS);
  unsigned short* dst = Xb + ((size_t)gid << 7);
#pragma unroll
  for (int k = 0; k < 8; ++k) {
    int4 o;
    unsigned short* op = (unsigned short*)&o;
#pragma unroll
    for (int j = 0; j < 8; ++j) {
      int d = k * 8 + j;
      op[j] = f2b((vr[d] - mu) * rs * w[d] + b[d]);
    }
    ((int4*)dst)[k] = o;
  }
#pragma unroll
  for (int k = 0; k < 8; ++k) {
    int4 o;
    unsigned short* op = (unsigned short*)&o;
#pragma unroll
    for (int j = 0; j < 8; ++j) {
      int d = k * 8 + j;
      op[j] = f2b((vi[d] - mu) * rs * w[64 + d] + b[64 + d]);
    }
    ((int4*)(dst + 64))[k] = o;
  }
}

// ------- Kernel X: transpose ln-out to channel-major for the FFT -----------
__global__ __launch_bounds__(256) void k_xpose(
    const unsigned short* __restrict__ Xb,   // [n][hw][c=128]
    unsigned short* __restrict__ Xc) {
  int bid = xcd_swizzle(blockIdx.x, 1024);   // same-n blocks share an XCD
  int n = bid >> 5, chp = bid & 31;          // channels chp*2, chp*2+1
  int tid = threadIdx.x;
  const unsigned short* src = Xb + (((size_t)n * 4096) << 7) + (chp << 1);
  size_t dst0 = (((size_t)n * 64 + chp * 2) << 13);   // slab * 8192 shorts
#pragma unroll
  for (int half = 0; half < 2; ++half) {
    union { unsigned short u[16]; int4 v[2]; } a0, a1;
#pragma unroll
    for (int m = 0; m < 16; ++m) {
      int hw = tid * 16 + m;
      unsigned vv = *(const unsigned*)(src + ((size_t)hw << 7) + (half << 6));
      a0.u[m] = (unsigned short)(vv & 0xffffu);
      a1.u[m] = (unsigned short)(vv >> 16);
    }
    *(int4*)(Xc + dst0 + (half << 12) + tid * 16)            = a0.v[0];
    *(int4*)(Xc + dst0 + (half << 12) + tid * 16 + 8)        = a0.v[1];
    *(int4*)(Xc + dst0 + 8192 + (half << 12) + tid * 16)     = a1.v[0];
    *(int4*)(Xc + dst0 + 8192 + (half << 12) + tid * 16 + 8) = a1.v[1];
  }
}

// ---------------- Kernel B: implicit-GEMM MFMA conv ------------------------
__global__ __launch_bounds__(256, 4) void k_conv_mfma(
    const unsigned short* __restrict__ Xb,   // [n][hw][c=128]
    const unsigned short* __restrict__ Wt,   // fragment-ordered (see k_wprep)
    const float* __restrict__ br, const float* __restrict__ bi,
    unsigned short* __restrict__ Cb) {       // [n][co=128][hw]
  __shared__ unsigned short Xs[4 * 8 * 66 * 8];   // 33,792 B
  int bid = xcd_swizzle(blockIdx.x, 1024);   // same-n blocks share an XCD
  int rg = bid & 31, n = bid >> 5;
  int r0 = rg << 1;
  int tid = threadIdx.x;
  int lane = tid & 63, wv = tid >> 6;
  int l31 = lane & 31, lhi = lane >> 5;
  int cb = wv >> 1;
  int cobase = cb << 6;
  int prow = wv & 1;

  accv acc[4] = {accv{}, accv{}, accv{}, accv{}};

  for (int q = tid; q < 2112; q += 256)
    ((int4*)Xs)[q] = make_int4(0, 0, 0, 0);
  __syncthreads();

  for (int half = 0; half < 2; ++half) {
    for (int q = tid; q < 2048; q += 256) {
      int cs = q & 7, col = (q >> 3) & 63, j = q >> 9;
      int gr = r0 - 1 + j;
      if (gr >= 0 && gr < 64) {
        const int4 v = *(const int4*)(Xb + (((size_t)n * 4096 + gr * 64 + col) << 7)
                                      + (half << 6) + (cs << 3));
        *(int4*)(Xs + (((j * 8 + cs) * 66 + col + 1) << 3)) = v;
      }
    }
    __syncthreads();
#pragma unroll
    for (int tap = 0; tap < 9; ++tap) {
      int kh = tap / 3, kw = tap - kh * 3;
#pragma unroll
      for (int ks = 0; ks < 4; ++ks) {
        bfrag af[2], bfv[2];
        const unsigned short* wf =
            Wt + ((((((tap * 2 + half) * 4 + ks) * 2 + cb) * 2) * 64) + lane) * 8;
        af[0] = *(const bfrag*)wf;
        af[1] = *(const bfrag*)(wf + 512);
        const unsigned short* xrow = Xs + ((((prow + kh) * 8 + (ks * 2 + lhi)) * 66 + kw) << 3);
#pragma unroll
        for (int u = 0; u < 2; ++u)
          bfv[u] = *(const bfrag*)(xrow + ((u * 32 + l31) << 3));
#pragma unroll
        for (int t2 = 0; t2 < 2; ++t2)
#pragma unroll
          for (int u = 0; u < 2; ++u)
            acc[t2 * 2 + u] = __builtin_amdgcn_mfma_f32_32x32x16_bf16(
                af[t2], bfv[u], acc[t2 * 2 + u], 0, 0, 0);
      }
    }
    __syncthreads();
  }

#pragma unroll
  for (int t2 = 0; t2 < 2; ++t2) {
#pragma unroll
    for (int u = 0; u < 2; ++u) {
      accv A = acc[t2 * 2 + u];
      int hw = (r0 + prow) * 64 + u * 32 + l31;
#pragma unroll
      for (int rr = 0; rr < 16; ++rr) {
        int co = cobase + t2 * 32 + (rr & 3) + ((rr >> 2) << 3) + (lhi << 2);
        float bias = (co < 64) ? br[co] : bi[co & 63];
        Cb[(((size_t)n * 128 + co) << 12) + hw] = f2b(A[rr] + bias);
      }
    }
  }
}

// -------- Kernel C: register-resident radix-4 FFT2 -> wspec -> iFFT2 -------
__global__ __launch_bounds__(256, 2) void k_fft_blend(
    float* __restrict__ Xr, float* __restrict__ Xi,        // W0 out
    const unsigned short* __restrict__ Xc,                 // [slab][half][4096]
    const unsigned short* __restrict__ Cb,                 // cliff   [n][co][hw]
    const float* __restrict__ rr_, const float* __restrict__ ri_,
    const float* __restrict__ swr, const float* __restrict__ swi,
    const float2* __restrict__ Ps,                         // prepped (or null)
    const float* __restrict__ gate) {
  __shared__ __align__(16) float2 sc[64 * 66];   // 33,792 B, pitch 66
  __shared__ float2 tw[64];                      // W64^j = (cos,sin)(2*pi*j/64)
  int bid = xcd_swizzle(blockIdx.x, 2048);   // same-n ch-blocks share an XCD
  int ch = bid & 63;
  int n = bid >> 6;
  int base = bid << 12;
  int tid = threadIdx.x;
  int lane = tid & 63, wv = tid >> 6;
  int l15 = lane & 15;
  int p = lane >> 4;                    // 16-block residue class, in-wave
  int kap = ((p & 1) << 1) | (p >> 1);  // pi(p): 2-bit reverse
  bool pswap = (p & 1), prot = (p & 2);
  float sA = prot ? -1.f : 1.f;         // sign for xor32-style round
  float sB = pswap ? -1.f : 1.f;        // sign for xor16-style round
  int r = wv * 16 + l15;                // line index for x-passes
  int cy = r;                           // column index for y-passes (same map)

  if (tid < 64) {
    float sv, cv;
    __sincosf(0.09817477042468103f * (float)tid, &sv, &cv);  // 2*pi/64
    tw[tid] = make_float2(cv, sv);
  }

  float2 x[16];
  // ---- coalesced load from Xc: thread owns row r, cols 16p..16p+15 ----
  {
    const unsigned short* xp = Xc + ((size_t)bid << 13) + r * 64 + 16 * p;
    int4 ra = *(const int4*)xp;
    int4 rb = *(const int4*)(xp + 8);
    int4 ia = *(const int4*)(xp + 4096);
    int4 ib = *(const int4*)(xp + 4104);
    const unsigned short* rap = (const unsigned short*)&ra;
    const unsigned short* rbp = (const unsigned short*)&rb;
    const unsigned short* iap = (const unsigned short*)&ia;
    const unsigned short* ibp = (const unsigned short*)&ib;
#pragma unroll
    for (int j = 0; j < 8; ++j) {
      x[j]     = make_float2(b2f(rap[j]), b2f(iap[j]));
      x[8 + j] = make_float2(b2f(rbp[j]), b2f(ibp[j]));
    }
  }
  __syncthreads();   // tw table ready

  // =================== forward x (DIF: q16 shfl, q4, q1) ===================
#pragma unroll
  for (int j = 0; j < 16; ++j) {        // q=16 stage across p, then twiddle
    float2 mine = x[j];
    float2 pr = shfl_xor2(mine, 32);
    float2 t = make_float2(pr.x + sA * mine.x, pr.y + sA * mine.y);
    float2 pr2 = shfl_xor2(t, 16);
    float2 low = pswap ? pr2 : t;
    float2 high = pswap ? t : pr2;
    float2 u = prot ? make_float2(high.y, -high.x) : high;   // -i*high
    float2 o = make_float2(low.x + sB * u.x, low.y + sB * u.y);
    x[j] = c_mul_conj(o, tw[kap * j]);
  }
#pragma unroll
  for (int b = 0; b < 4; ++b) {         // q=4
    float2 t0 = c_add(x[b], x[b + 8]), t1 = c_sub(x[b], x[b + 8]);
    float2 t2 = c_add(x[b + 4], x[b + 12]), t3 = c_sub(x[b + 4], x[b + 12]);
    x[b] = c_add(t0, t2);
    float2 u1 = make_float2(t1.x + t3.y, t1.y - t3.x);
    float2 u2 = c_sub(t0, t2);
    float2 u3 = make_float2(t1.x - t3.y, t1.y + t3.x);
    x[b + 4] = c_mul_conj(u1, tw[4 * b]);
    x[b + 8] = c_mul_conj(u2, tw[8 * b]);
    x[b + 12] = c_mul_conj(u3, tw[12 * b]);
  }
#pragma unroll
  for (int a = 0; a < 4; ++a) {         // q=1 (no twiddles)
    int a4 = 4 * a;
    float2 t0 = c_add(x[a4], x[a4 + 2]), t1 = c_sub(x[a4], x[a4 + 2]);
    float2 t2 = c_add(x[a4 + 1], x[a4 + 3]), t3 = c_sub(x[a4 + 1], x[a4 + 3]);
    x[a4] = c_add(t0, t2);
    x[a4 + 1] = make_float2(t1.x + t3.y, t1.y - t3.x);
    x[a4 + 2] = c_sub(t0, t2);
    x[a4 + 3] = make_float2(t1.x - t3.y, t1.y + t3.x);
  }
  // write row r, cols 16*kap.. (ownership permuted by pi)
#pragma unroll
  for (int q = 0; q < 8; ++q) {
    float4 v = make_float4(x[2 * q].x, x[2 * q].y, x[2 * q + 1].x, x[2 * q + 1].y);
    *(float4*)&sc[r * 66 + 16 * kap + 2 * q] = v;
  }
  __syncthreads();

  // =================== forward y (read natural block p) ====================
#pragma unroll
  for (int j = 0; j < 16; ++j)
    x[j] = sc[(16 * p + j) * 66 + cy];
#pragma unroll
  for (int j = 0; j < 16; ++j) {        // q=16 (identical to fwd-x)
    float2 mine = x[j];
    float2 pr = shfl_xor2(mine, 32);
    float2 t = make_float2(pr.x + sA * mine.x, pr.y + sA * mine.y);
    float2 pr2 = shfl_xor2(t, 16);
    float2 low = pswap ? pr2 : t;
    float2 high = pswap ? t : pr2;
    float2 u = prot ? make_float2(high.y, -high.x) : high;
    float2 o = make_float2(low.x + sB * u.x, low.y + sB * u.y);
    x[j] = c_mul_conj(o, tw[kap * j]);
  }
#pragma unroll
  for (int b = 0; b < 4; ++b) {
    float2 t0 = c_add(x[b], x[b + 8]), t1 = c_sub(x[b], x[b + 8]);
    float2 t2 = c_add(x[b + 4], x[b + 12]), t3 = c_sub(x[b + 4], x[b + 12]);
    x[b] = c_add(t0, t2);
    float2 u1 = make_float2(t1.x + t3.y, t1.y - t3.x);
    float2 u2 = c_sub(t0, t2);
    float2 u3 = make_float2(t1.x - t3.y, t1.y + t3.x);
    x[b + 4] = c_mul_conj(u1, tw[4 * b]);
    x[b + 8] = c_mul_conj(u2, tw[8 * b]);
    x[b + 12] = c_mul_conj(u3, tw[12 * b]);
  }
#pragma unroll
  for (int a = 0; a < 4; ++a) {
    int a4 = 4 * a;
    float2 t0 = c_add(x[a4], x[a4 + 2]), t1 = c_sub(x[a4], x[a4 + 2]);
    float2 t2 = c_add(x[a4 + 1], x[a4 + 3]), t3 = c_sub(x[a4 + 1], x[a4 + 3]);
    x[a4] = c_add(t0, t2);
    x[a4 + 1] = make_float2(t1.x + t3.y, t1.y - t3.x);
    x[a4 + 2] = c_sub(t0, t2);
    x[a4 + 3] = make_float2(t1.x - t3.y, t1.y + t3.x);
  }

  // ============ spectral multiply in registers (digit-reversed) ============
  if (Ps) {
    const float2* pp = Ps + (((size_t)(ch * 4 + p) * 16) << 6) + r;
#pragma unroll
    for (int j = 0; j < 16; ++j) {
      float2 w = pp[j * 64];
      float2 v = x[j];
      x[j] = make_float2(v.x * w.x - v.y * w.y, v.x * w.y + v.y * w.x);
    }
  } else {
    int fb = ch * 4096 + rev4(cy);      // + fr*64
#pragma unroll
    for (int j = 0; j < 16; ++j) {
      int fr = ((j & 3) << 4) | (((j >> 2) & 3) << 2) | kap;
      float wr = swr[fb + fr * 64];
      float wi = swi[fb + fr * 64];
      float2 v = x[j];
      x[j] = make_float2(v.x * wr - v.y * wi, v.x * wi + v.y * wr);
    }
  }

  // ====== inverse y (DIT: q1, q4, pre-twiddle, q16 shfl; own blk=pi(p)) ====
#pragma unroll
  for (int a = 0; a < 4; ++a) {         // q=1
    int a4 = 4 * a;
    float2 e0 = c_add(x[a4], x[a4 + 2]), e1 = c_sub(x[a4], x[a4 + 2]);
    float2 o0 = c_add(x[a4 + 1], x[a4 + 3]), o1 = c_sub(x[a4 + 1], x[a4 + 3]);
    x[a4] = c_add(e0, o0);
    x[a4 + 1] = make_float2(e1.x - o1.y, e1.y + o1.x);
    x[a4 + 2] = c_sub(e0, o0);
    x[a4 + 3] = make_float2(e1.x + o1.y, e1.y - o1.x);
  }
#pragma unroll
  for (int b = 0; b < 4; ++b) {         // q=4
    float2 v1 = c_mul_pos(x[b + 4], tw[4 * b]);
    float2 v2 = c_mul_pos(x[b + 8], tw[8 * b]);
    float2 v3 = c_mul_pos(x[b + 12], tw[12 * b]);
    float2 e0 = c_add(x[b], v2), e1 = c_sub(x[b], v2);
    float2 o0 = c_add(v1, v3), o1 = c_sub(v1, v3);
    x[b] = c_add(e0, o0);
    x[b + 4] = make_float2(e1.x - o1.y, e1.y + o1.x);
    x[b + 8] = c_sub(e0, o0);
    x[b + 12] = make_float2(e1.x + o1.y, e1.y - o1.x);
  }
#pragma unroll
  for (int j = 0; j < 16; ++j) {        // q=16, v = pi(p) ownership
    float2 mine = c_mul_pos(x[j], tw[kap * j]);
    float2 pr = shfl_xor2(mine, 16);
    float2 t = make_float2(pr.x + sB * mine.x, pr.y + sB * mine.y);
    float2 pr2 = shfl_xor2(t, 32);
    float2 low = prot ? pr2 : t;
    float2 high = prot ? t : pr2;
    float2 u = pswap ? make_float2(-high.y, high.x) : high;  // +i*high
    x[j] = make_float2(low.x + sA * u.x, low.y + sA * u.y);
  }
  // write natural rows 16p+j at column cy
#pragma unroll
  for (int j = 0; j < 16; ++j)
    sc[(16 * p + j) * 66 + cy] = x[j];
  __syncthreads();

  // ====== inverse x (read natural block p; q1, q4, pre-twiddle, q16) =======
#pragma unroll
  for (int q = 0; q < 8; ++q) {
    float4 v = *(const float4*)&sc[r * 66 + 16 * p + 2 * q];
    x[2 * q] = make_float2(v.x, v.y);
    x[2 * q + 1] = make_float2(v.z, v.w);
  }
#pragma unroll
  for (int a = 0; a < 4; ++a) {
    int a4 = 4 * a;
    float2 e0 = c_add(x[a4], x[a4 + 2]), e1 = c_sub(x[a4], x[a4 + 2]);
    float2 o0 = c_add(x[a4 + 1], x[a4 + 3]), o1 = c_sub(x[a4 + 1], x[a4 + 3]);
    x[a4] = c_add(e0, o0);
    x[a4 + 1] = make_float2(e1.x - o1.y, e1.y + o1.x);
    x[a4 + 2] = c_sub(e0, o0);
    x[a4 + 3] = make_float2(e1.x + o1.y, e1.y - o1.x);
  }
#pragma unroll
  for (int b = 0; b < 4; ++b) {
    float2 v1 = c_mul_pos(x[b + 4], tw[4 * b]);
    float2 v2 = c_mul_pos(x[b + 8], tw[8 * b]);
    float2 v3 = c_mul_pos(x[b + 12], tw[12 * b]);
    float2 e0 = c_add(x[b], v2), e1 = c_sub(x[b], v2);
    float2 o0 = c_add(v1, v3), o1 = c_sub(v1, v3);
    x[b] = c_add(e0, o0);
    x[b + 4] = make_float2(e1.x - o1.y, e1.y + o1.x);
    x[b + 8] = c_sub(e0, o0);
    x[b + 12] = make_float2(e1.x + o1.y, e1.y - o1.x);
  }
#pragma unroll
  for (int j = 0; j < 16; ++j) {        // q=16, v = p ownership -> blk pi(p)
    float2 mine = c_mul_pos(x[j], tw[p * j]);
    float2 pr = shfl_xor2(mine, 32);
    float2 t = make_float2(pr.x + sA * mine.x, pr.y + sA * mine.y);
    float2 pr2 = shfl_xor2(t, 16);
    float2 low = pswap ? pr2 : t;
    float2 high = pswap ? t : pr2;
    float2 u = prot ? make_float2(-high.y, high.x) : high;   // +i*high
    x[j] = make_float2(low.x + sB * u.x, low.y + sB * u.y);
  }
  __syncthreads();   // everyone done reading sc from inv-y transpose

  // stage final values to LDS: element (r, 16*kap + j) <- x[j]
#pragma unroll
  for (int q = 0; q < 8; ++q) {
    float4 v = make_float4(x[2 * q].x, x[2 * q].y, x[2 * q + 1].x, x[2 * q + 1].y);
    *(float4*)&sc[r * 66 + 16 * kap + 2 * q] = v;
  }
  __syncthreads();

  // ---- fully-coalesced blend with cliff + resid, store ----
  float g = gate[0];
  const float scale = 1.f / 4096.f;
  for (int idx = tid; idx < 4096; idx += 256) {
    int rr2 = idx >> 6, cc2 = idx & 63;
    float2 sp = sc[rr2 * 66 + cc2];
    int a = base + idx;
    float cr = b2f(Cb[(((size_t)n * 128 + ch) << 12) + idx]);
    float ci = b2f(Cb[(((size_t)n * 128 + 64 + ch) << 12) + idx]);
    Xr[a] = g * cr + (1.f - g) * sp.x * scale + rr_[a];
    Xi[a] = g * ci + (1.f - g) * sp.y * scale + ri_[a];
  }
}

// -------- Kernel D: fused temporal (LN -> GEMM1 -> scan -> GEMM2 -> +res) --
// Xe padded to stride 129. Scan threads remapped px=tid&3/dp=tid>>2 so the
// per-t Asub b16 writes span 16 banks (was 4 -> 16-way conflict, 3.9M extra
// cycles). LN pack remapped to c = k*8 + seg*2 so the packed dword writes
// land on bank tid&31 (conflict-free; was 8-way).
__global__ __launch_bounds__(256, 3) void k_temporal_mfma(
    float* __restrict__ Xr, float* __restrict__ Xi,   // W0 in/out
    const float* __restrict__ dt,
    const float* __restrict__ lnw, const float* __restrict__ lnb,
    const float* __restrict__ lam_re, const float* __restrict__ lam_im,
    const unsigned short* __restrict__ Wt1, const unsigned short* __restrict__ Wt2) {
  __shared__ unsigned short Asub[16 * 64 * 8];    // 16 KB
  __shared__ float Xe[64 * 129];                  // 33,024 B (padded)
  int bid = xcd_swizzle(blockIdx.x, 2048);
  int b = bid >> 10, tile = bid & 1023;
  int hw0 = tile * 4;
  int tid = threadIdx.x;
  int lane = tid & 63, wv = tid >> 6;
  int l31 = lane & 31, lhi = lane >> 5;
  size_t xbase = (size_t)b * TT * DCH * HW + hw0;

  float4 res[8];
#pragma unroll
  for (int q = 0; q < 8; ++q) {
    int item = tid + q * 256;          // t*128 + c
    int t = item >> 7, c = item & 127;
    int d = c & 63;
    const float* src = ((c >> 6) ? Xi : Xr) + xbase + ((size_t)t * 64 + d) * HW;
    float4 v = *(const float4*)src;
    res[q] = v;                        // residual stays in registers
    Xe[(t * 4 + 0) * 129 + c] = v.x;
    Xe[(t * 4 + 1) * 129 + c] = v.y;
    Xe[(t * 4 + 2) * 129 + c] = v.z;
    Xe[(t * 4 + 3) * 129 + c] = v.w;
  }
  __syncthreads();

  {
    int row = tid >> 2, seg = tid & 3;
    float s = 0.f, s2 = 0.f;
#pragma unroll
    for (int j = 0; j < 32; ++j) {
      float v = Xe[row * 129 + seg * 32 + j];
      s += v; s2 += v * v;
    }
    s += __shfl_xor(s, 1); s2 += __shfl_xor(s2, 1);
    s += __shfl_xor(s, 2); s2 += __shfl_xor(s2, 2);
    float mu = s * (1.f / 128.f);
    float var = s2 * (1.f / 128.f) - mu * mu;
    float rs = rsqrtf(var + EPS);
    // pack c = k*8 + seg*2, k=0..15: write bank = tid&31 (conflict-free)
#pragma unroll
    for (int k = 0; k < 16; ++k) {
      int c = k * 8 + seg * 2;
      float v0 = (Xe[row * 129 + c] - mu) * rs * lnw[c] + lnb[c];
      float v1 = (Xe[row * 129 + c + 1] - mu) * rs * lnw[c + 1] + lnb[c + 1];
      unsigned pk = (unsigned)f2b(v0) | ((unsigned)f2b(v1) << 16);
      *(unsigned*)(Asub + (k * 64 + row) * 8 + seg * 2) = pk;
    }
  }
  __syncthreads();

  int mt = wv & 1, ntb = (wv >> 1) << 1;
  accv acc0 = accv{}, acc1 = accv{};
#pragma unroll
  for (int ks = 0; ks < 8; ++ks) {
    int kg = ks * 2 + lhi;
    bfrag a = *(const bfrag*)(Asub + (kg * 64 + mt * 32 + l31) * 8);
    bfrag b0 = *(const bfrag*)(Wt1 + (kg * 128 + ntb * 32 + l31) * 8);
    bfrag b1 = *(const bfrag*)(Wt1 + (kg * 128 + (ntb + 1) * 32 + l31) * 8);
    acc0 = __builtin_amdgcn_mfma_f32_32x32x16_bf16(a, b0, acc0, 0, 0, 0);
    acc1 = __builtin_amdgcn_mfma_f32_32x32x16_bf16(a, b1, acc1, 0, 0, 0);
  }
  __syncthreads();

#pragma unroll
  for (int rr = 0; rr < 16; ++rr) {
    int mrow = mt * 32 + (rr & 3) + ((rr >> 2) << 3) + (lhi << 2);
    Xe[mrow * 129 + ntb * 32 + l31] = acc0[rr];
    Xe[mrow * 129 + (ntb + 1) * 32 + l31] = acc1[rr];
  }
  __syncthreads();

  {
    int px = tid & 3, dp = tid >> 2;   // r varies per-lane -> 4-way writes
    float x0 = lam_re[dp];
    float nl = -(x0 > 15.f ? x0 : log1pf(__expf(x0)));
    float li = lam_im[dp];
    float hr = 0.f, hi = 0.f;
    int cR = dp, cI = 64 + dp;
    for (int t = 0; t < TT; ++t) {
      float dtv = dt[b * 16 + t];
      float ea = __expf(nl * dtv);
      float sv, cv; __sincosf(li * dtv, &sv, &cv);
      float evr = ea * cv, evi = ea * sv;
      int r = t * 4 + px;
      float xr_ = Xe[r * 129 + cR], xi_ = Xe[r * 129 + cI];
      float nhr = evr * hr - evi * hi + xr_;
      float nhi = evr * hi + evi * hr + xi_;
      hr = nhr; hi = nhi;
      Asub[((cR >> 3) * 64 + r) * 8 + (cR & 7)] = f2b(hr);
      Asub[((cI >> 3) * 64 + r) * 8 + (cI & 7)] = f2b(hi);
    }
  }
  __syncthreads();

  acc0 = accv{}; acc1 = accv{};
#pragma unroll
  for (int ks = 0; ks < 8; ++ks) {
    int kg = ks * 2 + lhi;
    bfrag a = *(const bfrag*)(Asub + (kg * 64 + mt * 32 + l31) * 8);
    bfrag b0 = *(const bfrag*)(Wt2 + (kg * 128 + ntb * 32 + l31) * 8);
    bfrag b1 = *(const bfrag*)(Wt2 + (kg * 128 + (ntb + 1) * 32 + l31) * 8);
    acc0 = __builtin_amdgcn_mfma_f32_32x32x16_bf16(a, b0, acc0, 0, 0, 0);
    acc1 = __builtin_amdgcn_mfma_f32_32x32x16_bf16(a, b1, acc1, 0, 0, 0);
  }
  __syncthreads();

#pragma unroll
  for (int rr = 0; rr < 16; ++rr) {
    int mrow = mt * 32 + (rr & 3) + ((rr >> 2) << 3) + (lhi << 2);
    Xe[mrow * 129 + ntb * 32 + l31] = acc0[rr];
    Xe[mrow * 129 + (ntb + 1) * 32 + l31] = acc1[rr];
  }
  __syncthreads();

#pragma unroll
  for (int q = 0; q < 8; ++q) {
    int item = tid + q * 256;
    int t = item >> 7, c = item & 127;
    int d = c & 63;
    float* dst = ((c >> 6) ? Xi : Xr) + xbase + ((size_t)t * 64 + d) * HW;
    float4 o;
    o.x = Xe[(t * 4 + 0) * 129 + c] + res[q].x;
    o.y = Xe[(t * 4 + 1) * 129 + c] + res[q].y;
    o.z = Xe[(t * 4 + 2) * 129 + c] + res[q].z;
    o.w = Xe[(t * 4 + 3) * 129 + c] + res[q].w;
    *(float4*)dst = o;
  }
}

// -------- Kernel E2: MFMA MLP with prepped weights (B from global) ---------
__global__ __launch_bounds__(256, 4) void k_mlp_pre(
    const float* __restrict__ Xr, const float* __restrict__ Xi,
    const float* __restrict__ lnw, const float* __restrict__ lnb,
    const unsigned short* __restrict__ Wm1,   // [2h][16kg][128n][8]
    const unsigned short* __restrict__ Wm2,   // [2kh][16kg][128n][8]
    const float* __restrict__ b1, const float* __restrict__ b2,
    float* __restrict__ out) {
  __shared__ __align__(16) unsigned char smem[32768];
  float* Xe = (float*)smem;                               // [128c][64m]
  unsigned short* Asub = (unsigned short*)smem;           // [16kg][64m][8]
  unsigned short* mid  = (unsigned short*)(smem + 16384); // [16kg][64m][8]
  unsigned short* ost  = (unsigned short*)smem;           // [128ng][66]
  int bid = blockIdx.x;
  int bt = bid >> 6, tile = bid & 63;
  int hw0 = tile << 6;
  int tid = threadIdx.x;
  int lane = tid & 63, wv = tid >> 6;
  int l31 = lane & 31, lhi = lane >> 5;
  size_t base = (size_t)bt * DCH * HW + hw0;   // + d*HW + m

#pragma unroll
  for (int q = 0; q < 8; ++q) {
    int item = q * 256 + tid;           // 2048 float4
    int m4 = item & 15, c = item >> 4;
    int d = c & 63;
    const float* src = ((c >> 6) ? Xi : Xr) + base + (size_t)d * HW + m4 * 4;
    *(float4*)(Xe + c * 64 + m4 * 4) = *(const float4*)src;
  }
  __syncthreads();                      // (1) Xe ready

  // LN: values held in registers across the in-place Asub overwrite
  {
    int row = tid >> 2, seg = tid & 3;
    float xv[32];
    float s = 0.f, s2 = 0.f;
#pragma unroll
    for (int j = 0; j < 32; ++j) {
      float v = Xe[(seg * 32 + j) * 64 + row];
      xv[j] = v; s += v; s2 += v * v;
    }
    s += __shfl_xor(s, 1); s2 += __shfl_xor(s2, 1);
    s += __shfl_xor(s, 2); s2 += __shfl_xor(s2, 2);
    float mu = s * (1.f / 128.f);
    float var = s2 * (1.f / 128.f) - mu * mu;
    float rs = rsqrtf(var + EPS);
    __syncthreads();                    // (2) all Xe reads done
#pragma unroll
    for (int j = 0; j < 32; ++j) {
      int c = seg * 32 + j;
      Asub[((c >> 3) * 64 + row) * 8 + (c & 7)] =
          f2b((xv[j] - mu) * rs * lnw[c] + lnb[c]);
    }
  }
  __syncthreads();                      // (3) Asub ready

  int ng = wv * 32 + l31;
  accv c0 = accv{}, c1 = accv{};
#pragma unroll
  for (int h = 0; h < 2; ++h) {
    accv g0 = accv{}, g1 = accv{};
#pragma unroll
    for (int ks = 0; ks < 8; ++ks) {
      int kg = ks * 2 + lhi;
      bfrag bfr = *(const bfrag*)(Wm1 + (((h * 16 + kg) * 128) + ng) * 8);
      bfrag a0 = *(const bfrag*)(Asub + (kg * 64 + l31) * 8);
      bfrag a1 = *(const bfrag*)(Asub + (kg * 64 + 32 + l31) * 8);
      g0 = __builtin_amdgcn_mfma_f32_32x32x16_bf16(a0, bfr, g0, 0, 0, 0);
      g1 = __builtin_amdgcn_mfma_f32_32x32x16_bf16(a1, bfr, g1, 0, 0, 0);
    }
    if (h == 1) __syncthreads();        // (5) G2-kh0 mid reads done
    float b1v = b1[h * 128 + ng];
    int kgl = ng >> 3, jj = ng & 7;
#pragma unroll
    for (int rr = 0; rr < 16; ++rr) {
      int mr = (rr & 3) + ((rr >> 2) << 3) + (lhi << 2);
      mid[(kgl * 64 + mr) * 8 + jj] = f2b(gelu_f(g0[rr] + b1v));
      mid[(kgl * 64 + 32 + mr) * 8 + jj] = f2b(gelu_f(g1[rr] + b1v));
    }
    __syncthreads();                    // (4)/(6) mid ready
#pragma unroll
    for (int ks = 0; ks < 8; ++ks) {
      int kg = ks * 2 + lhi;
      bfrag bfr = *(const bfrag*)(Wm2 + (((h * 16 + kg) * 128) + ng) * 8);
      bfrag a0 = *(const bfrag*)(mid + (kg * 64 + l31) * 8);
      bfrag a1 = *(const bfrag*)(mid + (kg * 64 + 32 + l31) * 8);
      c0 = __builtin_amdgcn_mfma_f32_32x32x16_bf16(a0, bfr, c0, 0, 0, 0);
      c1 = __builtin_amdgcn_mfma_f32_32x32x16_bf16(a1, bfr, c1, 0, 0, 0);
    }
  }
  __syncthreads();                      // (7) all mid reads done

  {
    float b2v = b2[ng];
#pragma unroll
    for (int rr = 0; rr < 16; ++rr) {
      int mr = (rr & 3) + ((rr >> 2) << 3) + (lhi << 2);
      ost[ng * 66 + mr] = f2b(c0[rr] + b2v);
      ost[ng * 66 + 32 + mr] = f2b(c1[rr] + b2v);
    }
  }
  __syncthreads();                      // (8) ostage ready
#pragma unroll
  for (int q = 0; q < 4; ++q) {
    int item = q * 256 + tid;          // 1024: (d, m4)
    int m4 = item & 15, d = item >> 4;
    size_t xa = base + (size_t)d * HW + m4 * 4;
    float4 xr4 = *(const float4*)(Xr + xa);
    float4 xi4 = *(const float4*)(Xi + xa);
    int m = m4 * 4;
    float r0 = b2f(ost[d * 66 + m]),     i0 = b2f(ost[(64 + d) * 66 + m]);
    float r1 = b2f(ost[d * 66 + m + 1]), i1 = b2f(ost[(64 + d) * 66 + m + 1]);
    float r2 = b2f(ost[d * 66 + m + 2]), i2 = b2f(ost[(64 + d) * 66 + m + 2]);
    float r3 = b2f(ost[d * 66 + m + 3]), i3 = b2f(ost[(64 + d) * 66 + m + 3]);
    float4 o1, o2;
    o1.x = r0 + xr4.x; o1.y = i0 + xi4.x; o1.z = r1 + xr4.y; o1.w = i1 + xi4.y;
    o2.x = r2 + xr4.z; o2.y = i2 + xi4.z; o2.z = r3 + xr4.w; o2.w = i3 + xi4.w;
    *(float4*)(out + xa * 2) = o1;
    *(float4*)(out + xa * 2 + 4) = o2;
  }
}

extern "C" void kernel_launch(void* const* d_in, const int* in_sizes, int n_in,
                              void* d_out, int out_size, void* d_ws, size_t ws_size,
                              hipStream_t stream) {
  const float* x_real  = (const float*)d_in[0];
  const float* x_imag  = (const float*)d_in[1];
  const float* dt      = (const float*)d_in[2];
  const float* ln_s_w  = (const float*)d_in[3];
  const float* ln_s_b  = (const float*)d_in[4];
  const float* ln_t_w  = (const float*)d_in[5];
  const float* ln_t_b  = (const float*)d_in[6];
  const float* ln_m_w  = (const float*)d_in[7];
  const float* ln_m_b  = (const float*)d_in[8];
  const float* cw_r    = (const float*)d_in[9];
  const float* cw_i    = (const float*)d_in[10];
  const float* cb_r    = (const float*)d_in[11];
  const float* cb_i    = (const float*)d_in[12];
  const float* spec_wr = (const float*)d_in[13];
  const float* spec_wi = (const float*)d_in[14];
  const float* gate    = (const float*)d_in[15];
  const float* lam_re  = (const float*)d_in[16];
  const float* lam_im  = (const float*)d_in[17];
  const float* V_re    = (const float*)d_in[18];
  const float* V_im    = (const float*)d_in[19];
  const float* Vinv_re = (const float*)d_in[20];
  const float* Vinv_im = (const float*)d_in[21];
  const float* mlp_w1  = (const float*)d_in[22];
  const float* mlp_b1  = (const float*)d_in[23];
  const float* mlp_w2  = (const float*)d_in[24];
  const float* mlp_b2  = (const float*)d_in[25];

  float* out = (float*)d_out;
  unsigned short* Xb = (unsigned short*)d_out;
  unsigned short* Cb = Xb + (size_t)2 * NELEM;
  unsigned short* Wt1 = Xb;
  unsigned short* Wt2 = Xb + 16384;
  float* W0r = (float*)d_ws;
  float* W0i = W0r + NELEM;
  unsigned short* Wt = (unsigned short*)d_ws;
  // Xc (channel-major ln-out for the FFT) overlays W0i: each fft block reads
  // its Xc slab fully into registers before any of its W0i writes, and slabs
  // are block-disjoint with identical index <-> byte-range mapping.
  unsigned short* Xc = (unsigned short*)W0i;
  // MLP bf16 weights live past the 64 MB W0 region (ws_size-guarded; verified
  // large enough in rounds 6-9).
  size_t ws_used = (size_t)2 * NELEM * 4;
  unsigned short* Wm = (unsigned short*)((char*)d_ws + ws_used);
  // Spectral weight pre-gather (2 MB) past Wm, only if workspace permits.
  size_t ps_off = ws_used + 131072;
  bool sprep = ws_size >= ps_off + (size_t)262144 * 8;
  float2* Ps = sprep ? (float2*)((char*)d_ws + ps_off) : (float2*)nullptr;

  k_wprep<<<576, 256, 0, stream>>>(cw_r, cw_i, Wt);
  k_mprep<<<256, 256, 0, stream>>>(mlp_w1, mlp_w2, Wm);
  if (sprep) k_sprep<<<1024, 256, 0, stream>>>(spec_wr, spec_wi, Ps);
  k_ln_spatial<<<512, 256, 0, stream>>>(x_real, x_imag, ln_s_w, ln_s_b, Xb);
  k_xpose<<<1024, 256, 0, stream>>>(Xb, Xc);
  k_conv_mfma<<<1024, 256, 0, stream>>>(Xb, Wt, cb_r, cb_i, Cb);
  k_fft_blend<<<2048, 256, 0, stream>>>(W0r, W0i, Xc, Cb, x_real, x_imag,
                                        spec_wr, spec_wi, Ps, gate);
  k_vprep<<<64, 256, 0, stream>>>(V_re, V_im, Vinv_re, Vinv_im, Wt1, Wt2);
  k_temporal_mfma<<<2048, 256, 0, stream>>>(W0r, W0i, dt, ln_t_w, ln_t_b,
                                            lam_re, lam_im, Wt1, Wt2);
  k_mlp_pre<<<2048, 256, 0, stream>>>(W0r, W0i, ln_m_w, ln_m_b,
                                      Wm, Wm + 32768, mlp_b1, mlp_b2, out);
}

// Round 11
// 488.334 us; speedup vs baseline: 1.0189x; 1.0189x over previous
//
#include <hip/hip_runtime.h>
#include <math.h>

#define NELEM 8388608   // B*T*D*H*W = 2*16*64*64*64
#define HW    4096
#define DCH   64
#define TT    16
#define EPS   1e-5f

typedef __attribute__((ext_vector_type(8))) short bfrag;   // 8 bf16 = 4 VGPRs
typedef __attribute__((ext_vector_type(16))) float accv;   // 16 fp32 acc

__device__ __forceinline__ unsigned short f2b(float f) {
  union { float f; unsigned u; } v; v.f = f;
  unsigned r = (v.u + 0x7FFF + ((v.u >> 16) & 1)) >> 16;
  return (unsigned short)r;
}
__device__ __forceinline__ float b2f(unsigned short h) {
  union { unsigned u; float f; } v; v.u = ((unsigned)h) << 16;
  return v.f;
}
// base-4 digit reversal of a 6-bit index (3 digits)
__device__ __forceinline__ int rev4(int x) {
  return ((x & 3) << 4) | (x & 12) | ((x >> 4) & 3);
}
// XCD-locality swizzle: put consecutive logical tiles on the SAME XCD
// (dispatch is round-robin bid%8 -> XCD). NB must be divisible by 8.
__device__ __forceinline__ int xcd_swizzle(int bid, int nb) {
  return (bid & 7) * (nb >> 3) + (bid >> 3);
}

__device__ __forceinline__ float2 c_add(float2 a, float2 b) {
  return make_float2(a.x + b.x, a.y + b.y);
}
__device__ __forceinline__ float2 c_sub(float2 a, float2 b) {
  return make_float2(a.x - b.x, a.y - b.y);
}
// a * (w.x - i w.y)   [forward twiddle]
__device__ __forceinline__ float2 c_mul_conj(float2 a, float2 w) {
  return make_float2(a.x * w.x + a.y * w.y, a.y * w.x - a.x * w.y);
}
// a * (w.x + i w.y)   [inverse twiddle]
__device__ __forceinline__ float2 c_mul_pos(float2 a, float2 w) {
  return make_float2(a.x * w.x - a.y * w.y, a.y * w.x + a.x * w.y);
}
__device__ __forceinline__ float2 shfl_xor2(float2 v, int m) {
  return make_float2(__shfl_xor(v.x, m), __shfl_xor(v.y, m));
}
// tanh-form GELU: x*sigmoid(1.5958(x+0.044715x^3)); |err vs erf-gelu| < 1e-3,
// below bf16 rounding of the downstream f2b.
__device__ __forceinline__ float gelu_f(float v) {
  float y = -1.595769122f * (v + 0.044715f * v * v * v);
  return v * __builtin_amdgcn_rcpf(1.f + __expf(y));
}

// -------- Kernel W: weight prep -> MFMA-fragment order -----
// Wf[tap][half][ks][cb][t2][lane=lhi*32+l31][j]: the conv wave's A-fragment
// load becomes lane-consecutive 16 B (one coalesced 1 KB burst).
__global__ __launch_bounds__(256) void k_wprep(
    const float* __restrict__ cwr, const float* __restrict__ cwi,
    unsigned short* __restrict__ Wt) {
  int gid = blockIdx.x * 256 + threadIdx.x;
  if (gid >= 9 * 128 * 128) return;
  int j = gid & 7;
  int lane = (gid >> 3) & 63;
  int t2 = (gid >> 9) & 1;
  int cb = (gid >> 10) & 1;
  int ks = (gid >> 11) & 3;
  int half = (gid >> 13) & 1;
  int tap = gid >> 14;
  int l31 = lane & 31, lhi = lane >> 5;
  int co = cb * 64 + t2 * 32 + l31;
  int c = half * 64 + ks * 16 + lhi * 8 + j;
  int kh = tap / 3, kw = tap - kh * 3;
  int dout = co & 63, cin = c & 63;
  int widx = ((dout * 64 + cin) * 3 + kh) * 3 + kw;
  float v;
  if (co < 64) v = (c < 64) ? cwr[widx] : -cwi[widx];
  else         v = (c < 64) ? cwi[widx] :  cwr[widx];
  Wt[gid] = f2b(v);
}

// ------- Kernel V: temporal GEMM weights, MFMA-B layout [kg=16][n=128][8] --
__global__ __launch_bounds__(256) void k_vprep(
    const float* __restrict__ Vre, const float* __restrict__ Vim,
    const float* __restrict__ Vire, const float* __restrict__ Viim,
    unsigned short* __restrict__ Wt1, unsigned short* __restrict__ Wt2) {
  int gid = blockIdx.x * 256 + threadIdx.x;   // 0..16383
  int j = gid & 7, n = (gid >> 3) & 127, kg = gid >> 10;
  int k = kg * 8 + j;
  int d = k & 63, dp = n & 63;
  float v1, v2;
  if (k < 64) {
    v1 = (n < 64) ? Vire[dp * 64 + d] : Viim[dp * 64 + d];
    v2 = (n < 64) ? Vre[dp * 64 + d] : Vim[dp * 64 + d];
  } else {
    v1 = (n < 64) ? -Viim[dp * 64 + d] : Vire[dp * 64 + d];
    v2 = (n < 64) ? -Vim[dp * 64 + d] : Vre[dp * 64 + d];
  }
  Wt1[gid] = f2b(v1); Wt2[gid] = f2b(v2);
}

// ------- Kernel M: MLP weight prep -> Wm1[2h][16kg][128n][8], Wm2 same -----
__global__ __launch_bounds__(256) void k_mprep(
    const float* __restrict__ w1, const float* __restrict__ w2,
    unsigned short* __restrict__ Wm) {
  int gid = blockIdx.x * 256 + threadIdx.x;  // 0..65535
  int j = gid & 7, n = (gid >> 3) & 127, kgh = (gid >> 10) & 31;
  int hh = kgh >> 4, kg = kgh & 15;
  float v;
  if (gid < 32768) v = w1[(kg * 8 + j) * 256 + hh * 128 + n];
  else             v = w2[(hh * 128 + kg * 8 + j) * 128 + n];
  Wm[gid] = f2b(v);
}

// ------- Kernel S: spectral weight pre-gather into fft consumption order ---
// Ps[((ch*4 + p)*16 + j)*64 + cy] = (swr,swi)[ch*4096 + fr(j,kap(p))*64 +
// rev4(cy)]. Turns the fft's 64 scattered 4-B gathers/thread into 16 loads
// in 128-B lane-contiguous segments.
__global__ __launch_bounds__(256) void k_sprep(
    const float* __restrict__ swr, const float* __restrict__ swi,
    float2* __restrict__ Ps) {
  int gid = blockIdx.x * 256 + threadIdx.x;   // 0..262143
  int cy = gid & 63, j = (gid >> 6) & 15, p = (gid >> 10) & 3, ch = gid >> 12;
  int kap = ((p & 1) << 1) | (p >> 1);
  int fr = ((j & 3) << 4) | (((j >> 2) & 3) << 2) | kap;
  int addr = ch * 4096 + fr * 64 + rev4(cy);
  Ps[gid] = make_float2(swr[addr], swi[addr]);
}

// ---------------- Kernel A: spatial LN -> Xb[n][hw][c=128] bf16 ------------
__global__ __launch_bounds__(256) void k_ln_spatial(
    const float* __restrict__ xr, const float* __restrict__ xi,
    const float* __restrict__ w, const float* __restrict__ b,
    unsigned short* __restrict__ Xb) {
  int gid = blockIdx.x * 256 + threadIdx.x;   // 0..131071 = BT*HW
  int bt = gid >> 12;
  int hw = gid & 4095;
  size_t base = (size_t)bt * DCH * HW + hw;
  float vr[DCH], vi[DCH];
  float s = 0.f, s2 = 0.f;
#pragma unroll
  for (int d = 0; d < DCH; ++d) {
    float a = xr[base + d * HW];
    float c = xi[base + d * HW];
    vr[d] = a; vi[d] = c;
    s += a + c;
    s2 += a * a + c * c;
  }
  float mu = s * (1.f / 128.f);
  float var = s2 * (1.f / 128.f) - mu * mu;
  float rs = rsqrtf(var + EPS);
  unsigned short* dst = Xb + ((size_t)gid << 7);
#pragma unroll
  for (int k = 0; k < 8; ++k) {
    int4 o;
    unsigned short* op = (unsigned short*)&o;
#pragma unroll
    for (int j = 0; j < 8; ++j) {
      int d = k * 8 + j;
      op[j] = f2b((vr[d] - mu) * rs * w[d] + b[d]);
    }
    ((int4*)dst)[k] = o;
  }
#pragma unroll
  for (int k = 0; k < 8; ++k) {
    int4 o;
    unsigned short* op = (unsigned short*)&o;
#pragma unroll
    for (int j = 0; j < 8; ++j) {
      int d = k * 8 + j;
      op[j] = f2b((vi[d] - mu) * rs * w[64 + d] + b[64 + d]);
    }
    ((int4*)(dst + 64))[k] = o;
  }
}

// ------- Kernel X: transpose ln-out to channel-major for the FFT -----------
__global__ __launch_bounds__(256) void k_xpose(
    const unsigned short* __restrict__ Xb,   // [n][hw][c=128]
    unsigned short* __restrict__ Xc) {
  int bid = xcd_swizzle(blockIdx.x, 1024);   // same-n blocks share an XCD
  int n = bid >> 5, chp = bid & 31;          // channels chp*2, chp*2+1
  int tid = threadIdx.x;
  const unsigned short* src = Xb + (((size_t)n * 4096) << 7) + (chp << 1);
  size_t dst0 = (((size_t)n * 64 + chp * 2) << 13);   // slab * 8192 shorts
#pragma unroll
  for (int half = 0; half < 2; ++half) {
    union { unsigned short u[16]; int4 v[2]; } a0, a1;
#pragma unroll
    for (int m = 0; m < 16; ++m) {
      int hw = tid * 16 + m;
      unsigned vv = *(const unsigned*)(src + ((size_t)hw << 7) + (half << 6));
      a0.u[m] = (unsigned short)(vv & 0xffffu);
      a1.u[m] = (unsigned short)(vv >> 16);
    }
    *(int4*)(Xc + dst0 + (half << 12) + tid * 16)            = a0.v[0];
    *(int4*)(Xc + dst0 + (half << 12) + tid * 16 + 8)        = a0.v[1];
    *(int4*)(Xc + dst0 + 8192 + (half << 12) + tid * 16)     = a1.v[0];
    *(int4*)(Xc + dst0 + 8192 + (half << 12) + tid * 16 + 8) = a1.v[1];
  }
}

// ---------------- Kernel B: implicit-GEMM MFMA conv ------------------------
__global__ __launch_bounds__(256, 4) void k_conv_mfma(
    const unsigned short* __restrict__ Xb,   // [n][hw][c=128]
    const unsigned short* __restrict__ Wt,   // fragment-ordered (see k_wprep)
    const float* __restrict__ br, const float* __restrict__ bi,
    unsigned short* __restrict__ Cb) {       // [n][co=128][hw]
  __shared__ unsigned short Xs[4 * 8 * 66 * 8];   // 33,792 B
  int bid = xcd_swizzle(blockIdx.x, 1024);   // same-n blocks share an XCD
  int rg = bid & 31, n = bid >> 5;
  int r0 = rg << 1;
  int tid = threadIdx.x;
  int lane = tid & 63, wv = tid >> 6;
  int l31 = lane & 31, lhi = lane >> 5;
  int cb = wv >> 1;
  int cobase = cb << 6;
  int prow = wv & 1;

  accv acc[4] = {accv{}, accv{}, accv{}, accv{}};

  for (int q = tid; q < 2112; q += 256)
    ((int4*)Xs)[q] = make_int4(0, 0, 0, 0);
  __syncthreads();

  for (int half = 0; half < 2; ++half) {
    for (int q = tid; q < 2048; q += 256) {
      int cs = q & 7, col = (q >> 3) & 63, j = q >> 9;
      int gr = r0 - 1 + j;
      if (gr >= 0 && gr < 64) {
        const int4 v = *(const int4*)(Xb + (((size_t)n * 4096 + gr * 64 + col) << 7)
                                      + (half << 6) + (cs << 3));
        *(int4*)(Xs + (((j * 8 + cs) * 66 + col + 1) << 3)) = v;
      }
    }
    __syncthreads();
#pragma unroll
    for (int tap = 0; tap < 9; ++tap) {
      int kh = tap / 3, kw = tap - kh * 3;
#pragma unroll
      for (int ks = 0; ks < 4; ++ks) {
        bfrag af[2], bfv[2];
        const unsigned short* wf =
            Wt + ((((((tap * 2 + half) * 4 + ks) * 2 + cb) * 2) * 64) + lane) * 8;
        af[0] = *(const bfrag*)wf;
        af[1] = *(const bfrag*)(wf + 512);
        const unsigned short* xrow = Xs + ((((prow + kh) * 8 + (ks * 2 + lhi)) * 66 + kw) << 3);
#pragma unroll
        for (int u = 0; u < 2; ++u)
          bfv[u] = *(const bfrag*)(xrow + ((u * 32 + l31) << 3));
#pragma unroll
        for (int t2 = 0; t2 < 2; ++t2)
#pragma unroll
          for (int u = 0; u < 2; ++u)
            acc[t2 * 2 + u] = __builtin_amdgcn_mfma_f32_32x32x16_bf16(
                af[t2], bfv[u], acc[t2 * 2 + u], 0, 0, 0);
      }
    }
    __syncthreads();
  }

#pragma unroll
  for (int t2 = 0; t2 < 2; ++t2) {
#pragma unroll
    for (int u = 0; u < 2; ++u) {
      accv A = acc[t2 * 2 + u];
      int hw = (r0 + prow) * 64 + u * 32 + l31;
#pragma unroll
      for (int rr = 0; rr < 16; ++rr) {
        int co = cobase + t2 * 32 + (rr & 3) + ((rr >> 2) << 3) + (lhi << 2);
        float bias = (co < 64) ? br[co] : bi[co & 63];
        Cb[(((size_t)n * 128 + co) << 12) + hw] = f2b(A[rr] + bias);
      }
    }
  }
}

// -------- Kernel C: register-resident radix-4 FFT2 -> wspec -> iFFT2 -------
// (256,4): 4 blocks/CU (137 KB of the 160 KB LDS). The old (256,2) was a
// round-3 anti-spill hack; at 68 VGPR the 128-VGPR cap of 4 waves/EU is
// comfortable, and 2 blocks/CU left the shfl chains and the 160 MB blend
// stream latency-exposed (20% HBM at 30% occupancy).
__global__ __launch_bounds__(256, 4) void k_fft_blend(
    float* __restrict__ Xr, float* __restrict__ Xi,        // W0 out
    const unsigned short* __restrict__ Xc,                 // [slab][half][4096]
    const unsigned short* __restrict__ Cb,                 // cliff   [n][co][hw]
    const float* __restrict__ rr_, const float* __restrict__ ri_,
    const float* __restrict__ swr, const float* __restrict__ swi,
    const float2* __restrict__ Ps,                         // prepped (or null)
    const float* __restrict__ gate) {
  __shared__ __align__(16) float2 sc[64 * 66];   // 33,792 B, pitch 66
  __shared__ float2 tw[64];                      // W64^j = (cos,sin)(2*pi*j/64)
  int bid = xcd_swizzle(blockIdx.x, 2048);   // same-n ch-blocks share an XCD
  int ch = bid & 63;
  int n = bid >> 6;
  int base = bid << 12;
  int tid = threadIdx.x;
  int lane = tid & 63, wv = tid >> 6;
  int l15 = lane & 15;
  int p = lane >> 4;                    // 16-block residue class, in-wave
  int kap = ((p & 1) << 1) | (p >> 1);  // pi(p): 2-bit reverse
  bool pswap = (p & 1), prot = (p & 2);
  float sA = prot ? -1.f : 1.f;         // sign for xor32-style round
  float sB = pswap ? -1.f : 1.f;        // sign for xor16-style round
  int r = wv * 16 + l15;                // line index for x-passes
  int cy = r;                           // column index for y-passes (same map)

  if (tid < 64) {
    float sv, cv;
    __sincosf(0.09817477042468103f * (float)tid, &sv, &cv);  // 2*pi/64
    tw[tid] = make_float2(cv, sv);
  }

  float2 x[16];
  // ---- coalesced load from Xc: thread owns row r, cols 16p..16p+15 ----
  {
    const unsigned short* xp = Xc + ((size_t)bid << 13) + r * 64 + 16 * p;
    int4 ra = *(const int4*)xp;
    int4 rb = *(const int4*)(xp + 8);
    int4 ia = *(const int4*)(xp + 4096);
    int4 ib = *(const int4*)(xp + 4104);
    const unsigned short* rap = (const unsigned short*)&ra;
    const unsigned short* rbp = (const unsigned short*)&rb;
    const unsigned short* iap = (const unsigned short*)&ia;
    const unsigned short* ibp = (const unsigned short*)&ib;
#pragma unroll
    for (int j = 0; j < 8; ++j) {
      x[j]     = make_float2(b2f(rap[j]), b2f(iap[j]));
      x[8 + j] = make_float2(b2f(rbp[j]), b2f(ibp[j]));
    }
  }
  __syncthreads();   // tw table ready

  // =================== forward x (DIF: q16 shfl, q4, q1) ===================
#pragma unroll
  for (int j = 0; j < 16; ++j) {        // q=16 stage across p, then twiddle
    float2 mine = x[j];
    float2 pr = shfl_xor2(mine, 32);
    float2 t = make_float2(pr.x + sA * mine.x, pr.y + sA * mine.y);
    float2 pr2 = shfl_xor2(t, 16);
    float2 low = pswap ? pr2 : t;
    float2 high = pswap ? t : pr2;
    float2 u = prot ? make_float2(high.y, -high.x) : high;   // -i*high
    float2 o = make_float2(low.x + sB * u.x, low.y + sB * u.y);
    x[j] = c_mul_conj(o, tw[kap * j]);
  }
#pragma unroll
  for (int b = 0; b < 4; ++b) {         // q=4
    float2 t0 = c_add(x[b], x[b + 8]), t1 = c_sub(x[b], x[b + 8]);
    float2 t2 = c_add(x[b + 4], x[b + 12]), t3 = c_sub(x[b + 4], x[b + 12]);
    x[b] = c_add(t0, t2);
    float2 u1 = make_float2(t1.x + t3.y, t1.y - t3.x);
    float2 u2 = c_sub(t0, t2);
    float2 u3 = make_float2(t1.x - t3.y, t1.y + t3.x);
    x[b + 4] = c_mul_conj(u1, tw[4 * b]);
    x[b + 8] = c_mul_conj(u2, tw[8 * b]);
    x[b + 12] = c_mul_conj(u3, tw[12 * b]);
  }
#pragma unroll
  for (int a = 0; a < 4; ++a) {         // q=1 (no twiddles)
    int a4 = 4 * a;
    float2 t0 = c_add(x[a4], x[a4 + 2]), t1 = c_sub(x[a4], x[a4 + 2]);
    float2 t2 = c_add(x[a4 + 1], x[a4 + 3]), t3 = c_sub(x[a4 + 1], x[a4 + 3]);
    x[a4] = c_add(t0, t2);
    x[a4 + 1] = make_float2(t1.x + t3.y, t1.y - t3.x);
    x[a4 + 2] = c_sub(t0, t2);
    x[a4 + 3] = make_float2(t1.x - t3.y, t1.y + t3.x);
  }
  // write row r, cols 16*kap.. (ownership permuted by pi)
#pragma unroll
  for (int q = 0; q < 8; ++q) {
    float4 v = make_float4(x[2 * q].x, x[2 * q].y, x[2 * q + 1].x, x[2 * q + 1].y);
    *(float4*)&sc[r * 66 + 16 * kap + 2 * q] = v;
  }
  __syncthreads();

  // =================== forward y (read natural block p) ====================
#pragma unroll
  for (int j = 0; j < 16; ++j)
    x[j] = sc[(16 * p + j) * 66 + cy];
#pragma unroll
  for (int j = 0; j < 16; ++j) {        // q=16 (identical to fwd-x)
    float2 mine = x[j];
    float2 pr = shfl_xor2(mine, 32);
    float2 t = make_float2(pr.x + sA * mine.x, pr.y + sA * mine.y);
    float2 pr2 = shfl_xor2(t, 16);
    float2 low = pswap ? pr2 : t;
    float2 high = pswap ? t : pr2;
    float2 u = prot ? make_float2(high.y, -high.x) : high;
    float2 o = make_float2(low.x + sB * u.x, low.y + sB * u.y);
    x[j] = c_mul_conj(o, tw[kap * j]);
  }
#pragma unroll
  for (int b = 0; b < 4; ++b) {
    float2 t0 = c_add(x[b], x[b + 8]), t1 = c_sub(x[b], x[b + 8]);
    float2 t2 = c_add(x[b + 4], x[b + 12]), t3 = c_sub(x[b + 4], x[b + 12]);
    x[b] = c_add(t0, t2);
    float2 u1 = make_float2(t1.x + t3.y, t1.y - t3.x);
    float2 u2 = c_sub(t0, t2);
    float2 u3 = make_float2(t1.x - t3.y, t1.y + t3.x);
    x[b + 4] = c_mul_conj(u1, tw[4 * b]);
    x[b + 8] = c_mul_conj(u2, tw[8 * b]);
    x[b + 12] = c_mul_conj(u3, tw[12 * b]);
  }
#pragma unroll
  for (int a = 0; a < 4; ++a) {
    int a4 = 4 * a;
    float2 t0 = c_add(x[a4], x[a4 + 2]), t1 = c_sub(x[a4], x[a4 + 2]);
    float2 t2 = c_add(x[a4 + 1], x[a4 + 3]), t3 = c_sub(x[a4 + 1], x[a4 + 3]);
    x[a4] = c_add(t0, t2);
    x[a4 + 1] = make_float2(t1.x + t3.y, t1.y - t3.x);
    x[a4 + 2] = c_sub(t0, t2);
    x[a4 + 3] = make_float2(t1.x - t3.y, t1.y + t3.x);
  }

  // ============ spectral multiply in registers (digit-reversed) ============
  if (Ps) {
    const float2* pp = Ps + (((size_t)(ch * 4 + p) * 16) << 6) + r;
#pragma unroll
    for (int j = 0; j < 16; ++j) {
      float2 w = pp[j * 64];
      float2 v = x[j];
      x[j] = make_float2(v.x * w.x - v.y * w.y, v.x * w.y + v.y * w.x);
    }
  } else {
    int fb = ch * 4096 + rev4(cy);      // + fr*64
#pragma unroll
    for (int j = 0; j < 16; ++j) {
      int fr = ((j & 3) << 4) | (((j >> 2) & 3) << 2) | kap;
      float wr = swr[fb + fr * 64];
      float wi = swi[fb + fr * 64];
      float2 v = x[j];
      x[j] = make_float2(v.x * wr - v.y * wi, v.x * wi + v.y * wr);
    }
  }

  // ====== inverse y (DIT: q1, q4, pre-twiddle, q16 shfl; own blk=pi(p)) ====
#pragma unroll
  for (int a = 0; a < 4; ++a) {         // q=1
    int a4 = 4 * a;
    float2 e0 = c_add(x[a4], x[a4 + 2]), e1 = c_sub(x[a4], x[a4 + 2]);
    float2 o0 = c_add(x[a4 + 1], x[a4 + 3]), o1 = c_sub(x[a4 + 1], x[a4 + 3]);
    x[a4] = c_add(e0, o0);
    x[a4 + 1] = make_float2(e1.x - o1.y, e1.y + o1.x);
    x[a4 + 2] = c_sub(e0, o0);
    x[a4 + 3] = make_float2(e1.x + o1.y, e1.y - o1.x);
  }
#pragma unroll
  for (int b = 0; b < 4; ++b) {         // q=4
    float2 v1 = c_mul_pos(x[b + 4], tw[4 * b]);
    float2 v2 = c_mul_pos(x[b + 8], tw[8 * b]);
    float2 v3 = c_mul_pos(x[b + 12], tw[12 * b]);
    float2 e0 = c_add(x[b], v2), e1 = c_sub(x[b], v2);
    float2 o0 = c_add(v1, v3), o1 = c_sub(v1, v3);
    x[b] = c_add(e0, o0);
    x[b + 4] = make_float2(e1.x - o1.y, e1.y + o1.x);
    x[b + 8] = c_sub(e0, o0);
    x[b + 12] = make_float2(e1.x + o1.y, e1.y - o1.x);
  }
#pragma unroll
  for (int j = 0; j < 16; ++j) {        // q=16, v = pi(p) ownership
    float2 mine = c_mul_pos(x[j], tw[kap * j]);
    float2 pr = shfl_xor2(mine, 16);
    float2 t = make_float2(pr.x + sB * mine.x, pr.y + sB * mine.y);
    float2 pr2 = shfl_xor2(t, 32);
    float2 low = prot ? pr2 : t;
    float2 high = prot ? t : pr2;
    float2 u = pswap ? make_float2(-high.y, high.x) : high;  // +i*high
    x[j] = make_float2(low.x + sA * u.x, low.y + sA * u.y);
  }
  // write natural rows 16p+j at column cy
#pragma unroll
  for (int j = 0; j < 16; ++j)
    sc[(16 * p + j) * 66 + cy] = x[j];
  __syncthreads();

  // ====== inverse x (read natural block p; q1, q4, pre-twiddle, q16) =======
#pragma unroll
  for (int q = 0; q < 8; ++q) {
    float4 v = *(const float4*)&sc[r * 66 + 16 * p + 2 * q];
    x[2 * q] = make_float2(v.x, v.y);
    x[2 * q + 1] = make_float2(v.z, v.w);
  }
#pragma unroll
  for (int a = 0; a < 4; ++a) {
    int a4 = 4 * a;
    float2 e0 = c_add(x[a4], x[a4 + 2]), e1 = c_sub(x[a4], x[a4 + 2]);
    float2 o0 = c_add(x[a4 + 1], x[a4 + 3]), o1 = c_sub(x[a4 + 1], x[a4 + 3]);
    x[a4] = c_add(e0, o0);
    x[a4 + 1] = make_float2(e1.x - o1.y, e1.y + o1.x);
    x[a4 + 2] = c_sub(e0, o0);
    x[a4 + 3] = make_float2(e1.x + o1.y, e1.y - o1.x);
  }
#pragma unroll
  for (int b = 0; b < 4; ++b) {
    float2 v1 = c_mul_pos(x[b + 4], tw[4 * b]);
    float2 v2 = c_mul_pos(x[b + 8], tw[8 * b]);
    float2 v3 = c_mul_pos(x[b + 12], tw[12 * b]);
    float2 e0 = c_add(x[b], v2), e1 = c_sub(x[b], v2);
    float2 o0 = c_add(v1, v3), o1 = c_sub(v1, v3);
    x[b] = c_add(e0, o0);
    x[b + 4] = make_float2(e1.x - o1.y, e1.y + o1.x);
    x[b + 8] = c_sub(e0, o0);
    x[b + 12] = make_float2(e1.x + o1.y, e1.y - o1.x);
  }
#pragma unroll
  for (int j = 0; j < 16; ++j) {        // q=16, v = p ownership -> blk pi(p)
    float2 mine = c_mul_pos(x[j], tw[p * j]);
    float2 pr = shfl_xor2(mine, 32);
    float2 t = make_float2(pr.x + sA * mine.x, pr.y + sA * mine.y);
    float2 pr2 = shfl_xor2(t, 16);
    float2 low = pswap ? pr2 : t;
    float2 high = pswap ? t : pr2;
    float2 u = prot ? make_float2(-high.y, high.x) : high;   // +i*high
    x[j] = make_float2(low.x + sB * u.x, low.y + sB * u.y);
  }
  __syncthreads();   // everyone done reading sc from inv-y transpose

  // stage final values to LDS: element (r, 16*kap + j) <- x[j]
#pragma unroll
  for (int q = 0; q < 8; ++q) {
    float4 v = make_float4(x[2 * q].x, x[2 * q].y, x[2 * q + 1].x, x[2 * q + 1].y);
    *(float4*)&sc[r * 66 + 16 * kap + 2 * q] = v;
  }
  __syncthreads();

  // ---- fully-coalesced blend with cliff + resid, store ----
  float g = gate[0];
  const float scale = 1.f / 4096.f;
  for (int idx = tid; idx < 4096; idx += 256) {
    int rr2 = idx >> 6, cc2 = idx & 63;
    float2 sp = sc[rr2 * 66 + cc2];
    int a = base + idx;
    float cr = b2f(Cb[(((size_t)n * 128 + ch) << 12) + idx]);
    float ci = b2f(Cb[(((size_t)n * 128 + 64 + ch) << 12) + idx]);
    Xr[a] = g * cr + (1.f - g) * sp.x * scale + rr_[a];
    Xi[a] = g * ci + (1.f - g) * sp.y * scale + ri_[a];
  }
}

// -------- Kernel D: fused temporal (LN -> GEMM1 -> scan -> GEMM2 -> +res) --
// Xe padded to stride 129. Scan threads remapped px=tid&3/dp=tid>>2 so the
// per-t Asub b16 writes span 16 banks (was 4 -> 16-way conflict). LN pack
// remapped to c = k*8 + seg*2 so the packed dword writes land on bank
// tid&31 (conflict-free). Residual kept in registers.
__global__ __launch_bounds__(256, 3) void k_temporal_mfma(
    float* __restrict__ Xr, float* __restrict__ Xi,   // W0 in/out
    const float* __restrict__ dt,
    const float* __restrict__ lnw, const float* __restrict__ lnb,
    const float* __restrict__ lam_re, const float* __restrict__ lam_im,
    const unsigned short* __restrict__ Wt1, const unsigned short* __restrict__ Wt2) {
  __shared__ unsigned short Asub[16 * 64 * 8];    // 16 KB
  __shared__ float Xe[64 * 129];                  // 33,024 B (padded)
  int bid = xcd_swizzle(blockIdx.x, 2048);
  int b = bid >> 10, tile = bid & 1023;
  int hw0 = tile * 4;
  int tid = threadIdx.x;
  int lane = tid & 63, wv = tid >> 6;
  int l31 = lane & 31, lhi = lane >> 5;
  size_t xbase = (size_t)b * TT * DCH * HW + hw0;

  float4 res[8];
#pragma unroll
  for (int q = 0; q < 8; ++q) {
    int item = tid + q * 256;          // t*128 + c
    int t = item >> 7, c = item & 127;
    int d = c & 63;
    const float* src = ((c >> 6) ? Xi : Xr) + xbase + ((size_t)t * 64 + d) * HW;
    float4 v = *(const float4*)src;
    res[q] = v;                        // residual stays in registers
    Xe[(t * 4 + 0) * 129 + c] = v.x;
    Xe[(t * 4 + 1) * 129 + c] = v.y;
    Xe[(t * 4 + 2) * 129 + c] = v.z;
    Xe[(t * 4 + 3) * 129 + c] = v.w;
  }
  __syncthreads();

  {
    int row = tid >> 2, seg = tid & 3;
    float s = 0.f, s2 = 0.f;
#pragma unroll
    for (int j = 0; j < 32; ++j) {
      float v = Xe[row * 129 + seg * 32 + j];
      s += v; s2 += v * v;
    }
    s += __shfl_xor(s, 1); s2 += __shfl_xor(s2, 1);
    s += __shfl_xor(s, 2); s2 += __shfl_xor(s2, 2);
    float mu = s * (1.f / 128.f);
    float var = s2 * (1.f / 128.f) - mu * mu;
    float rs = rsqrtf(var + EPS);
    // pack c = k*8 + seg*2, k=0..15: write bank = tid&31 (conflict-free)
#pragma unroll
    for (int k = 0; k < 16; ++k) {
      int c = k * 8 + seg * 2;
      float v0 = (Xe[row * 129 + c] - mu) * rs * lnw[c] + lnb[c];
      float v1 = (Xe[row * 129 + c + 1] - mu) * rs * lnw[c + 1] + lnb[c + 1];
      unsigned pk = (unsigned)f2b(v0) | ((unsigned)f2b(v1) << 16);
      *(unsigned*)(Asub + (k * 64 + row) * 8 + seg * 2) = pk;
    }
  }
  __syncthreads();

  int mt = wv & 1, ntb = (wv >> 1) << 1;
  accv acc0 = accv{}, acc1 = accv{};
#pragma unroll
  for (int ks = 0; ks < 8; ++ks) {
    int kg = ks * 2 + lhi;
    bfrag a = *(const bfrag*)(Asub + (kg * 64 + mt * 32 + l31) * 8);
    bfrag b0 = *(const bfrag*)(Wt1 + (kg * 128 + ntb * 32 + l31) * 8);
    bfrag b1 = *(const bfrag*)(Wt1 + (kg * 128 + (ntb + 1) * 32 + l31) * 8);
    acc0 = __builtin_amdgcn_mfma_f32_32x32x16_bf16(a, b0, acc0, 0, 0, 0);
    acc1 = __builtin_amdgcn_mfma_f32_32x32x16_bf16(a, b1, acc1, 0, 0, 0);
  }
  __syncthreads();

#pragma unroll
  for (int rr = 0; rr < 16; ++rr) {
    int mrow = mt * 32 + (rr & 3) + ((rr >> 2) << 3) + (lhi << 2);
    Xe[mrow * 129 + ntb * 32 + l31] = acc0[rr];
    Xe[mrow * 129 + (ntb + 1) * 32 + l31] = acc1[rr];
  }
  __syncthreads();

  {
    int px = tid & 3, dp = tid >> 2;   // r varies per-lane -> 4-way writes
    float x0 = lam_re[dp];
    float nl = -(x0 > 15.f ? x0 : log1pf(__expf(x0)));
    float li = lam_im[dp];
    float hr = 0.f, hi = 0.f;
    int cR = dp, cI = 64 + dp;
    for (int t = 0; t < TT; ++t) {
      float dtv = dt[b * 16 + t];
      float ea = __expf(nl * dtv);
      float sv, cv; __sincosf(li * dtv, &sv, &cv);
      float evr = ea * cv, evi = ea * sv;
      int r = t * 4 + px;
      float xr_ = Xe[r * 129 + cR], xi_ = Xe[r * 129 + cI];
      float nhr = evr * hr - evi * hi + xr_;
      float nhi = evr * hi + evi * hr + xi_;
      hr = nhr; hi = nhi;
      Asub[((cR >> 3) * 64 + r) * 8 + (cR & 7)] = f2b(hr);
      Asub[((cI >> 3) * 64 + r) * 8 + (cI & 7)] = f2b(hi);
    }
  }
  __syncthreads();

  acc0 = accv{}; acc1 = accv{};
#pragma unroll
  for (int ks = 0; ks < 8; ++ks) {
    int kg = ks * 2 + lhi;
    bfrag a = *(const bfrag*)(Asub + (kg * 64 + mt * 32 + l31) * 8);
    bfrag b0 = *(const bfrag*)(Wt2 + (kg * 128 + ntb * 32 + l31) * 8);
    bfrag b1 = *(const bfrag*)(Wt2 + (kg * 128 + (ntb + 1) * 32 + l31) * 8);
    acc0 = __builtin_amdgcn_mfma_f32_32x32x16_bf16(a, b0, acc0, 0, 0, 0);
    acc1 = __builtin_amdgcn_mfma_f32_32x32x16_bf16(a, b1, acc1, 0, 0, 0);
  }
  __syncthreads();

#pragma unroll
  for (int rr = 0; rr < 16; ++rr) {
    int mrow = mt * 32 + (rr & 3) + ((rr >> 2) << 3) + (lhi << 2);
    Xe[mrow * 129 + ntb * 32 + l31] = acc0[rr];
    Xe[mrow * 129 + (ntb + 1) * 32 + l31] = acc1[rr];
  }
  __syncthreads();

#pragma unroll
  for (int q = 0; q < 8; ++q) {
    int item = tid + q * 256;
    int t = item >> 7, c = item & 127;
    int d = c & 63;
    float* dst = ((c >> 6) ? Xi : Xr) + xbase + ((size_t)t * 64 + d) * HW;
    float4 o;
    o.x = Xe[(t * 4 + 0) * 129 + c] + res[q].x;
    o.y = Xe[(t * 4 + 1) * 129 + c] + res[q].y;
    o.z = Xe[(t * 4 + 2) * 129 + c] + res[q].z;
    o.w = Xe[(t * 4 + 3) * 129 + c] + res[q].w;
    *(float4*)dst = o;
  }
}

// -------- Kernel E2: MFMA MLP with prepped weights (B from global) ---------
__global__ __launch_bounds__(256, 4) void k_mlp_pre(
    const float* __restrict__ Xr, const float* __restrict__ Xi,
    const float* __restrict__ lnw, const float* __restrict__ lnb,
    const unsigned short* __restrict__ Wm1,   // [2h][16kg][128n][8]
    const unsigned short* __restrict__ Wm2,   // [2kh][16kg][128n][8]
    const float* __restrict__ b1, const float* __restrict__ b2,
    float* __restrict__ out) {
  __shared__ __align__(16) unsigned char smem[32768];
  float* Xe = (float*)smem;                               // [128c][64m]
  unsigned short* Asub = (unsigned short*)smem;           // [16kg][64m][8]
  unsigned short* mid  = (unsigned short*)(smem + 16384); // [16kg][64m][8]
  unsigned short* ost  = (unsigned short*)smem;           // [128ng][66]
  int bid = blockIdx.x;
  int bt = bid >> 6, tile = bid & 63;
  int hw0 = tile << 6;
  int tid = threadIdx.x;
  int lane = tid & 63, wv = tid >> 6;
  int l31 = lane & 31, lhi = lane >> 5;
  size_t base = (size_t)bt * DCH * HW + hw0;   // + d*HW + m

#pragma unroll
  for (int q = 0; q < 8; ++q) {
    int item = q * 256 + tid;           // 2048 float4
    int m4 = item & 15, c = item >> 4;
    int d = c & 63;
    const float* src = ((c >> 6) ? Xi : Xr) + base + (size_t)d * HW + m4 * 4;
    *(float4*)(Xe + c * 64 + m4 * 4) = *(const float4*)src;
  }
  __syncthreads();                      // (1) Xe ready

  // LN: values held in registers across the in-place Asub overwrite
  {
    int row = tid >> 2, seg = tid & 3;
    float xv[32];
    float s = 0.f, s2 = 0.f;
#pragma unroll
    for (int j = 0; j < 32; ++j) {
      float v = Xe[(seg * 32 + j) * 64 + row];
      xv[j] = v; s += v; s2 += v * v;
    }
    s += __shfl_xor(s, 1); s2 += __shfl_xor(s2, 1);
    s += __shfl_xor(s, 2); s2 += __shfl_xor(s2, 2);
    float mu = s * (1.f / 128.f);
    float var = s2 * (1.f / 128.f) - mu * mu;
    float rs = rsqrtf(var + EPS);
    __syncthreads();                    // (2) all Xe reads done
#pragma unroll
    for (int j = 0; j < 32; ++j) {
      int c = seg * 32 + j;
      Asub[((c >> 3) * 64 + row) * 8 + (c & 7)] =
          f2b((xv[j] - mu) * rs * lnw[c] + lnb[c]);
    }
  }
  __syncthreads();                      // (3) Asub ready

  int ng = wv * 32 + l31;
  accv c0 = accv{}, c1 = accv{};
#pragma unroll
  for (int h = 0; h < 2; ++h) {
    accv g0 = accv{}, g1 = accv{};
#pragma unroll
    for (int ks = 0; ks < 8; ++ks) {
      int kg = ks * 2 + lhi;
      bfrag bfr = *(const bfrag*)(Wm1 + (((h * 16 + kg) * 128) + ng) * 8);
      bfrag a0 = *(const bfrag*)(Asub + (kg * 64 + l31) * 8);
      bfrag a1 = *(const bfrag*)(Asub + (kg * 64 + 32 + l31) * 8);
      g0 = __builtin_amdgcn_mfma_f32_32x32x16_bf16(a0, bfr, g0, 0, 0, 0);
      g1 = __builtin_amdgcn_mfma_f32_32x32x16_bf16(a1, bfr, g1, 0, 0, 0);
    }
    if (h == 1) __syncthreads();        // (5) G2-kh0 mid reads done
    float b1v = b1[h * 128 + ng];
    int kgl = ng >> 3, jj = ng & 7;
#pragma unroll
    for (int rr = 0; rr < 16; ++rr) {
      int mr = (rr & 3) + ((rr >> 2) << 3) + (lhi << 2);
      mid[(kgl * 64 + mr) * 8 + jj] = f2b(gelu_f(g0[rr] + b1v));
      mid[(kgl * 64 + 32 + mr) * 8 + jj] = f2b(gelu_f(g1[rr] + b1v));
    }
    __syncthreads();                    // (4)/(6) mid ready
#pragma unroll
    for (int ks = 0; ks < 8; ++ks) {
      int kg = ks * 2 + lhi;
      bfrag bfr = *(const bfrag*)(Wm2 + (((h * 16 + kg) * 128) + ng) * 8);
      bfrag a0 = *(const bfrag*)(mid + (kg * 64 + l31) * 8);
      bfrag a1 = *(const bfrag*)(mid + (kg * 64 + 32 + l31) * 8);
      c0 = __builtin_amdgcn_mfma_f32_32x32x16_bf16(a0, bfr, c0, 0, 0, 0);
      c1 = __builtin_amdgcn_mfma_f32_32x32x16_bf16(a1, bfr, c1, 0, 0, 0);
    }
  }
  __syncthreads();                      // (7) all mid reads done

  {
    float b2v = b2[ng];
#pragma unroll
    for (int rr = 0; rr < 16; ++rr) {
      int mr = (rr & 3) + ((rr >> 2) << 3) + (lhi << 2);
      ost[ng * 66 + mr] = f2b(c0[rr] + b2v);
      ost[ng * 66 + 32 + mr] = f2b(c1[rr] + b2v);
    }
  }
  __syncthreads();                      // (8) ostage ready
#pragma unroll
  for (int q = 0; q < 4; ++q) {
    int item = q * 256 + tid;          // 1024: (d, m4)
    int m4 = item & 15, d = item >> 4;
    size_t xa = base + (size_t)d * HW + m4 * 4;
    float4 xr4 = *(const float4*)(Xr + xa);
    float4 xi4 = *(const float4*)(Xi + xa);
    int m = m4 * 4;
    float r0 = b2f(ost[d * 66 + m]),     i0 = b2f(ost[(64 + d) * 66 + m]);
    float r1 = b2f(ost[d * 66 + m + 1]), i1 = b2f(ost[(64 + d) * 66 + m + 1]);
    float r2 = b2f(ost[d * 66 + m + 2]), i2 = b2f(ost[(64 + d) * 66 + m + 2]);
    float r3 = b2f(ost[d * 66 + m + 3]), i3 = b2f(ost[(64 + d) * 66 + m + 3]);
    float4 o1, o2;
    o1.x = r0 + xr4.x; o1.y = i0 + xi4.x; o1.z = r1 + xr4.y; o1.w = i1 + xi4.y;
    o2.x = r2 + xr4.z; o2.y = i2 + xi4.z; o2.z = r3 + xr4.w; o2.w = i3 + xi4.w;
    *(float4*)(out + xa * 2) = o1;
    *(float4*)(out + xa * 2 + 4) = o2;
  }
}

extern "C" void kernel_launch(void* const* d_in, const int* in_sizes, int n_in,
                              void* d_out, int out_size, void* d_ws, size_t ws_size,
                              hipStream_t stream) {
  const float* x_real  = (const float*)d_in[0];
  const float* x_imag  = (const float*)d_in[1];
  const float* dt      = (const float*)d_in[2];
  const float* ln_s_w  = (const float*)d_in[3];
  const float* ln_s_b  = (const float*)d_in[4];
  const float* ln_t_w  = (const float*)d_in[5];
  const float* ln_t_b  = (const float*)d_in[6];
  const float* ln_m_w  = (const float*)d_in[7];
  const float* ln_m_b  = (const float*)d_in[8];
  const float* cw_r    = (const float*)d_in[9];
  const float* cw_i    = (const float*)d_in[10];
  const float* cb_r    = (const float*)d_in[11];
  const float* cb_i    = (const float*)d_in[12];
  const float* spec_wr = (const float*)d_in[13];
  const float* spec_wi = (const float*)d_in[14];
  const float* gate    = (const float*)d_in[15];
  const float* lam_re  = (const float*)d_in[16];
  const float* lam_im  = (const float*)d_in[17];
  const float* V_re    = (const float*)d_in[18];
  const float* V_im    = (const float*)d_in[19];
  const float* Vinv_re = (const float*)d_in[20];
  const float* Vinv_im = (const float*)d_in[21];
  const float* mlp_w1  = (const float*)d_in[22];
  const float* mlp_b1  = (const float*)d_in[23];
  const float* mlp_w2  = (const float*)d_in[24];
  const float* mlp_b2  = (const float*)d_in[25];

  float* out = (float*)d_out;
  unsigned short* Xb = (unsigned short*)d_out;
  unsigned short* Cb = Xb + (size_t)2 * NELEM;
  unsigned short* Wt1 = Xb;
  unsigned short* Wt2 = Xb + 16384;
  float* W0r = (float*)d_ws;
  float* W0i = W0r + NELEM;
  unsigned short* Wt = (unsigned short*)d_ws;
  // Xc (channel-major ln-out for the FFT) overlays W0i: each fft block reads
  // its Xc slab fully into registers before any of its W0i writes, and slabs
  // are block-disjoint with identical index <-> byte-range mapping.
  unsigned short* Xc = (unsigned short*)W0i;
  // MLP bf16 weights live past the 64 MB W0 region (ws_size-guarded; verified
  // large enough in rounds 6-10).
  size_t ws_used = (size_t)2 * NELEM * 4;
  unsigned short* Wm = (unsigned short*)((char*)d_ws + ws_used);
  // Spectral weight pre-gather (2 MB) past Wm, only if workspace permits.
  size_t ps_off = ws_used + 131072;
  bool sprep = ws_size >= ps_off + (size_t)262144 * 8;
  float2* Ps = sprep ? (float2*)((char*)d_ws + ps_off) : (float2*)nullptr;

  k_wprep<<<576, 256, 0, stream>>>(cw_r, cw_i, Wt);
  k_mprep<<<256, 256, 0, stream>>>(mlp_w1, mlp_w2, Wm);
  if (sprep) k_sprep<<<1024, 256, 0, stream>>>(spec_wr, spec_wi, Ps);
  k_ln_spatial<<<512, 256, 0, stream>>>(x_real, x_imag, ln_s_w, ln_s_b, Xb);
  k_xpose<<<1024, 256, 0, stream>>>(Xb, Xc);
  k_conv_mfma<<<1024, 256, 0, stream>>>(Xb, Wt, cb_r, cb_i, Cb);
  k_fft_blend<<<2048, 256, 0, stream>>>(W0r, W0i, Xc, Cb, x_real, x_imag,
                                        spec_wr, spec_wi, Ps, gate);
  k_vprep<<<64, 256, 0, stream>>>(V_re, V_im, Vinv_re, Vinv_im, Wt1, Wt2);
  k_temporal_mfma<<<2048, 256, 0, stream>>>(W0r, W0i, dt, ln_t_w, ln_t_b,
                                            lam_re, lam_im, Wt1, Wt2);
  k_mlp_pre<<<2048, 256, 0, stream>>>(W0r, W0i, ln_m_w, ln_m_b,
                                      Wm, Wm + 32768, mlp_b1, mlp_b2, out);
}

// Round 12
// 466.987 us; speedup vs baseline: 1.0655x; 1.0457x over previous
//
#include <hip/hip_runtime.h>
#include <math.h>

#define NELEM 8388608   // B*T*D*H*W = 2*16*64*64*64
#define HW    4096
#define DCH   64
#define TT    16
#define EPS   1e-5f

typedef __attribute__((ext_vector_type(8))) short bfrag;   // 8 bf16 = 4 VGPRs
typedef __attribute__((ext_vector_type(16))) float accv;   // 16 fp32 acc

__device__ __forceinline__ unsigned short f2b(float f) {
  union { float f; unsigned u; } v; v.f = f;
  unsigned r = (v.u + 0x7FFF + ((v.u >> 16) & 1)) >> 16;
  return (unsigned short)r;
}
__device__ __forceinline__ float b2f(unsigned short h) {
  union { unsigned u; float f; } v; v.u = ((unsigned)h) << 16;
  return v.f;
}
// base-4 digit reversal of a 6-bit index (3 digits)
__device__ __forceinline__ int rev4(int x) {
  return ((x & 3) << 4) | (x & 12) | ((x >> 4) & 3);
}
// XCD-locality swizzle: put consecutive logical tiles on the SAME XCD
// (dispatch is round-robin bid%8 -> XCD). NB must be divisible by 8.
__device__ __forceinline__ int xcd_swizzle(int bid, int nb) {
  return (bid & 7) * (nb >> 3) + (bid >> 3);
}

__device__ __forceinline__ float2 c_add(float2 a, float2 b) {
  return make_float2(a.x + b.x, a.y + b.y);
}
__device__ __forceinline__ float2 c_sub(float2 a, float2 b) {
  return make_float2(a.x - b.x, a.y - b.y);
}
// a * (w.x - i w.y)   [forward twiddle]
__device__ __forceinline__ float2 c_mul_conj(float2 a, float2 w) {
  return make_float2(a.x * w.x + a.y * w.y, a.y * w.x - a.x * w.y);
}
// a * (w.x + i w.y)   [inverse twiddle]
__device__ __forceinline__ float2 c_mul_pos(float2 a, float2 w) {
  return make_float2(a.x * w.x - a.y * w.y, a.y * w.x + a.x * w.y);
}
__device__ __forceinline__ float2 shfl_xor2(float2 v, int m) {
  return make_float2(__shfl_xor(v.x, m), __shfl_xor(v.y, m));
}
// tanh-form GELU: x*sigmoid(1.5958(x+0.044715x^3)); |err vs erf-gelu| < 1e-3,
// below bf16 rounding of the downstream f2b.
__device__ __forceinline__ float gelu_f(float v) {
  float y = -1.595769122f * (v + 0.044715f * v * v * v);
  return v * __builtin_amdgcn_rcpf(1.f + __expf(y));
}

// -------- Kernel W: weight prep -> MFMA-fragment order -----
// Wf[tap][half][ks][cb][t2][lane=lhi*32+l31][j]: the conv wave's A-fragment
// load becomes lane-consecutive 16 B (one coalesced 1 KB burst).
__global__ __launch_bounds__(256) void k_wprep(
    const float* __restrict__ cwr, const float* __restrict__ cwi,
    unsigned short* __restrict__ Wt) {
  int gid = blockIdx.x * 256 + threadIdx.x;
  if (gid >= 9 * 128 * 128) return;
  int j = gid & 7;
  int lane = (gid >> 3) & 63;
  int t2 = (gid >> 9) & 1;
  int cb = (gid >> 10) & 1;
  int ks = (gid >> 11) & 3;
  int half = (gid >> 13) & 1;
  int tap = gid >> 14;
  int l31 = lane & 31, lhi = lane >> 5;
  int co = cb * 64 + t2 * 32 + l31;
  int c = half * 64 + ks * 16 + lhi * 8 + j;
  int kh = tap / 3, kw = tap - kh * 3;
  int dout = co & 63, cin = c & 63;
  int widx = ((dout * 64 + cin) * 3 + kh) * 3 + kw;
  float v;
  if (co < 64) v = (c < 64) ? cwr[widx] : -cwi[widx];
  else         v = (c < 64) ? cwi[widx] :  cwr[widx];
  Wt[gid] = f2b(v);
}

// ------- Kernel V: temporal GEMM weights, MFMA-B layout [kg=16][n=128][8] --
__global__ __launch_bounds__(256) void k_vprep(
    const float* __restrict__ Vre, const float* __restrict__ Vim,
    const float* __restrict__ Vire, const float* __restrict__ Viim,
    unsigned short* __restrict__ Wt1, unsigned short* __restrict__ Wt2) {
  int gid = blockIdx.x * 256 + threadIdx.x;   // 0..16383
  int j = gid & 7, n = (gid >> 3) & 127, kg = gid >> 10;
  int k = kg * 8 + j;
  int d = k & 63, dp = n & 63;
  float v1, v2;
  if (k < 64) {
    v1 = (n < 64) ? Vire[dp * 64 + d] : Viim[dp * 64 + d];
    v2 = (n < 64) ? Vre[dp * 64 + d] : Vim[dp * 64 + d];
  } else {
    v1 = (n < 64) ? -Viim[dp * 64 + d] : Vire[dp * 64 + d];
    v2 = (n < 64) ? -Vim[dp * 64 + d] : Vre[dp * 64 + d];
  }
  Wt1[gid] = f2b(v1); Wt2[gid] = f2b(v2);
}

// ------- Kernel M: MLP weight prep -> Wm1[2h][16kg][128n][8], Wm2 same -----
__global__ __launch_bounds__(256) void k_mprep(
    const float* __restrict__ w1, const float* __restrict__ w2,
    unsigned short* __restrict__ Wm) {
  int gid = blockIdx.x * 256 + threadIdx.x;  // 0..65535
  int j = gid & 7, n = (gid >> 3) & 127, kgh = (gid >> 10) & 31;
  int hh = kgh >> 4, kg = kgh & 15;
  float v;
  if (gid < 32768) v = w1[(kg * 8 + j) * 256 + hh * 128 + n];
  else             v = w2[(hh * 128 + kg * 8 + j) * 128 + n];
  Wm[gid] = f2b(v);
}

// ------- Kernel S: spectral weight pre-gather into fft consumption order ---
// Ps[((ch*4 + p)*16 + j)*64 + cy] = (swr,swi)[ch*4096 + fr(j,kap(p))*64 +
// rev4(cy)]. Turns the fft's 64 scattered 4-B gathers/thread into 16 loads
// in 128-B lane-contiguous segments.
__global__ __launch_bounds__(256) void k_sprep(
    const float* __restrict__ swr, const float* __restrict__ swi,
    float2* __restrict__ Ps) {
  int gid = blockIdx.x * 256 + threadIdx.x;   // 0..262143
  int cy = gid & 63, j = (gid >> 6) & 15, p = (gid >> 10) & 3, ch = gid >> 12;
  int kap = ((p & 1) << 1) | (p >> 1);
  int fr = ((j & 3) << 4) | (((j >> 2) & 3) << 2) | kap;
  int addr = ch * 4096 + fr * 64 + rev4(cy);
  Ps[gid] = make_float2(swr[addr], swi[addr]);
}

// ---------------- Kernel A: spatial LN -> Xb[n][hw][c=128] bf16 ------------
__global__ __launch_bounds__(256) void k_ln_spatial(
    const float* __restrict__ xr, const float* __restrict__ xi,
    const float* __restrict__ w, const float* __restrict__ b,
    unsigned short* __restrict__ Xb) {
  int gid = blockIdx.x * 256 + threadIdx.x;   // 0..131071 = BT*HW
  int bt = gid >> 12;
  int hw = gid & 4095;
  size_t base = (size_t)bt * DCH * HW + hw;
  float vr[DCH], vi[DCH];
  float s = 0.f, s2 = 0.f;
#pragma unroll
  for (int d = 0; d < DCH; ++d) {
    float a = xr[base + d * HW];
    float c = xi[base + d * HW];
    vr[d] = a; vi[d] = c;
    s += a + c;
    s2 += a * a + c * c;
  }
  float mu = s * (1.f / 128.f);
  float var = s2 * (1.f / 128.f) - mu * mu;
  float rs = rsqrtf(var + EPS);
  unsigned short* dst = Xb + ((size_t)gid << 7);
#pragma unroll
  for (int k = 0; k < 8; ++k) {
    int4 o;
    unsigned short* op = (unsigned short*)&o;
#pragma unroll
    for (int j = 0; j < 8; ++j) {
      int d = k * 8 + j;
      op[j] = f2b((vr[d] - mu) * rs * w[d] + b[d]);
    }
    ((int4*)dst)[k] = o;
  }
#pragma unroll
  for (int k = 0; k < 8; ++k) {
    int4 o;
    unsigned short* op = (unsigned short*)&o;
#pragma unroll
    for (int j = 0; j < 8; ++j) {
      int d = k * 8 + j;
      op[j] = f2b((vi[d] - mu) * rs * w[64 + d] + b[64 + d]);
    }
    ((int4*)(dst + 64))[k] = o;
  }
}

// ------- Kernel X: transpose ln-out to channel-major for the FFT -----------
__global__ __launch_bounds__(256) void k_xpose(
    const unsigned short* __restrict__ Xb,   // [n][hw][c=128]
    unsigned short* __restrict__ Xc) {
  int bid = xcd_swizzle(blockIdx.x, 1024);   // same-n blocks share an XCD
  int n = bid >> 5, chp = bid & 31;          // channels chp*2, chp*2+1
  int tid = threadIdx.x;
  const unsigned short* src = Xb + (((size_t)n * 4096) << 7) + (chp << 1);
  size_t dst0 = (((size_t)n * 64 + chp * 2) << 13);   // slab * 8192 shorts
#pragma unroll
  for (int half = 0; half < 2; ++half) {
    union { unsigned short u[16]; int4 v[2]; } a0, a1;
#pragma unroll
    for (int m = 0; m < 16; ++m) {
      int hw = tid * 16 + m;
      unsigned vv = *(const unsigned*)(src + ((size_t)hw << 7) + (half << 6));
      a0.u[m] = (unsigned short)(vv & 0xffffu);
      a1.u[m] = (unsigned short)(vv >> 16);
    }
    *(int4*)(Xc + dst0 + (half << 12) + tid * 16)            = a0.v[0];
    *(int4*)(Xc + dst0 + (half << 12) + tid * 16 + 8)        = a0.v[1];
    *(int4*)(Xc + dst0 + 8192 + (half << 12) + tid * 16)     = a1.v[0];
    *(int4*)(Xc + dst0 + 8192 + (half << 12) + tid * 16 + 8) = a1.v[1];
  }
}

// ---------------- Kernel B: implicit-GEMM MFMA conv ------------------------
__global__ __launch_bounds__(256, 4) void k_conv_mfma(
    const unsigned short* __restrict__ Xb,   // [n][hw][c=128]
    const unsigned short* __restrict__ Wt,   // fragment-ordered (see k_wprep)
    const float* __restrict__ br, const float* __restrict__ bi,
    unsigned short* __restrict__ Cb) {       // [n][co=128][hw]
  __shared__ unsigned short Xs[4 * 8 * 66 * 8];   // 33,792 B
  int bid = xcd_swizzle(blockIdx.x, 1024);   // same-n blocks share an XCD
  int rg = bid & 31, n = bid >> 5;
  int r0 = rg << 1;
  int tid = threadIdx.x;
  int lane = tid & 63, wv = tid >> 6;
  int l31 = lane & 31, lhi = lane >> 5;
  int cb = wv >> 1;
  int cobase = cb << 6;
  int prow = wv & 1;

  accv acc[4] = {accv{}, accv{}, accv{}, accv{}};

  for (int q = tid; q < 2112; q += 256)
    ((int4*)Xs)[q] = make_int4(0, 0, 0, 0);
  __syncthreads();

  for (int half = 0; half < 2; ++half) {
    for (int q = tid; q < 2048; q += 256) {
      int cs = q & 7, col = (q >> 3) & 63, j = q >> 9;
      int gr = r0 - 1 + j;
      if (gr >= 0 && gr < 64) {
        const int4 v = *(const int4*)(Xb + (((size_t)n * 4096 + gr * 64 + col) << 7)
                                      + (half << 6) + (cs << 3));
        *(int4*)(Xs + (((j * 8 + cs) * 66 + col + 1) << 3)) = v;
      }
    }
    __syncthreads();
#pragma unroll
    for (int tap = 0; tap < 9; ++tap) {
      int kh = tap / 3, kw = tap - kh * 3;
#pragma unroll
      for (int ks = 0; ks < 4; ++ks) {
        bfrag af[2], bfv[2];
        const unsigned short* wf =
            Wt + ((((((tap * 2 + half) * 4 + ks) * 2 + cb) * 2) * 64) + lane) * 8;
        af[0] = *(const bfrag*)wf;
        af[1] = *(const bfrag*)(wf + 512);
        const unsigned short* xrow = Xs + ((((prow + kh) * 8 + (ks * 2 + lhi)) * 66 + kw) << 3);
#pragma unroll
        for (int u = 0; u < 2; ++u)
          bfv[u] = *(const bfrag*)(xrow + ((u * 32 + l31) << 3));
#pragma unroll
        for (int t2 = 0; t2 < 2; ++t2)
#pragma unroll
          for (int u = 0; u < 2; ++u)
            acc[t2 * 2 + u] = __builtin_amdgcn_mfma_f32_32x32x16_bf16(
                af[t2], bfv[u], acc[t2 * 2 + u], 0, 0, 0);
      }
    }
    __syncthreads();
  }

#pragma unroll
  for (int t2 = 0; t2 < 2; ++t2) {
#pragma unroll
    for (int u = 0; u < 2; ++u) {
      accv A = acc[t2 * 2 + u];
      int hw = (r0 + prow) * 64 + u * 32 + l31;
#pragma unroll
      for (int rr = 0; rr < 16; ++rr) {
        int co = cobase + t2 * 32 + (rr & 3) + ((rr >> 2) << 3) + (lhi << 2);
        float bias = (co < 64) ? br[co] : bi[co & 63];
        Cb[(((size_t)n * 128 + co) << 12) + hw] = f2b(A[rr] + bias);
      }
    }
  }
}

// -------- Kernel C: register-resident radix-4 FFT2 -> wspec -> iFFT2 -------
// Plain (256): no min-waves hint. (256,2) starved occupancy at 2 blocks/CU;
// (256,4) made the allocator squeeze to 64 VGPR and spill 32 B/thread
// (round-11 WRITE_SIZE +16 MB). Unconstrained, the kernel's natural ~72-90
// VGPR still allows >=4 waves/SIMD and occupancy is LDS-bound at 4 blocks/CU
// (137 of 160 KB) -- round-11's occupancy without its spill.
__global__ __launch_bounds__(256) void k_fft_blend(
    float* __restrict__ Xr, float* __restrict__ Xi,        // W0 out
    const unsigned short* __restrict__ Xc,                 // [slab][half][4096]
    const unsigned short* __restrict__ Cb,                 // cliff   [n][co][hw]
    const float* __restrict__ rr_, const float* __restrict__ ri_,
    const float* __restrict__ swr, const float* __restrict__ swi,
    const float2* __restrict__ Ps,                         // prepped (or null)
    const float* __restrict__ gate) {
  __shared__ __align__(16) float2 sc[64 * 66];   // 33,792 B, pitch 66
  __shared__ float2 tw[64];                      // W64^j = (cos,sin)(2*pi*j/64)
  int bid = xcd_swizzle(blockIdx.x, 2048);   // same-n ch-blocks share an XCD
  int ch = bid & 63;
  int n = bid >> 6;
  int base = bid << 12;
  int tid = threadIdx.x;
  int lane = tid & 63, wv = tid >> 6;
  int l15 = lane & 15;
  int p = lane >> 4;                    // 16-block residue class, in-wave
  int kap = ((p & 1) << 1) | (p >> 1);  // pi(p): 2-bit reverse
  bool pswap = (p & 1), prot = (p & 2);
  float sA = prot ? -1.f : 1.f;         // sign for xor32-style round
  float sB = pswap ? -1.f : 1.f;        // sign for xor16-style round
  int r = wv * 16 + l15;                // line index for x-passes
  int cy = r;                           // column index for y-passes (same map)

  if (tid < 64) {
    float sv, cv;
    __sincosf(0.09817477042468103f * (float)tid, &sv, &cv);  // 2*pi/64
    tw[tid] = make_float2(cv, sv);
  }

  float2 x[16];
  // ---- coalesced load from Xc: thread owns row r, cols 16p..16p+15 ----
  {
    const unsigned short* xp = Xc + ((size_t)bid << 13) + r * 64 + 16 * p;
    int4 ra = *(const int4*)xp;
    int4 rb = *(const int4*)(xp + 8);
    int4 ia = *(const int4*)(xp + 4096);
    int4 ib = *(const int4*)(xp + 4104);
    const unsigned short* rap = (const unsigned short*)&ra;
    const unsigned short* rbp = (const unsigned short*)&rb;
    const unsigned short* iap = (const unsigned short*)&ia;
    const unsigned short* ibp = (const unsigned short*)&ib;
#pragma unroll
    for (int j = 0; j < 8; ++j) {
      x[j]     = make_float2(b2f(rap[j]), b2f(iap[j]));
      x[8 + j] = make_float2(b2f(rbp[j]), b2f(ibp[j]));
    }
  }
  __syncthreads();   // tw table ready

  // =================== forward x (DIF: q16 shfl, q4, q1) ===================
#pragma unroll
  for (int j = 0; j < 16; ++j) {        // q=16 stage across p, then twiddle
    float2 mine = x[j];
    float2 pr = shfl_xor2(mine, 32);
    float2 t = make_float2(pr.x + sA * mine.x, pr.y + sA * mine.y);
    float2 pr2 = shfl_xor2(t, 16);
    float2 low = pswap ? pr2 : t;
    float2 high = pswap ? t : pr2;
    float2 u = prot ? make_float2(high.y, -high.x) : high;   // -i*high
    float2 o = make_float2(low.x + sB * u.x, low.y + sB * u.y);
    x[j] = c_mul_conj(o, tw[kap * j]);
  }
#pragma unroll
  for (int b = 0; b < 4; ++b) {         // q=4
    float2 t0 = c_add(x[b], x[b + 8]), t1 = c_sub(x[b], x[b + 8]);
    float2 t2 = c_add(x[b + 4], x[b + 12]), t3 = c_sub(x[b + 4], x[b + 12]);
    x[b] = c_add(t0, t2);
    float2 u1 = make_float2(t1.x + t3.y, t1.y - t3.x);
    float2 u2 = c_sub(t0, t2);
    float2 u3 = make_float2(t1.x - t3.y, t1.y + t3.x);
    x[b + 4] = c_mul_conj(u1, tw[4 * b]);
    x[b + 8] = c_mul_conj(u2, tw[8 * b]);
    x[b + 12] = c_mul_conj(u3, tw[12 * b]);
  }
#pragma unroll
  for (int a = 0; a < 4; ++a) {         // q=1 (no twiddles)
    int a4 = 4 * a;
    float2 t0 = c_add(x[a4], x[a4 + 2]), t1 = c_sub(x[a4], x[a4 + 2]);
    float2 t2 = c_add(x[a4 + 1], x[a4 + 3]), t3 = c_sub(x[a4 + 1], x[a4 + 3]);
    x[a4] = c_add(t0, t2);
    x[a4 + 1] = make_float2(t1.x + t3.y, t1.y - t3.x);
    x[a4 + 2] = c_sub(t0, t2);
    x[a4 + 3] = make_float2(t1.x - t3.y, t1.y + t3.x);
  }
  // write row r, cols 16*kap.. (ownership permuted by pi)
#pragma unroll
  for (int q = 0; q < 8; ++q) {
    float4 v = make_float4(x[2 * q].x, x[2 * q].y, x[2 * q + 1].x, x[2 * q + 1].y);
    *(float4*)&sc[r * 66 + 16 * kap + 2 * q] = v;
  }
  __syncthreads();

  // =================== forward y (read natural block p) ====================
#pragma unroll
  for (int j = 0; j < 16; ++j)
    x[j] = sc[(16 * p + j) * 66 + cy];
#pragma unroll
  for (int j = 0; j < 16; ++j) {        // q=16 (identical to fwd-x)
    float2 mine = x[j];
    float2 pr = shfl_xor2(mine, 32);
    float2 t = make_float2(pr.x + sA * mine.x, pr.y + sA * mine.y);
    float2 pr2 = shfl_xor2(t, 16);
    float2 low = pswap ? pr2 : t;
    float2 high = pswap ? t : pr2;
    float2 u = prot ? make_float2(high.y, -high.x) : high;
    float2 o = make_float2(low.x + sB * u.x, low.y + sB * u.y);
    x[j] = c_mul_conj(o, tw[kap * j]);
  }
#pragma unroll
  for (int b = 0; b < 4; ++b) {
    float2 t0 = c_add(x[b], x[b + 8]), t1 = c_sub(x[b], x[b + 8]);
    float2 t2 = c_add(x[b + 4], x[b + 12]), t3 = c_sub(x[b + 4], x[b + 12]);
    x[b] = c_add(t0, t2);
    float2 u1 = make_float2(t1.x + t3.y, t1.y - t3.x);
    float2 u2 = c_sub(t0, t2);
    float2 u3 = make_float2(t1.x - t3.y, t1.y + t3.x);
    x[b + 4] = c_mul_conj(u1, tw[4 * b]);
    x[b + 8] = c_mul_conj(u2, tw[8 * b]);
    x[b + 12] = c_mul_conj(u3, tw[12 * b]);
  }
#pragma unroll
  for (int a = 0; a < 4; ++a) {
    int a4 = 4 * a;
    float2 t0 = c_add(x[a4], x[a4 + 2]), t1 = c_sub(x[a4], x[a4 + 2]);
    float2 t2 = c_add(x[a4 + 1], x[a4 + 3]), t3 = c_sub(x[a4 + 1], x[a4 + 3]);
    x[a4] = c_add(t0, t2);
    x[a4 + 1] = make_float2(t1.x + t3.y, t1.y - t3.x);
    x[a4 + 2] = c_sub(t0, t2);
    x[a4 + 3] = make_float2(t1.x - t3.y, t1.y + t3.x);
  }

  // ============ spectral multiply in registers (digit-reversed) ============
  if (Ps) {
    const float2* pp = Ps + (((size_t)(ch * 4 + p) * 16) << 6) + r;
#pragma unroll
    for (int j = 0; j < 16; ++j) {
      float2 w = pp[j * 64];
      float2 v = x[j];
      x[j] = make_float2(v.x * w.x - v.y * w.y, v.x * w.y + v.y * w.x);
    }
  } else {
    int fb = ch * 4096 + rev4(cy);      // + fr*64
#pragma unroll
    for (int j = 0; j < 16; ++j) {
      int fr = ((j & 3) << 4) | (((j >> 2) & 3) << 2) | kap;
      float wr = swr[fb + fr * 64];
      float wi = swi[fb + fr * 64];
      float2 v = x[j];
      x[j] = make_float2(v.x * wr - v.y * wi, v.x * wi + v.y * wr);
    }
  }

  // ====== inverse y (DIT: q1, q4, pre-twiddle, q16 shfl; own blk=pi(p)) ====
#pragma unroll
  for (int a = 0; a < 4; ++a) {         // q=1
    int a4 = 4 * a;
    float2 e0 = c_add(x[a4], x[a4 + 2]), e1 = c_sub(x[a4], x[a4 + 2]);
    float2 o0 = c_add(x[a4 + 1], x[a4 + 3]), o1 = c_sub(x[a4 + 1], x[a4 + 3]);
    x[a4] = c_add(e0, o0);
    x[a4 + 1] = make_float2(e1.x - o1.y, e1.y + o1.x);
    x[a4 + 2] = c_sub(e0, o0);
    x[a4 + 3] = make_float2(e1.x + o1.y, e1.y - o1.x);
  }
#pragma unroll
  for (int b = 0; b < 4; ++b) {         // q=4
    float2 v1 = c_mul_pos(x[b + 4], tw[4 * b]);
    float2 v2 = c_mul_pos(x[b + 8], tw[8 * b]);
    float2 v3 = c_mul_pos(x[b + 12], tw[12 * b]);
    float2 e0 = c_add(x[b], v2), e1 = c_sub(x[b], v2);
    float2 o0 = c_add(v1, v3), o1 = c_sub(v1, v3);
    x[b] = c_add(e0, o0);
    x[b + 4] = make_float2(e1.x - o1.y, e1.y + o1.x);
    x[b + 8] = c_sub(e0, o0);
    x[b + 12] = make_float2(e1.x + o1.y, e1.y - o1.x);
  }
#pragma unroll
  for (int j = 0; j < 16; ++j) {        // q=16, v = pi(p) ownership
    float2 mine = c_mul_pos(x[j], tw[kap * j]);
    float2 pr = shfl_xor2(mine, 16);
    float2 t = make_float2(pr.x + sB * mine.x, pr.y + sB * mine.y);
    float2 pr2 = shfl_xor2(t, 32);
    float2 low = prot ? pr2 : t;
    float2 high = prot ? t : pr2;
    float2 u = pswap ? make_float2(-high.y, high.x) : high;  // +i*high
    x[j] = make_float2(low.x + sA * u.x, low.y + sA * u.y);
  }
  // write natural rows 16p+j at column cy
#pragma unroll
  for (int j = 0; j < 16; ++j)
    sc[(16 * p + j) * 66 + cy] = x[j];
  __syncthreads();

  // ====== inverse x (read natural block p; q1, q4, pre-twiddle, q16) =======
#pragma unroll
  for (int q = 0; q < 8; ++q) {
    float4 v = *(const float4*)&sc[r * 66 + 16 * p + 2 * q];
    x[2 * q] = make_float2(v.x, v.y);
    x[2 * q + 1] = make_float2(v.z, v.w);
  }
#pragma unroll
  for (int a = 0; a < 4; ++a) {
    int a4 = 4 * a;
    float2 e0 = c_add(x[a4], x[a4 + 2]), e1 = c_sub(x[a4], x[a4 + 2]);
    float2 o0 = c_add(x[a4 + 1], x[a4 + 3]), o1 = c_sub(x[a4 + 1], x[a4 + 3]);
    x[a4] = c_add(e0, o0);
    x[a4 + 1] = make_float2(e1.x - o1.y, e1.y + o1.x);
    x[a4 + 2] = c_sub(e0, o0);
    x[a4 + 3] = make_float2(e1.x + o1.y, e1.y - o1.x);
  }
#pragma unroll
  for (int b = 0; b < 4; ++b) {
    float2 v1 = c_mul_pos(x[b + 4], tw[4 * b]);
    float2 v2 = c_mul_pos(x[b + 8], tw[8 * b]);
    float2 v3 = c_mul_pos(x[b + 12], tw[12 * b]);
    float2 e0 = c_add(x[b], v2), e1 = c_sub(x[b], v2);
    float2 o0 = c_add(v1, v3), o1 = c_sub(v1, v3);
    x[b] = c_add(e0, o0);
    x[b + 4] = make_float2(e1.x - o1.y, e1.y + o1.x);
    x[b + 8] = c_sub(e0, o0);
    x[b + 12] = make_float2(e1.x + o1.y, e1.y - o1.x);
  }
#pragma unroll
  for (int j = 0; j < 16; ++j) {        // q=16, v = p ownership -> blk pi(p)
    float2 mine = c_mul_pos(x[j], tw[p * j]);
    float2 pr = shfl_xor2(mine, 32);
    float2 t = make_float2(pr.x + sA * mine.x, pr.y + sA * mine.y);
    float2 pr2 = shfl_xor2(t, 16);
    float2 low = pswap ? pr2 : t;
    float2 high = pswap ? t : pr2;
    float2 u = prot ? make_float2(-high.y, high.x) : high;   // +i*high
    x[j] = make_float2(low.x + sB * u.x, low.y + sB * u.y);
  }
  __syncthreads();   // everyone done reading sc from inv-y transpose

  // stage final values to LDS: element (r, 16*kap + j) <- x[j]
#pragma unroll
  for (int q = 0; q < 8; ++q) {
    float4 v = make_float4(x[2 * q].x, x[2 * q].y, x[2 * q + 1].x, x[2 * q + 1].y);
    *(float4*)&sc[r * 66 + 16 * kap + 2 * q] = v;
  }
  __syncthreads();

  // ---- fully-coalesced blend with cliff + resid, store ----
  float g = gate[0];
  const float scale = 1.f / 4096.f;
  for (int idx = tid; idx < 4096; idx += 256) {
    int rr2 = idx >> 6, cc2 = idx & 63;
    float2 sp = sc[rr2 * 66 + cc2];
    int a = base + idx;
    float cr = b2f(Cb[(((size_t)n * 128 + ch) << 12) + idx]);
    float ci = b2f(Cb[(((size_t)n * 128 + 64 + ch) << 12) + idx]);
    Xr[a] = g * cr + (1.f - g) * sp.x * scale + rr_[a];
    Xi[a] = g * ci + (1.f - g) * sp.y * scale + ri_[a];
  }
}

// -------- Kernel D: fused temporal (LN -> GEMM1 -> scan -> GEMM2 -> +res) --
// Xe padded to stride 129. Scan threads remapped px=tid&3/dp=tid>>2 so the
// per-t Asub b16 writes span 16 banks (was 4 -> 16-way conflict). LN pack
// remapped to c = k*8 + seg*2 so the packed dword writes land on bank
// tid&31 (conflict-free). Residual kept in registers.
__global__ __launch_bounds__(256, 3) void k_temporal_mfma(
    float* __restrict__ Xr, float* __restrict__ Xi,   // W0 in/out
    const float* __restrict__ dt,
    const float* __restrict__ lnw, const float* __restrict__ lnb,
    const float* __restrict__ lam_re, const float* __restrict__ lam_im,
    const unsigned short* __restrict__ Wt1, const unsigned short* __restrict__ Wt2) {
  __shared__ unsigned short Asub[16 * 64 * 8];    // 16 KB
  __shared__ float Xe[64 * 129];                  // 33,024 B (padded)
  int bid = xcd_swizzle(blockIdx.x, 2048);
  int b = bid >> 10, tile = bid & 1023;
  int hw0 = tile * 4;
  int tid = threadIdx.x;
  int lane = tid & 63, wv = tid >> 6;
  int l31 = lane & 31, lhi = lane >> 5;
  size_t xbase = (size_t)b * TT * DCH * HW + hw0;

  float4 res[8];
#pragma unroll
  for (int q = 0; q < 8; ++q) {
    int item = tid + q * 256;          // t*128 + c
    int t = item >> 7, c = item & 127;
    int d = c & 63;
    const float* src = ((c >> 6) ? Xi : Xr) + xbase + ((size_t)t * 64 + d) * HW;
    float4 v = *(const float4*)src;
    res[q] = v;                        // residual stays in registers
    Xe[(t * 4 + 0) * 129 + c] = v.x;
    Xe[(t * 4 + 1) * 129 + c] = v.y;
    Xe[(t * 4 + 2) * 129 + c] = v.z;
    Xe[(t * 4 + 3) * 129 + c] = v.w;
  }
  __syncthreads();

  {
    int row = tid >> 2, seg = tid & 3;
    float s = 0.f, s2 = 0.f;
#pragma unroll
    for (int j = 0; j < 32; ++j) {
      float v = Xe[row * 129 + seg * 32 + j];
      s += v; s2 += v * v;
    }
    s += __shfl_xor(s, 1); s2 += __shfl_xor(s2, 1);
    s += __shfl_xor(s, 2); s2 += __shfl_xor(s2, 2);
    float mu = s * (1.f / 128.f);
    float var = s2 * (1.f / 128.f) - mu * mu;
    float rs = rsqrtf(var + EPS);
    // pack c = k*8 + seg*2, k=0..15: write bank = tid&31 (conflict-free)
#pragma unroll
    for (int k = 0; k < 16; ++k) {
      int c = k * 8 + seg * 2;
      float v0 = (Xe[row * 129 + c] - mu) * rs * lnw[c] + lnb[c];
      float v1 = (Xe[row * 129 + c + 1] - mu) * rs * lnw[c + 1] + lnb[c + 1];
      unsigned pk = (unsigned)f2b(v0) | ((unsigned)f2b(v1) << 16);
      *(unsigned*)(Asub + (k * 64 + row) * 8 + seg * 2) = pk;
    }
  }
  __syncthreads();

  int mt = wv & 1, ntb = (wv >> 1) << 1;
  accv acc0 = accv{}, acc1 = accv{};
#pragma unroll
  for (int ks = 0; ks < 8; ++ks) {
    int kg = ks * 2 + lhi;
    bfrag a = *(const bfrag*)(Asub + (kg * 64 + mt * 32 + l31) * 8);
    bfrag b0 = *(const bfrag*)(Wt1 + (kg * 128 + ntb * 32 + l31) * 8);
    bfrag b1 = *(const bfrag*)(Wt1 + (kg * 128 + (ntb + 1) * 32 + l31) * 8);
    acc0 = __builtin_amdgcn_mfma_f32_32x32x16_bf16(a, b0, acc0, 0, 0, 0);
    acc1 = __builtin_amdgcn_mfma_f32_32x32x16_bf16(a, b1, acc1, 0, 0, 0);
  }
  __syncthreads();

#pragma unroll
  for (int rr = 0; rr < 16; ++rr) {
    int mrow = mt * 32 + (rr & 3) + ((rr >> 2) << 3) + (lhi << 2);
    Xe[mrow * 129 + ntb * 32 + l31] = acc0[rr];
    Xe[mrow * 129 + (ntb + 1) * 32 + l31] = acc1[rr];
  }
  __syncthreads();

  {
    int px = tid & 3, dp = tid >> 2;   // r varies per-lane -> 4-way writes
    float x0 = lam_re[dp];
    float nl = -(x0 > 15.f ? x0 : log1pf(__expf(x0)));
    float li = lam_im[dp];
    float hr = 0.f, hi = 0.f;
    int cR = dp, cI = 64 + dp;
    for (int t = 0; t < TT; ++t) {
      float dtv = dt[b * 16 + t];
      float ea = __expf(nl * dtv);
      float sv, cv; __sincosf(li * dtv, &sv, &cv);
      float evr = ea * cv, evi = ea * sv;
      int r = t * 4 + px;
      float xr_ = Xe[r * 129 + cR], xi_ = Xe[r * 129 + cI];
      float nhr = evr * hr - evi * hi + xr_;
      float nhi = evr * hi + evi * hr + xi_;
      hr = nhr; hi = nhi;
      Asub[((cR >> 3) * 64 + r) * 8 + (cR & 7)] = f2b(hr);
      Asub[((cI >> 3) * 64 + r) * 8 + (cI & 7)] = f2b(hi);
    }
  }
  __syncthreads();

  acc0 = accv{}; acc1 = accv{};
#pragma unroll
  for (int ks = 0; ks < 8; ++ks) {
    int kg = ks * 2 + lhi;
    bfrag a = *(const bfrag*)(Asub + (kg * 64 + mt * 32 + l31) * 8);
    bfrag b0 = *(const bfrag*)(Wt2 + (kg * 128 + ntb * 32 + l31) * 8);
    bfrag b1 = *(const bfrag*)(Wt2 + (kg * 128 + (ntb + 1) * 32 + l31) * 8);
    acc0 = __builtin_amdgcn_mfma_f32_32x32x16_bf16(a, b0, acc0, 0, 0, 0);
    acc1 = __builtin_amdgcn_mfma_f32_32x32x16_bf16(a, b1, acc1, 0, 0, 0);
  }
  __syncthreads();

#pragma unroll
  for (int rr = 0; rr < 16; ++rr) {
    int mrow = mt * 32 + (rr & 3) + ((rr >> 2) << 3) + (lhi << 2);
    Xe[mrow * 129 + ntb * 32 + l31] = acc0[rr];
    Xe[mrow * 129 + (ntb + 1) * 32 + l31] = acc1[rr];
  }
  __syncthreads();

#pragma unroll
  for (int q = 0; q < 8; ++q) {
    int item = tid + q * 256;
    int t = item >> 7, c = item & 127;
    int d = c & 63;
    float* dst = ((c >> 6) ? Xi : Xr) + xbase + ((size_t)t * 64 + d) * HW;
    float4 o;
    o.x = Xe[(t * 4 + 0) * 129 + c] + res[q].x;
    o.y = Xe[(t * 4 + 1) * 129 + c] + res[q].y;
    o.z = Xe[(t * 4 + 2) * 129 + c] + res[q].z;
    o.w = Xe[(t * 4 + 3) * 129 + c] + res[q].w;
    *(float4*)dst = o;
  }
}

// -------- Kernel E2: MFMA MLP with prepped weights (B from global) ---------
__global__ __launch_bounds__(256, 4) void k_mlp_pre(
    const float* __restrict__ Xr, const float* __restrict__ Xi,
    const float* __restrict__ lnw, const float* __restrict__ lnb,
    const unsigned short* __restrict__ Wm1,   // [2h][16kg][128n][8]
    const unsigned short* __restrict__ Wm2,   // [2kh][16kg][128n][8]
    const float* __restrict__ b1, const float* __restrict__ b2,
    float* __restrict__ out) {
  __shared__ __align__(16) unsigned char smem[32768];
  float* Xe = (float*)smem;                               // [128c][64m]
  unsigned short* Asub = (unsigned short*)smem;           // [16kg][64m][8]
  unsigned short* mid  = (unsigned short*)(smem + 16384); // [16kg][64m][8]
  unsigned short* ost  = (unsigned short*)smem;           // [128ng][66]
  int bid = blockIdx.x;
  int bt = bid >> 6, tile = bid & 63;
  int hw0 = tile << 6;
  int tid = threadIdx.x;
  int lane = tid & 63, wv = tid >> 6;
  int l31 = lane & 31, lhi = lane >> 5;
  size_t base = (size_t)bt * DCH * HW + hw0;   // + d*HW + m

#pragma unroll
  for (int q = 0; q < 8; ++q) {
    int item = q * 256 + tid;           // 2048 float4
    int m4 = item & 15, c = item >> 4;
    int d = c & 63;
    const float* src = ((c >> 6) ? Xi : Xr) + base + (size_t)d * HW + m4 * 4;
    *(float4*)(Xe + c * 64 + m4 * 4) = *(const float4*)src;
  }
  __syncthreads();                      // (1) Xe ready

  // LN: values held in registers across the in-place Asub overwrite
  {
    int row = tid >> 2, seg = tid & 3;
    float xv[32];
    float s = 0.f, s2 = 0.f;
#pragma unroll
    for (int j = 0; j < 32; ++j) {
      float v = Xe[(seg * 32 + j) * 64 + row];
      xv[j] = v; s += v; s2 += v * v;
    }
    s += __shfl_xor(s, 1); s2 += __shfl_xor(s2, 1);
    s += __shfl_xor(s, 2); s2 += __shfl_xor(s2, 2);
    float mu = s * (1.f / 128.f);
    float var = s2 * (1.f / 128.f) - mu * mu;
    float rs = rsqrtf(var + EPS);
    __syncthreads();                    // (2) all Xe reads done
#pragma unroll
    for (int j = 0; j < 32; ++j) {
      int c = seg * 32 + j;
      Asub[((c >> 3) * 64 + row) * 8 + (c & 7)] =
          f2b((xv[j] - mu) * rs * lnw[c] + lnb[c]);
    }
  }
  __syncthreads();                      // (3) Asub ready

  int ng = wv * 32 + l31;
  accv c0 = accv{}, c1 = accv{};
#pragma unroll
  for (int h = 0; h < 2; ++h) {
    accv g0 = accv{}, g1 = accv{};
#pragma unroll
    for (int ks = 0; ks < 8; ++ks) {
      int kg = ks * 2 + lhi;
      bfrag bfr = *(const bfrag*)(Wm1 + (((h * 16 + kg) * 128) + ng) * 8);
      bfrag a0 = *(const bfrag*)(Asub + (kg * 64 + l31) * 8);
      bfrag a1 = *(const bfrag*)(Asub + (kg * 64 + 32 + l31) * 8);
      g0 = __builtin_amdgcn_mfma_f32_32x32x16_bf16(a0, bfr, g0, 0, 0, 0);
      g1 = __builtin_amdgcn_mfma_f32_32x32x16_bf16(a1, bfr, g1, 0, 0, 0);
    }
    if (h == 1) __syncthreads();        // (5) G2-kh0 mid reads done
    float b1v = b1[h * 128 + ng];
    int kgl = ng >> 3, jj = ng & 7;
#pragma unroll
    for (int rr = 0; rr < 16; ++rr) {
      int mr = (rr & 3) + ((rr >> 2) << 3) + (lhi << 2);
      mid[(kgl * 64 + mr) * 8 + jj] = f2b(gelu_f(g0[rr] + b1v));
      mid[(kgl * 64 + 32 + mr) * 8 + jj] = f2b(gelu_f(g1[rr] + b1v));
    }
    __syncthreads();                    // (4)/(6) mid ready
#pragma unroll
    for (int ks = 0; ks < 8; ++ks) {
      int kg = ks * 2 + lhi;
      bfrag bfr = *(const bfrag*)(Wm2 + (((h * 16 + kg) * 128) + ng) * 8);
      bfrag a0 = *(const bfrag*)(mid + (kg * 64 + l31) * 8);
      bfrag a1 = *(const bfrag*)(mid + (kg * 64 + 32 + l31) * 8);
      c0 = __builtin_amdgcn_mfma_f32_32x32x16_bf16(a0, bfr, c0, 0, 0, 0);
      c1 = __builtin_amdgcn_mfma_f32_32x32x16_bf16(a1, bfr, c1, 0, 0, 0);
    }
  }
  __syncthreads();                      // (7) all mid reads done

  {
    float b2v = b2[ng];
#pragma unroll
    for (int rr = 0; rr < 16; ++rr) {
      int mr = (rr & 3) + ((rr >> 2) << 3) + (lhi << 2);
      ost[ng * 66 + mr] = f2b(c0[rr] + b2v);
      ost[ng * 66 + 32 + mr] = f2b(c1[rr] + b2v);
    }
  }
  __syncthreads();                      // (8) ostage ready
#pragma unroll
  for (int q = 0; q < 4; ++q) {
    int item = q * 256 + tid;          // 1024: (d, m4)
    int m4 = item & 15, d = item >> 4;
    size_t xa = base + (size_t)d * HW + m4 * 4;
    float4 xr4 = *(const float4*)(Xr + xa);
    float4 xi4 = *(const float4*)(Xi + xa);
    int m = m4 * 4;
    float r0 = b2f(ost[d * 66 + m]),     i0 = b2f(ost[(64 + d) * 66 + m]);
    float r1 = b2f(ost[d * 66 + m + 1]), i1 = b2f(ost[(64 + d) * 66 + m + 1]);
    float r2 = b2f(ost[d * 66 + m + 2]), i2 = b2f(ost[(64 + d) * 66 + m + 2]);
    float r3 = b2f(ost[d * 66 + m + 3]), i3 = b2f(ost[(64 + d) * 66 + m + 3]);
    float4 o1, o2;
    o1.x = r0 + xr4.x; o1.y = i0 + xi4.x; o1.z = r1 + xr4.y; o1.w = i1 + xi4.y;
    o2.x = r2 + xr4.z; o2.y = i2 + xi4.z; o2.z = r3 + xr4.w; o2.w = i3 + xi4.w;
    *(float4*)(out + xa * 2) = o1;
    *(float4*)(out + xa * 2 + 4) = o2;
  }
}

extern "C" void kernel_launch(void* const* d_in, const int* in_sizes, int n_in,
                              void* d_out, int out_size, void* d_ws, size_t ws_size,
                              hipStream_t stream) {
  const float* x_real  = (const float*)d_in[0];
  const float* x_imag  = (const float*)d_in[1];
  const float* dt      = (const float*)d_in[2];
  const float* ln_s_w  = (const float*)d_in[3];
  const float* ln_s_b  = (const float*)d_in[4];
  const float* ln_t_w  = (const float*)d_in[5];
  const float* ln_t_b  = (const float*)d_in[6];
  const float* ln_m_w  = (const float*)d_in[7];
  const float* ln_m_b  = (const float*)d_in[8];
  const float* cw_r    = (const float*)d_in[9];
  const float* cw_i    = (const float*)d_in[10];
  const float* cb_r    = (const float*)d_in[11];
  const float* cb_i    = (const float*)d_in[12];
  const float* spec_wr = (const float*)d_in[13];
  const float* spec_wi = (const float*)d_in[14];
  const float* gate    = (const float*)d_in[15];
  const float* lam_re  = (const float*)d_in[16];
  const float* lam_im  = (const float*)d_in[17];
  const float* V_re    = (const float*)d_in[18];
  const float* V_im    = (const float*)d_in[19];
  const float* Vinv_re = (const float*)d_in[20];
  const float* Vinv_im = (const float*)d_in[21];
  const float* mlp_w1  = (const float*)d_in[22];
  const float* mlp_b1  = (const float*)d_in[23];
  const float* mlp_w2  = (const float*)d_in[24];
  const float* mlp_b2  = (const float*)d_in[25];

  float* out = (float*)d_out;
  unsigned short* Xb = (unsigned short*)d_out;
  unsigned short* Cb = Xb + (size_t)2 * NELEM;
  unsigned short* Wt1 = Xb;
  unsigned short* Wt2 = Xb + 16384;
  float* W0r = (float*)d_ws;
  float* W0i = W0r + NELEM;
  unsigned short* Wt = (unsigned short*)d_ws;
  // Xc (channel-major ln-out for the FFT) overlays W0i: each fft block reads
  // its Xc slab fully into registers before any of its W0i writes, and slabs
  // are block-disjoint with identical index <-> byte-range mapping.
  unsigned short* Xc = (unsigned short*)W0i;
  // MLP bf16 weights live past the 64 MB W0 region (ws_size-guarded; verified
  // large enough in rounds 6-11).
  size_t ws_used = (size_t)2 * NELEM * 4;
  unsigned short* Wm = (unsigned short*)((char*)d_ws + ws_used);
  // Spectral weight pre-gather (2 MB) past Wm, only if workspace permits.
  size_t ps_off = ws_used + 131072;
  bool sprep = ws_size >= ps_off + (size_t)262144 * 8;
  float2* Ps = sprep ? (float2*)((char*)d_ws + ps_off) : (float2*)nullptr;

  k_wprep<<<576, 256, 0, stream>>>(cw_r, cw_i, Wt);
  k_mprep<<<256, 256, 0, stream>>>(mlp_w1, mlp_w2, Wm);
  if (sprep) k_sprep<<<1024, 256, 0, stream>>>(spec_wr, spec_wi, Ps);
  k_ln_spatial<<<512, 256, 0, stream>>>(x_real, x_imag, ln_s_w, ln_s_b, Xb);
  k_xpose<<<1024, 256, 0, stream>>>(Xb, Xc);
  k_conv_mfma<<<1024, 256, 0, stream>>>(Xb, Wt, cb_r, cb_i, Cb);
  k_fft_blend<<<2048, 256, 0, stream>>>(W0r, W0i, Xc, Cb, x_real, x_imag,
                                        spec_wr, spec_wi, Ps, gate);
  k_vprep<<<64, 256, 0, stream>>>(V_re, V_im, Vinv_re, Vinv_im, Wt1, Wt2);
  k_temporal_mfma<<<2048, 256, 0, stream>>>(W0r, W0i, dt, ln_t_w, ln_t_b,
                                            lam_re, lam_im, Wt1, Wt2);
  k_mlp_pre<<<2048, 256, 0, stream>>>(W0r, W0i, ln_m_w, ln_m_b,
                                      Wm, Wm + 32768, mlp_b1, mlp_b2, out);
}

// Round 13
// 435.593 us; speedup vs baseline: 1.1423x; 1.0721x over previous
//
#include <hip/hip_runtime.h>
#include <math.h>

#define NELEM 8388608   // B*T*D*H*W = 2*16*64*64*64
#define HW    4096
#define DCH   64
#define TT    16
#define EPS   1e-5f

typedef __attribute__((ext_vector_type(8))) short bfrag;   // 8 bf16 = 4 VGPRs
typedef __attribute__((ext_vector_type(16))) float accv;   // 16 fp32 acc

__device__ __forceinline__ unsigned short f2b(float f) {
  union { float f; unsigned u; } v; v.f = f;
  unsigned r = (v.u + 0x7FFF + ((v.u >> 16) & 1)) >> 16;
  return (unsigned short)r;
}
__device__ __forceinline__ float b2f(unsigned short h) {
  union { unsigned u; float f; } v; v.u = ((unsigned)h) << 16;
  return v.f;
}
// base-4 digit reversal of a 6-bit index (3 digits)
__device__ __forceinline__ int rev4(int x) {
  return ((x & 3) << 4) | (x & 12) | ((x >> 4) & 3);
}
// XCD-locality swizzle: put consecutive logical tiles on the SAME XCD
// (dispatch is round-robin bid%8 -> XCD). NB must be divisible by 8.
__device__ __forceinline__ int xcd_swizzle(int bid, int nb) {
  return (bid & 7) * (nb >> 3) + (bid >> 3);
}

__device__ __forceinline__ float2 c_add(float2 a, float2 b) {
  return make_float2(a.x + b.x, a.y + b.y);
}
__device__ __forceinline__ float2 c_sub(float2 a, float2 b) {
  return make_float2(a.x - b.x, a.y - b.y);
}
// a * (w.x - i w.y)   [forward twiddle]
__device__ __forceinline__ float2 c_mul_conj(float2 a, float2 w) {
  return make_float2(a.x * w.x + a.y * w.y, a.y * w.x - a.x * w.y);
}
// a * (w.x + i w.y)   [inverse twiddle]
__device__ __forceinline__ float2 c_mul_pos(float2 a, float2 w) {
  return make_float2(a.x * w.x - a.y * w.y, a.y * w.x + a.x * w.y);
}
__device__ __forceinline__ float2 shfl_xor2(float2 v, int m) {
  return make_float2(__shfl_xor(v.x, m), __shfl_xor(v.y, m));
}
// tanh-form GELU: x*sigmoid(1.5958(x+0.044715x^3)); |err vs erf-gelu| < 1e-3,
// below bf16 rounding of the downstream f2b.
__device__ __forceinline__ float gelu_f(float v) {
  float y = -1.595769122f * (v + 0.044715f * v * v * v);
  return v * __builtin_amdgcn_rcpf(1.f + __expf(y));
}

// -------- Kernel W: weight prep -> MFMA-fragment order -----
// Wf[tap][half][ks][cb][t2][lane=lhi*32+l31][j]: the conv wave's A-fragment
// load becomes lane-consecutive 16 B (one coalesced 1 KB burst).
__global__ __launch_bounds__(256) void k_wprep(
    const float* __restrict__ cwr, const float* __restrict__ cwi,
    unsigned short* __restrict__ Wt) {
  int gid = blockIdx.x * 256 + threadIdx.x;
  if (gid >= 9 * 128 * 128) return;
  int j = gid & 7;
  int lane = (gid >> 3) & 63;
  int t2 = (gid >> 9) & 1;
  int cb = (gid >> 10) & 1;
  int ks = (gid >> 11) & 3;
  int half = (gid >> 13) & 1;
  int tap = gid >> 14;
  int l31 = lane & 31, lhi = lane >> 5;
  int co = cb * 64 + t2 * 32 + l31;
  int c = half * 64 + ks * 16 + lhi * 8 + j;
  int kh = tap / 3, kw = tap - kh * 3;
  int dout = co & 63, cin = c & 63;
  int widx = ((dout * 64 + cin) * 3 + kh) * 3 + kw;
  float v;
  if (co < 64) v = (c < 64) ? cwr[widx] : -cwi[widx];
  else         v = (c < 64) ? cwi[widx] :  cwr[widx];
  Wt[gid] = f2b(v);
}

// ------- Kernel V: temporal GEMM weights, MFMA-B layout [kg=16][n=128][8] --
__global__ __launch_bounds__(256) void k_vprep(
    const float* __restrict__ Vre, const float* __restrict__ Vim,
    const float* __restrict__ Vire, const float* __restrict__ Viim,
    unsigned short* __restrict__ Wt1, unsigned short* __restrict__ Wt2) {
  int gid = blockIdx.x * 256 + threadIdx.x;   // 0..16383
  int j = gid & 7, n = (gid >> 3) & 127, kg = gid >> 10;
  int k = kg * 8 + j;
  int d = k & 63, dp = n & 63;
  float v1, v2;
  if (k < 64) {
    v1 = (n < 64) ? Vire[dp * 64 + d] : Viim[dp * 64 + d];
    v2 = (n < 64) ? Vre[dp * 64 + d] : Vim[dp * 64 + d];
  } else {
    v1 = (n < 64) ? -Viim[dp * 64 + d] : Vire[dp * 64 + d];
    v2 = (n < 64) ? -Vim[dp * 64 + d] : Vre[dp * 64 + d];
  }
  Wt1[gid] = f2b(v1); Wt2[gid] = f2b(v2);
}

// ------- Kernel M: MLP weight prep -> Wm1[2h][16kg][128n][8], Wm2 same -----
__global__ __launch_bounds__(256) void k_mprep(
    const float* __restrict__ w1, const float* __restrict__ w2,
    unsigned short* __restrict__ Wm) {
  int gid = blockIdx.x * 256 + threadIdx.x;  // 0..65535
  int j = gid & 7, n = (gid >> 3) & 127, kgh = (gid >> 10) & 31;
  int hh = kgh >> 4, kg = kgh & 15;
  float v;
  if (gid < 32768) v = w1[(kg * 8 + j) * 256 + hh * 128 + n];
  else             v = w2[(hh * 128 + kg * 8 + j) * 128 + n];
  Wm[gid] = f2b(v);
}

// ------- Kernel S: spectral weight pre-gather into fft consumption order ---
__global__ __launch_bounds__(256) void k_sprep(
    const float* __restrict__ swr, const float* __restrict__ swi,
    float2* __restrict__ Ps) {
  int gid = blockIdx.x * 256 + threadIdx.x;   // 0..262143
  int cy = gid & 63, j = (gid >> 6) & 15, p = (gid >> 10) & 3, ch = gid >> 12;
  int kap = ((p & 1) << 1) | (p >> 1);
  int fr = ((j & 3) << 4) | (((j >> 2) & 3) << 2) | kap;
  int addr = ch * 4096 + fr * 64 + rev4(cy);
  Ps[gid] = make_float2(swr[addr], swi[addr]);
}

// ---------------- Kernel A: spatial LN -> Xb[n][hw][c=128] bf16 ------------
// Tiled LDS rewrite (round-12's 65 us kernel was parallelism-starved:
// vr/vi[64] arrays -> 132 VGPR, grid 512 -> 8% occupancy, 1 TB/s).
// 2048 blocks x 64-pixel tile; coalesced float4 in, LN via 4 threads/pixel
// + shfl, bf16 ost staging (overlays Xe), coalesced int4 out.
__global__ __launch_bounds__(256) void k_ln_spatial(
    const float* __restrict__ xr, const float* __restrict__ xi,
    const float* __restrict__ w, const float* __restrict__ b,
    unsigned short* __restrict__ Xb) {
  __shared__ __align__(16) unsigned char smem[34816];
  float* Xe = (float*)smem;                     // [128c][68 pitch]
  unsigned short* ost = (unsigned short*)smem;  // [64pix][136 pitch]
  int bid = xcd_swizzle(blockIdx.x, 2048);
  int bt = bid >> 6, tile = bid & 63;
  int hw0 = tile << 6;
  int tid = threadIdx.x;
  size_t base = (size_t)bt * DCH * HW + hw0;

#pragma unroll
  for (int q = 0; q < 8; ++q) {
    int item = q * 256 + tid;           // 2048 float4: (c, m4)
    int m4 = item & 15, c = item >> 4;
    int d = c & 63;
    const float* src = ((c >> 6) ? xi : xr) + base + (size_t)d * HW + m4 * 4;
    *(float4*)(Xe + c * 68 + m4 * 4) = *(const float4*)src;
  }
  __syncthreads();

  {
    int row = tid >> 2, seg = tid & 3;   // row = pixel in tile
    float xv[32];
    float s = 0.f, s2 = 0.f;
#pragma unroll
    for (int k = 0; k < 16; ++k) {
      int c = k * 8 + seg * 2;
      float v0 = Xe[c * 68 + row];
      float v1 = Xe[(c + 1) * 68 + row];
      xv[2 * k] = v0; xv[2 * k + 1] = v1;
      s += v0 + v1; s2 += v0 * v0 + v1 * v1;
    }
    s += __shfl_xor(s, 1); s2 += __shfl_xor(s2, 1);
    s += __shfl_xor(s, 2); s2 += __shfl_xor(s2, 2);
    float mu = s * (1.f / 128.f);
    float var = s2 * (1.f / 128.f) - mu * mu;
    float rs = rsqrtf(var + EPS);
    __syncthreads();                    // all Xe reads done; ost overlays
#pragma unroll
    for (int k = 0; k < 16; ++k) {
      int c = k * 8 + seg * 2;
      float v0 = (xv[2 * k] - mu) * rs * w[c] + b[c];
      float v1 = (xv[2 * k + 1] - mu) * rs * w[c + 1] + b[c + 1];
      unsigned pk = (unsigned)f2b(v0) | ((unsigned)f2b(v1) << 16);
      *(unsigned*)(ost + row * 136 + c) = pk;
    }
  }
  __syncthreads();

#pragma unroll
  for (int q = 0; q < 4; ++q) {
    int item = q * 256 + tid;           // 1024 int4: (pix, cq)
    int cq = item & 15, pix = item >> 4;
    int4 v = *(const int4*)(ost + pix * 136 + cq * 8);
    *(int4*)(Xb + (((size_t)bt * 4096 + hw0 + pix) << 7) + cq * 8) = v;
  }
}

// ------- Kernel X: transpose ln-out to channel-major for the FFT -----------
__global__ __launch_bounds__(256) void k_xpose(
    const unsigned short* __restrict__ Xb,   // [n][hw][c=128]
    unsigned short* __restrict__ Xc) {
  int bid = xcd_swizzle(blockIdx.x, 1024);   // same-n blocks share an XCD
  int n = bid >> 5, chp = bid & 31;          // channels chp*2, chp*2+1
  int tid = threadIdx.x;
  const unsigned short* src = Xb + (((size_t)n * 4096) << 7) + (chp << 1);
  size_t dst0 = (((size_t)n * 64 + chp * 2) << 13);   // slab * 8192 shorts
#pragma unroll
  for (int half = 0; half < 2; ++half) {
    union { unsigned short u[16]; int4 v[2]; } a0, a1;
#pragma unroll
    for (int m = 0; m < 16; ++m) {
      int hw = tid * 16 + m;
      unsigned vv = *(const unsigned*)(src + ((size_t)hw << 7) + (half << 6));
      a0.u[m] = (unsigned short)(vv & 0xffffu);
      a1.u[m] = (unsigned short)(vv >> 16);
    }
    *(int4*)(Xc + dst0 + (half << 12) + tid * 16)            = a0.v[0];
    *(int4*)(Xc + dst0 + (half << 12) + tid * 16 + 8)        = a0.v[1];
    *(int4*)(Xc + dst0 + 8192 + (half << 12) + tid * 16)     = a1.v[0];
    *(int4*)(Xc + dst0 + 8192 + (half << 12) + tid * 16 + 8) = a1.v[1];
  }
}

// ---------------- Kernel B: implicit-GEMM MFMA conv ------------------------
__global__ __launch_bounds__(256, 4) void k_conv_mfma(
    const unsigned short* __restrict__ Xb,   // [n][hw][c=128]
    const unsigned short* __restrict__ Wt,   // fragment-ordered (see k_wprep)
    const float* __restrict__ br, const float* __restrict__ bi,
    unsigned short* __restrict__ Cb) {       // [n][co=128][hw]
  __shared__ unsigned short Xs[4 * 8 * 66 * 8];   // 33,792 B
  int bid = xcd_swizzle(blockIdx.x, 1024);   // same-n blocks share an XCD
  int rg = bid & 31, n = bid >> 5;
  int r0 = rg << 1;
  int tid = threadIdx.x;
  int lane = tid & 63, wv = tid >> 6;
  int l31 = lane & 31, lhi = lane >> 5;
  int cb = wv >> 1;
  int cobase = cb << 6;
  int prow = wv & 1;

  accv acc[4] = {accv{}, accv{}, accv{}, accv{}};

  for (int q = tid; q < 2112; q += 256)
    ((int4*)Xs)[q] = make_int4(0, 0, 0, 0);
  __syncthreads();

  for (int half = 0; half < 2; ++half) {
    for (int q = tid; q < 2048; q += 256) {
      int cs = q & 7, col = (q >> 3) & 63, j = q >> 9;
      int gr = r0 - 1 + j;
      if (gr >= 0 && gr < 64) {
        const int4 v = *(const int4*)(Xb + (((size_t)n * 4096 + gr * 64 + col) << 7)
                                      + (half << 6) + (cs << 3));
        *(int4*)(Xs + (((j * 8 + cs) * 66 + col + 1) << 3)) = v;
      }
    }
    __syncthreads();
#pragma unroll
    for (int tap = 0; tap < 9; ++tap) {
      int kh = tap / 3, kw = tap - kh * 3;
#pragma unroll
      for (int ks = 0; ks < 4; ++ks) {
        bfrag af[2], bfv[2];
        const unsigned short* wf =
            Wt + ((((((tap * 2 + half) * 4 + ks) * 2 + cb) * 2) * 64) + lane) * 8;
        af[0] = *(const bfrag*)wf;
        af[1] = *(const bfrag*)(wf + 512);
        const unsigned short* xrow = Xs + ((((prow + kh) * 8 + (ks * 2 + lhi)) * 66 + kw) << 3);
#pragma unroll
        for (int u = 0; u < 2; ++u)
          bfv[u] = *(const bfrag*)(xrow + ((u * 32 + l31) << 3));
#pragma unroll
        for (int t2 = 0; t2 < 2; ++t2)
#pragma unroll
          for (int u = 0; u < 2; ++u)
            acc[t2 * 2 + u] = __builtin_amdgcn_mfma_f32_32x32x16_bf16(
                af[t2], bfv[u], acc[t2 * 2 + u], 0, 0, 0);
      }
    }
    __syncthreads();
  }

#pragma unroll
  for (int t2 = 0; t2 < 2; ++t2) {
#pragma unroll
    for (int u = 0; u < 2; ++u) {
      accv A = acc[t2 * 2 + u];
      int hw = (r0 + prow) * 64 + u * 32 + l31;
#pragma unroll
      for (int rr = 0; rr < 16; ++rr) {
        int co = cobase + t2 * 32 + (rr & 3) + ((rr >> 2) << 3) + (lhi << 2);
        float bias = (co < 64) ? br[co] : bi[co & 63];
        Cb[(((size_t)n * 128 + co) << 12) + hw] = f2b(A[rr] + bias);
      }
    }
  }
}

// -------- Kernel C: register-resident radix-4 FFT2 -> wspec -> iFFT2 -------
// Plain (256): no min-waves hint (round-11: (256,4) forced a spill; (256,2)
// starved occupancy). LDS-bound at 4 blocks/CU.
__global__ __launch_bounds__(256) void k_fft_blend(
    float* __restrict__ Xr, float* __restrict__ Xi,        // W0 out
    const unsigned short* __restrict__ Xc,                 // [slab][half][4096]
    const unsigned short* __restrict__ Cb,                 // cliff   [n][co][hw]
    const float* __restrict__ rr_, const float* __restrict__ ri_,
    const float* __restrict__ swr, const float* __restrict__ swi,
    const float2* __restrict__ Ps,                         // prepped (or null)
    const float* __restrict__ gate) {
  __shared__ __align__(16) float2 sc[64 * 66];   // 33,792 B, pitch 66
  __shared__ float2 tw[64];                      // W64^j = (cos,sin)(2*pi*j/64)
  int bid = xcd_swizzle(blockIdx.x, 2048);   // same-n ch-blocks share an XCD
  int ch = bid & 63;
  int n = bid >> 6;
  int base = bid << 12;
  int tid = threadIdx.x;
  int lane = tid & 63, wv = tid >> 6;
  int l15 = lane & 15;
  int p = lane >> 4;                    // 16-block residue class, in-wave
  int kap = ((p & 1) << 1) | (p >> 1);  // pi(p): 2-bit reverse
  bool pswap = (p & 1), prot = (p & 2);
  float sA = prot ? -1.f : 1.f;         // sign for xor32-style round
  float sB = pswap ? -1.f : 1.f;        // sign for xor16-style round
  int r = wv * 16 + l15;                // line index for x-passes
  int cy = r;                           // column index for y-passes (same map)

  if (tid < 64) {
    float sv, cv;
    __sincosf(0.09817477042468103f * (float)tid, &sv, &cv);  // 2*pi/64
    tw[tid] = make_float2(cv, sv);
  }

  float2 x[16];
  // ---- coalesced load from Xc: thread owns row r, cols 16p..16p+15 ----
  {
    const unsigned short* xp = Xc + ((size_t)bid << 13) + r * 64 + 16 * p;
    int4 ra = *(const int4*)xp;
    int4 rb = *(const int4*)(xp + 8);
    int4 ia = *(const int4*)(xp + 4096);
    int4 ib = *(const int4*)(xp + 4104);
    const unsigned short* rap = (const unsigned short*)&ra;
    const unsigned short* rbp = (const unsigned short*)&rb;
    const unsigned short* iap = (const unsigned short*)&ia;
    const unsigned short* ibp = (const unsigned short*)&ib;
#pragma unroll
    for (int j = 0; j < 8; ++j) {
      x[j]     = make_float2(b2f(rap[j]), b2f(iap[j]));
      x[8 + j] = make_float2(b2f(rbp[j]), b2f(ibp[j]));
    }
  }
  __syncthreads();   // tw table ready

  // =================== forward x (DIF: q16 shfl, q4, q1) ===================
#pragma unroll
  for (int j = 0; j < 16; ++j) {        // q=16 stage across p, then twiddle
    float2 mine = x[j];
    float2 pr = shfl_xor2(mine, 32);
    float2 t = make_float2(pr.x + sA * mine.x, pr.y + sA * mine.y);
    float2 pr2 = shfl_xor2(t, 16);
    float2 low = pswap ? pr2 : t;
    float2 high = pswap ? t : pr2;
    float2 u = prot ? make_float2(high.y, -high.x) : high;   // -i*high
    float2 o = make_float2(low.x + sB * u.x, low.y + sB * u.y);
    x[j] = c_mul_conj(o, tw[kap * j]);
  }
#pragma unroll
  for (int b = 0; b < 4; ++b) {         // q=4
    float2 t0 = c_add(x[b], x[b + 8]), t1 = c_sub(x[b], x[b + 8]);
    float2 t2 = c_add(x[b + 4], x[b + 12]), t3 = c_sub(x[b + 4], x[b + 12]);
    x[b] = c_add(t0, t2);
    float2 u1 = make_float2(t1.x + t3.y, t1.y - t3.x);
    float2 u2 = c_sub(t0, t2);
    float2 u3 = make_float2(t1.x - t3.y, t1.y + t3.x);
    x[b + 4] = c_mul_conj(u1, tw[4 * b]);
    x[b + 8] = c_mul_conj(u2, tw[8 * b]);
    x[b + 12] = c_mul_conj(u3, tw[12 * b]);
  }
#pragma unroll
  for (int a = 0; a < 4; ++a) {         // q=1 (no twiddles)
    int a4 = 4 * a;
    float2 t0 = c_add(x[a4], x[a4 + 2]), t1 = c_sub(x[a4], x[a4 + 2]);
    float2 t2 = c_add(x[a4 + 1], x[a4 + 3]), t3 = c_sub(x[a4 + 1], x[a4 + 3]);
    x[a4] = c_add(t0, t2);
    x[a4 + 1] = make_float2(t1.x + t3.y, t1.y - t3.x);
    x[a4 + 2] = c_sub(t0, t2);
    x[a4 + 3] = make_float2(t1.x - t3.y, t1.y + t3.x);
  }
  // write row r, cols 16*kap.. (ownership permuted by pi)
#pragma unroll
  for (int q = 0; q < 8; ++q) {
    float4 v = make_float4(x[2 * q].x, x[2 * q].y, x[2 * q + 1].x, x[2 * q + 1].y);
    *(float4*)&sc[r * 66 + 16 * kap + 2 * q] = v;
  }
  __syncthreads();

  // =================== forward y (read natural block p) ====================
#pragma unroll
  for (int j = 0; j < 16; ++j)
    x[j] = sc[(16 * p + j) * 66 + cy];
#pragma unroll
  for (int j = 0; j < 16; ++j) {        // q=16 (identical to fwd-x)
    float2 mine = x[j];
    float2 pr = shfl_xor2(mine, 32);
    float2 t = make_float2(pr.x + sA * mine.x, pr.y + sA * mine.y);
    float2 pr2 = shfl_xor2(t, 16);
    float2 low = pswap ? pr2 : t;
    float2 high = pswap ? t : pr2;
    float2 u = prot ? make_float2(high.y, -high.x) : high;
    float2 o = make_float2(low.x + sB * u.x, low.y + sB * u.y);
    x[j] = c_mul_conj(o, tw[kap * j]);
  }
#pragma unroll
  for (int b = 0; b < 4; ++b) {
    float2 t0 = c_add(x[b], x[b + 8]), t1 = c_sub(x[b], x[b + 8]);
    float2 t2 = c_add(x[b + 4], x[b + 12]), t3 = c_sub(x[b + 4], x[b + 12]);
    x[b] = c_add(t0, t2);
    float2 u1 = make_float2(t1.x + t3.y, t1.y - t3.x);
    float2 u2 = c_sub(t0, t2);
    float2 u3 = make_float2(t1.x - t3.y, t1.y + t3.x);
    x[b + 4] = c_mul_conj(u1, tw[4 * b]);
    x[b + 8] = c_mul_conj(u2, tw[8 * b]);
    x[b + 12] = c_mul_conj(u3, tw[12 * b]);
  }
#pragma unroll
  for (int a = 0; a < 4; ++a) {
    int a4 = 4 * a;
    float2 t0 = c_add(x[a4], x[a4 + 2]), t1 = c_sub(x[a4], x[a4 + 2]);
    float2 t2 = c_add(x[a4 + 1], x[a4 + 3]), t3 = c_sub(x[a4 + 1], x[a4 + 3]);
    x[a4] = c_add(t0, t2);
    x[a4 + 1] = make_float2(t1.x + t3.y, t1.y - t3.x);
    x[a4 + 2] = c_sub(t0, t2);
    x[a4 + 3] = make_float2(t1.x - t3.y, t1.y + t3.x);
  }

  // ============ spectral multiply in registers (digit-reversed) ============
  if (Ps) {
    const float2* pp = Ps + (((size_t)(ch * 4 + p) * 16) << 6) + r;
#pragma unroll
    for (int j = 0; j < 16; ++j) {
      float2 w = pp[j * 64];
      float2 v = x[j];
      x[j] = make_float2(v.x * w.x - v.y * w.y, v.x * w.y + v.y * w.x);
    }
  } else {
    int fb = ch * 4096 + rev4(cy);      // + fr*64
#pragma unroll
    for (int j = 0; j < 16; ++j) {
      int fr = ((j & 3) << 4) | (((j >> 2) & 3) << 2) | kap;
      float wr = swr[fb + fr * 64];
      float wi = swi[fb + fr * 64];
      float2 v = x[j];
      x[j] = make_float2(v.x * wr - v.y * wi, v.x * wi + v.y * wr);
    }
  }

  // ====== inverse y (DIT: q1, q4, pre-twiddle, q16 shfl; own blk=pi(p)) ====
#pragma unroll
  for (int a = 0; a < 4; ++a) {         // q=1
    int a4 = 4 * a;
    float2 e0 = c_add(x[a4], x[a4 + 2]), e1 = c_sub(x[a4], x[a4 + 2]);
    float2 o0 = c_add(x[a4 + 1], x[a4 + 3]), o1 = c_sub(x[a4 + 1], x[a4 + 3]);
    x[a4] = c_add(e0, o0);
    x[a4 + 1] = make_float2(e1.x - o1.y, e1.y + o1.x);
    x[a4 + 2] = c_sub(e0, o0);
    x[a4 + 3] = make_float2(e1.x + o1.y, e1.y - o1.x);
  }
#pragma unroll
  for (int b = 0; b < 4; ++b) {         // q=4
    float2 v1 = c_mul_pos(x[b + 4], tw[4 * b]);
    float2 v2 = c_mul_pos(x[b + 8], tw[8 * b]);
    float2 v3 = c_mul_pos(x[b + 12], tw[12 * b]);
    float2 e0 = c_add(x[b], v2), e1 = c_sub(x[b], v2);
    float2 o0 = c_add(v1, v3), o1 = c_sub(v1, v3);
    x[b] = c_add(e0, o0);
    x[b + 4] = make_float2(e1.x - o1.y, e1.y + o1.x);
    x[b + 8] = c_sub(e0, o0);
    x[b + 12] = make_float2(e1.x + o1.y, e1.y - o1.x);
  }
#pragma unroll
  for (int j = 0; j < 16; ++j) {        // q=16, v = pi(p) ownership
    float2 mine = c_mul_pos(x[j], tw[kap * j]);
    float2 pr = shfl_xor2(mine, 16);
    float2 t = make_float2(pr.x + sB * mine.x, pr.y + sB * mine.y);
    float2 pr2 = shfl_xor2(t, 32);
    float2 low = prot ? pr2 : t;
    float2 high = prot ? t : pr2;
    float2 u = pswap ? make_float2(-high.y, high.x) : high;  // +i*high
    x[j] = make_float2(low.x + sA * u.x, low.y + sA * u.y);
  }
  // write natural rows 16p+j at column cy
#pragma unroll
  for (int j = 0; j < 16; ++j)
    sc[(16 * p + j) * 66 + cy] = x[j];
  __syncthreads();

  // ====== inverse x (read natural block p; q1, q4, pre-twiddle, q16) =======
#pragma unroll
  for (int q = 0; q < 8; ++q) {
    float4 v = *(const float4*)&sc[r * 66 + 16 * p + 2 * q];
    x[2 * q] = make_float2(v.x, v.y);
    x[2 * q + 1] = make_float2(v.z, v.w);
  }
#pragma unroll
  for (int a = 0; a < 4; ++a) {
    int a4 = 4 * a;
    float2 e0 = c_add(x[a4], x[a4 + 2]), e1 = c_sub(x[a4], x[a4 + 2]);
    float2 o0 = c_add(x[a4 + 1], x[a4 + 3]), o1 = c_sub(x[a4 + 1], x[a4 + 3]);
    x[a4] = c_add(e0, o0);
    x[a4 + 1] = make_float2(e1.x - o1.y, e1.y + o1.x);
    x[a4 + 2] = c_sub(e0, o0);
    x[a4 + 3] = make_float2(e1.x + o1.y, e1.y - o1.x);
  }
#pragma unroll
  for (int b = 0; b < 4; ++b) {
    float2 v1 = c_mul_pos(x[b + 4], tw[4 * b]);
    float2 v2 = c_mul_pos(x[b + 8], tw[8 * b]);
    float2 v3 = c_mul_pos(x[b + 12], tw[12 * b]);
    float2 e0 = c_add(x[b], v2), e1 = c_sub(x[b], v2);
    float2 o0 = c_add(v1, v3), o1 = c_sub(v1, v3);
    x[b] = c_add(e0, o0);
    x[b + 4] = make_float2(e1.x - o1.y, e1.y + o1.x);
    x[b + 8] = c_sub(e0, o0);
    x[b + 12] = make_float2(e1.x + o1.y, e1.y - o1.x);
  }
#pragma unroll
  for (int j = 0; j < 16; ++j) {        // q=16, v = p ownership -> blk pi(p)
    float2 mine = c_mul_pos(x[j], tw[p * j]);
    float2 pr = shfl_xor2(mine, 32);
    float2 t = make_float2(pr.x + sA * mine.x, pr.y + sA * mine.y);
    float2 pr2 = shfl_xor2(t, 16);
    float2 low = pswap ? pr2 : t;
    float2 high = pswap ? t : pr2;
    float2 u = prot ? make_float2(-high.y, high.x) : high;   // +i*high
    x[j] = make_float2(low.x + sB * u.x, low.y + sB * u.y);
  }
  __syncthreads();   // everyone done reading sc from inv-y transpose

  // stage final values to LDS: element (r, 16*kap + j) <- x[j]
#pragma unroll
  for (int q = 0; q < 8; ++q) {
    float4 v = make_float4(x[2 * q].x, x[2 * q].y, x[2 * q + 1].x, x[2 * q + 1].y);
    *(float4*)&sc[r * 66 + 16 * kap + 2 * q] = v;
  }
  __syncthreads();

  // ---- fully-coalesced blend with cliff + resid, store ----
  float g = gate[0];
  const float scale = 1.f / 4096.f;
  for (int idx = tid; idx < 4096; idx += 256) {
    int rr2 = idx >> 6, cc2 = idx & 63;
    float2 sp = sc[rr2 * 66 + cc2];
    int a = base + idx;
    float cr = b2f(Cb[(((size_t)n * 128 + ch) << 12) + idx]);
    float ci = b2f(Cb[(((size_t)n * 128 + 64 + ch) << 12) + idx]);
    Xr[a] = g * cr + (1.f - g) * sp.x * scale + rr_[a];
    Xi[a] = g * ci + (1.f - g) * sp.y * scale + ri_[a];
  }
}

// -------- Kernel D: fused temporal (LN -> GEMM1 -> scan -> GEMM2 -> +res) --
__global__ __launch_bounds__(256, 3) void k_temporal_mfma(
    float* __restrict__ Xr, float* __restrict__ Xi,   // W0 in/out
    const float* __restrict__ dt,
    const float* __restrict__ lnw, const float* __restrict__ lnb,
    const float* __restrict__ lam_re, const float* __restrict__ lam_im,
    const unsigned short* __restrict__ Wt1, const unsigned short* __restrict__ Wt2) {
  __shared__ unsigned short Asub[16 * 64 * 8];    // 16 KB
  __shared__ float Xe[64 * 129];                  // 33,024 B (padded)
  int bid = xcd_swizzle(blockIdx.x, 2048);
  int b = bid >> 10, tile = bid & 1023;
  int hw0 = tile * 4;
  int tid = threadIdx.x;
  int lane = tid & 63, wv = tid >> 6;
  int l31 = lane & 31, lhi = lane >> 5;
  size_t xbase = (size_t)b * TT * DCH * HW + hw0;

  float4 res[8];
#pragma unroll
  for (int q = 0; q < 8; ++q) {
    int item = tid + q * 256;          // t*128 + c
    int t = item >> 7, c = item & 127;
    int d = c & 63;
    const float* src = ((c >> 6) ? Xi : Xr) + xbase + ((size_t)t * 64 + d) * HW;
    float4 v = *(const float4*)src;
    res[q] = v;                        // residual stays in registers
    Xe[(t * 4 + 0) * 129 + c] = v.x;
    Xe[(t * 4 + 1) * 129 + c] = v.y;
    Xe[(t * 4 + 2) * 129 + c] = v.z;
    Xe[(t * 4 + 3) * 129 + c] = v.w;
  }
  __syncthreads();

  {
    int row = tid >> 2, seg = tid & 3;
    float s = 0.f, s2 = 0.f;
#pragma unroll
    for (int j = 0; j < 32; ++j) {
      float v = Xe[row * 129 + seg * 32 + j];
      s += v; s2 += v * v;
    }
    s += __shfl_xor(s, 1); s2 += __shfl_xor(s2, 1);
    s += __shfl_xor(s, 2); s2 += __shfl_xor(s2, 2);
    float mu = s * (1.f / 128.f);
    float var = s2 * (1.f / 128.f) - mu * mu;
    float rs = rsqrtf(var + EPS);
    // pack c = k*8 + seg*2, k=0..15: write bank = tid&31 (conflict-free)
#pragma unroll
    for (int k = 0; k < 16; ++k) {
      int c = k * 8 + seg * 2;
      float v0 = (Xe[row * 129 + c] - mu) * rs * lnw[c] + lnb[c];
      float v1 = (Xe[row * 129 + c + 1] - mu) * rs * lnw[c + 1] + lnb[c + 1];
      unsigned pk = (unsigned)f2b(v0) | ((unsigned)f2b(v1) << 16);
      *(unsigned*)(Asub + (k * 64 + row) * 8 + seg * 2) = pk;
    }
  }
  __syncthreads();

  int mt = wv & 1, ntb = (wv >> 1) << 1;
  accv acc0 = accv{}, acc1 = accv{};
#pragma unroll
  for (int ks = 0; ks < 8; ++ks) {
    int kg = ks * 2 + lhi;
    bfrag a = *(const bfrag*)(Asub + (kg * 64 + mt * 32 + l31) * 8);
    bfrag b0 = *(const bfrag*)(Wt1 + (kg * 128 + ntb * 32 + l31) * 8);
    bfrag b1 = *(const bfrag*)(Wt1 + (kg * 128 + (ntb + 1) * 32 + l31) * 8);
    acc0 = __builtin_amdgcn_mfma_f32_32x32x16_bf16(a, b0, acc0, 0, 0, 0);
    acc1 = __builtin_amdgcn_mfma_f32_32x32x16_bf16(a, b1, acc1, 0, 0, 0);
  }
  __syncthreads();

#pragma unroll
  for (int rr = 0; rr < 16; ++rr) {
    int mrow = mt * 32 + (rr & 3) + ((rr >> 2) << 3) + (lhi << 2);
    Xe[mrow * 129 + ntb * 32 + l31] = acc0[rr];
    Xe[mrow * 129 + (ntb + 1) * 32 + l31] = acc1[rr];
  }
  __syncthreads();

  {
    int px = tid & 3, dp = tid >> 2;   // r varies per-lane -> 4-way writes
    float x0 = lam_re[dp];
    float nl = -(x0 > 15.f ? x0 : log1pf(__expf(x0)));
    float li = lam_im[dp];
    float hr = 0.f, hi = 0.f;
    int cR = dp, cI = 64 + dp;
    for (int t = 0; t < TT; ++t) {
      float dtv = dt[b * 16 + t];
      float ea = __expf(nl * dtv);
      float sv, cv; __sincosf(li * dtv, &sv, &cv);
      float evr = ea * cv, evi = ea * sv;
      int r = t * 4 + px;
      float xr_ = Xe[r * 129 + cR], xi_ = Xe[r * 129 + cI];
      float nhr = evr * hr - evi * hi + xr_;
      float nhi = evr * hi + evi * hr + xi_;
      hr = nhr; hi = nhi;
      Asub[((cR >> 3) * 64 + r) * 8 + (cR & 7)] = f2b(hr);
      Asub[((cI >> 3) * 64 + r) * 8 + (cI & 7)] = f2b(hi);
    }
  }
  __syncthreads();

  acc0 = accv{}; acc1 = accv{};
#pragma unroll
  for (int ks = 0; ks < 8; ++ks) {
    int kg = ks * 2 + lhi;
    bfrag a = *(const bfrag*)(Asub + (kg * 64 + mt * 32 + l31) * 8);
    bfrag b0 = *(const bfrag*)(Wt2 + (kg * 128 + ntb * 32 + l31) * 8);
    bfrag b1 = *(const bfrag*)(Wt2 + (kg * 128 + (ntb + 1) * 32 + l31) * 8);
    acc0 = __builtin_amdgcn_mfma_f32_32x32x16_bf16(a, b0, acc0, 0, 0, 0);
    acc1 = __builtin_amdgcn_mfma_f32_32x32x16_bf16(a, b1, acc1, 0, 0, 0);
  }
  __syncthreads();

#pragma unroll
  for (int rr = 0; rr < 16; ++rr) {
    int mrow = mt * 32 + (rr & 3) + ((rr >> 2) << 3) + (lhi << 2);
    Xe[mrow * 129 + ntb * 32 + l31] = acc0[rr];
    Xe[mrow * 129 + (ntb + 1) * 32 + l31] = acc1[rr];
  }
  __syncthreads();

#pragma unroll
  for (int q = 0; q < 8; ++q) {
    int item = tid + q * 256;
    int t = item >> 7, c = item & 127;
    int d = c & 63;
    float* dst = ((c >> 6) ? Xi : Xr) + xbase + ((size_t)t * 64 + d) * HW;
    float4 o;
    o.x = Xe[(t * 4 + 0) * 129 + c] + res[q].x;
    o.y = Xe[(t * 4 + 1) * 129 + c] + res[q].y;
    o.z = Xe[(t * 4 + 2) * 129 + c] + res[q].z;
    o.w = Xe[(t * 4 + 3) * 129 + c] + res[q].w;
    *(float4*)dst = o;
  }
}

// -------- Kernel E2: MFMA MLP with prepped weights (B from global) ---------
__global__ __launch_bounds__(256, 4) void k_mlp_pre(
    const float* __restrict__ Xr, const float* __restrict__ Xi,
    const float* __restrict__ lnw, const float* __restrict__ lnb,
    const unsigned short* __restrict__ Wm1,   // [2h][16kg][128n][8]
    const unsigned short* __restrict__ Wm2,   // [2kh][16kg][128n][8]
    const float* __restrict__ b1, const float* __restrict__ b2,
    float* __restrict__ out) {
  __shared__ __align__(16) unsigned char smem[32768];
  float* Xe = (float*)smem;                               // [128c][64m]
  unsigned short* Asub = (unsigned short*)smem;           // [16kg][64m][8]
  unsigned short* mid  = (unsigned short*)(smem + 16384); // [16kg][64m][8]
  unsigned short* ost  = (unsigned short*)smem;           // [128ng][66]
  int bid = blockIdx.x;
  int bt = bid >> 6, tile = bid & 63;
  int hw0 = tile << 6;
  int tid = threadIdx.x;
  int lane = tid & 63, wv = tid >> 6;
  int l31 = lane & 31, lhi = lane >> 5;
  size_t base = (size_t)bt * DCH * HW + hw0;   // + d*HW + m

#pragma unroll
  for (int q = 0; q < 8; ++q) {
    int item = q * 256 + tid;           // 2048 float4
    int m4 = item & 15, c = item >> 4;
    int d = c & 63;
    const float* src = ((c >> 6) ? Xi : Xr) + base + (size_t)d * HW + m4 * 4;
    *(float4*)(Xe + c * 64 + m4 * 4) = *(const float4*)src;
  }
  __syncthreads();                      // (1) Xe ready

  // LN: values held in registers across the in-place Asub overwrite
  {
    int row = tid >> 2, seg = tid & 3;
    float xv[32];
    float s = 0.f, s2 = 0.f;
#pragma unroll
    for (int j = 0; j < 32; ++j) {
      float v = Xe[(seg * 32 + j) * 64 + row];
      xv[j] = v; s += v; s2 += v * v;
    }
    s += __shfl_xor(s, 1); s2 += __shfl_xor(s2, 1);
    s += __shfl_xor(s, 2); s2 += __shfl_xor(s2, 2);
    float mu = s * (1.f / 128.f);
    float var = s2 * (1.f / 128.f) - mu * mu;
    float rs = rsqrtf(var + EPS);
    __syncthreads();                    // (2) all Xe reads done
#pragma unroll
    for (int j = 0; j < 32; ++j) {
      int c = seg * 32 + j;
      Asub[((c >> 3) * 64 + row) * 8 + (c & 7)] =
          f2b((xv[j] - mu) * rs * lnw[c] + lnb[c]);
    }
  }
  __syncthreads();                      // (3) Asub ready

  int ng = wv * 32 + l31;
  accv c0 = accv{}, c1 = accv{};
#pragma unroll
  for (int h = 0; h < 2; ++h) {
    accv g0 = accv{}, g1 = accv{};
#pragma unroll
    for (int ks = 0; ks < 8; ++ks) {
      int kg = ks * 2 + lhi;
      bfrag bfr = *(const bfrag*)(Wm1 + (((h * 16 + kg) * 128) + ng) * 8);
      bfrag a0 = *(const bfrag*)(Asub + (kg * 64 + l31) * 8);
      bfrag a1 = *(const bfrag*)(Asub + (kg * 64 + 32 + l31) * 8);
      g0 = __builtin_amdgcn_mfma_f32_32x32x16_bf16(a0, bfr, g0, 0, 0, 0);
      g1 = __builtin_amdgcn_mfma_f32_32x32x16_bf16(a1, bfr, g1, 0, 0, 0);
    }
    if (h == 1) __syncthreads();        // (5) G2-kh0 mid reads done
    float b1v = b1[h * 128 + ng];
    int kgl = ng >> 3, jj = ng & 7;
#pragma unroll
    for (int rr = 0; rr < 16; ++rr) {
      int mr = (rr & 3) + ((rr >> 2) << 3) + (lhi << 2);
      mid[(kgl * 64 + mr) * 8 + jj] = f2b(gelu_f(g0[rr] + b1v));
      mid[(kgl * 64 + 32 + mr) * 8 + jj] = f2b(gelu_f(g1[rr] + b1v));
    }
    __syncthreads();                    // (4)/(6) mid ready
#pragma unroll
    for (int ks = 0; ks < 8; ++ks) {
      int kg = ks * 2 + lhi;
      bfrag bfr = *(const bfrag*)(Wm2 + (((h * 16 + kg) * 128) + ng) * 8);
      bfrag a0 = *(const bfrag*)(mid + (kg * 64 + l31) * 8);
      bfrag a1 = *(const bfrag*)(mid + (kg * 64 + 32 + l31) * 8);
      c0 = __builtin_amdgcn_mfma_f32_32x32x16_bf16(a0, bfr, c0, 0, 0, 0);
      c1 = __builtin_amdgcn_mfma_f32_32x32x16_bf16(a1, bfr, c1, 0, 0, 0);
    }
  }
  __syncthreads();                      // (7) all mid reads done

  {
    float b2v = b2[ng];
#pragma unroll
    for (int rr = 0; rr < 16; ++rr) {
      int mr = (rr & 3) + ((rr >> 2) << 3) + (lhi << 2);
      ost[ng * 66 + mr] = f2b(c0[rr] + b2v);
      ost[ng * 66 + 32 + mr] = f2b(c1[rr] + b2v);
    }
  }
  __syncthreads();                      // (8) ostage ready
#pragma unroll
  for (int q = 0; q < 4; ++q) {
    int item = q * 256 + tid;          // 1024: (d, m4)
    int m4 = item & 15, d = item >> 4;
    size_t xa = base + (size_t)d * HW + m4 * 4;
    float4 xr4 = *(const float4*)(Xr + xa);
    float4 xi4 = *(const float4*)(Xi + xa);
    int m = m4 * 4;
    float r0 = b2f(ost[d * 66 + m]),     i0 = b2f(ost[(64 + d) * 66 + m]);
    float r1 = b2f(ost[d * 66 + m + 1]), i1 = b2f(ost[(64 + d) * 66 + m + 1]);
    float r2 = b2f(ost[d * 66 + m + 2]), i2 = b2f(ost[(64 + d) * 66 + m + 2]);
    float r3 = b2f(ost[d * 66 + m + 3]), i3 = b2f(ost[(64 + d) * 66 + m + 3]);
    float4 o1, o2;
    o1.x = r0 + xr4.x; o1.y = i0 + xi4.x; o1.z = r1 + xr4.y; o1.w = i1 + xi4.y;
    o2.x = r2 + xr4.z; o2.y = i2 + xi4.z; o2.z = r3 + xr4.w; o2.w = i3 + xi4.w;
    *(float4*)(out + xa * 2) = o1;
    *(float4*)(out + xa * 2 + 4) = o2;
  }
}

extern "C" void kernel_launch(void* const* d_in, const int* in_sizes, int n_in,
                              void* d_out, int out_size, void* d_ws, size_t ws_size,
                              hipStream_t stream) {
  const float* x_real  = (const float*)d_in[0];
  const float* x_imag  = (const float*)d_in[1];
  const float* dt      = (const float*)d_in[2];
  const float* ln_s_w  = (const float*)d_in[3];
  const float* ln_s_b  = (const float*)d_in[4];
  const float* ln_t_w  = (const float*)d_in[5];
  const float* ln_t_b  = (const float*)d_in[6];
  const float* ln_m_w  = (const float*)d_in[7];
  const float* ln_m_b  = (const float*)d_in[8];
  const float* cw_r    = (const float*)d_in[9];
  const float* cw_i    = (const float*)d_in[10];
  const float* cb_r    = (const float*)d_in[11];
  const float* cb_i    = (const float*)d_in[12];
  const float* spec_wr = (const float*)d_in[13];
  const float* spec_wi = (const float*)d_in[14];
  const float* gate    = (const float*)d_in[15];
  const float* lam_re  = (const float*)d_in[16];
  const float* lam_im  = (const float*)d_in[17];
  const float* V_re    = (const float*)d_in[18];
  const float* V_im    = (const float*)d_in[19];
  const float* Vinv_re = (const float*)d_in[20];
  const float* Vinv_im = (const float*)d_in[21];
  const float* mlp_w1  = (const float*)d_in[22];
  const float* mlp_b1  = (const float*)d_in[23];
  const float* mlp_w2  = (const float*)d_in[24];
  const float* mlp_b2  = (const float*)d_in[25];

  float* out = (float*)d_out;
  unsigned short* Xb = (unsigned short*)d_out;
  unsigned short* Cb = Xb + (size_t)2 * NELEM;
  unsigned short* Wt1 = Xb;
  unsigned short* Wt2 = Xb + 16384;
  float* W0r = (float*)d_ws;
  float* W0i = W0r + NELEM;
  unsigned short* Wt = (unsigned short*)d_ws;
  // Xc (channel-major ln-out for the FFT) overlays W0i: each fft block reads
  // its Xc slab fully into registers before any of its W0i writes, and slabs
  // are block-disjoint with identical index <-> byte-range mapping.
  unsigned short* Xc = (unsigned short*)W0i;
  // MLP bf16 weights live past the 64 MB W0 region (ws_size-guarded; verified
  // large enough in rounds 6-12).
  size_t ws_used = (size_t)2 * NELEM * 4;
  unsigned short* Wm = (unsigned short*)((char*)d_ws + ws_used);
  // Spectral weight pre-gather (2 MB) past Wm, only if workspace permits.
  size_t ps_off = ws_used + 131072;
  bool sprep = ws_size >= ps_off + (size_t)262144 * 8;
  float2* Ps = sprep ? (float2*)((char*)d_ws + ps_off) : (float2*)nullptr;

  k_wprep<<<576, 256, 0, stream>>>(cw_r, cw_i, Wt);
  k_mprep<<<256, 256, 0, stream>>>(mlp_w1, mlp_w2, Wm);
  if (sprep) k_sprep<<<1024, 256, 0, stream>>>(spec_wr, spec_wi, Ps);
  k_ln_spatial<<<2048, 256, 0, stream>>>(x_real, x_imag, ln_s_w, ln_s_b, Xb);
  k_xpose<<<1024, 256, 0, stream>>>(Xb, Xc);
  k_conv_mfma<<<1024, 256, 0, stream>>>(Xb, Wt, cb_r, cb_i, Cb);
  k_fft_blend<<<2048, 256, 0, stream>>>(W0r, W0i, Xc, Cb, x_real, x_imag,
                                        spec_wr, spec_wi, Ps, gate);
  k_vprep<<<64, 256, 0, stream>>>(V_re, V_im, Vinv_re, Vinv_im, Wt1, Wt2);
  k_temporal_mfma<<<2048, 256, 0, stream>>>(W0r, W0i, dt, ln_t_w, ln_t_b,
                                            lam_re, lam_im, Wt1, Wt2);
  k_mlp_pre<<<2048, 256, 0, stream>>>(W0r, W0i, ln_m_w, ln_m_b,
                                      Wm, Wm + 32768, mlp_b1, mlp_b2, out);
}

// Round 14
// 403.410 us; speedup vs baseline: 1.2334x; 1.0798x over previous
//
#include <hip/hip_runtime.h>
#include <math.h>

#define NELEM 8388608   // B*T*D*H*W = 2*16*64*64*64
#define HW    4096
#define DCH   64
#define TT    16
#define EPS   1e-5f

typedef __attribute__((ext_vector_type(8))) short bfrag;   // 8 bf16 = 4 VGPRs
typedef __attribute__((ext_vector_type(16))) float accv;   // 16 fp32 acc

__device__ __forceinline__ unsigned short f2b(float f) {
  union { float f; unsigned u; } v; v.f = f;
  unsigned r = (v.u + 0x7FFF + ((v.u >> 16) & 1)) >> 16;
  return (unsigned short)r;
}
__device__ __forceinline__ float b2f(unsigned short h) {
  union { unsigned u; float f; } v; v.u = ((unsigned)h) << 16;
  return v.f;
}
// base-4 digit reversal of a 6-bit index (3 digits)
__device__ __forceinline__ int rev4(int x) {
  return ((x & 3) << 4) | (x & 12) | ((x >> 4) & 3);
}
// XCD-locality swizzle: put consecutive logical tiles on the SAME XCD
// (dispatch is round-robin bid%8 -> XCD). NB must be divisible by 8.
__device__ __forceinline__ int xcd_swizzle(int bid, int nb) {
  return (bid & 7) * (nb >> 3) + (bid >> 3);
}

__device__ __forceinline__ float2 c_add(float2 a, float2 b) {
  return make_float2(a.x + b.x, a.y + b.y);
}
__device__ __forceinline__ float2 c_sub(float2 a, float2 b) {
  return make_float2(a.x - b.x, a.y - b.y);
}
// a * (w.x - i w.y)   [forward twiddle]
__device__ __forceinline__ float2 c_mul_conj(float2 a, float2 w) {
  return make_float2(a.x * w.x + a.y * w.y, a.y * w.x - a.x * w.y);
}
// a * (w.x + i w.y)   [inverse twiddle]
__device__ __forceinline__ float2 c_mul_pos(float2 a, float2 w) {
  return make_float2(a.x * w.x - a.y * w.y, a.y * w.x + a.x * w.y);
}
__device__ __forceinline__ float2 shfl_xor2(float2 v, int m) {
  return make_float2(__shfl_xor(v.x, m), __shfl_xor(v.y, m));
}
// tanh-form GELU: x*sigmoid(1.5958(x+0.044715x^3)); |err vs erf-gelu| < 1e-3,
// below bf16 rounding of the downstream f2b.
__device__ __forceinline__ float gelu_f(float v) {
  float y = -1.595769122f * (v + 0.044715f * v * v * v);
  return v * __builtin_amdgcn_rcpf(1.f + __expf(y));
}

// -------- Kernel W: weight prep -> MFMA-fragment order -----
// Wf[tap][half][ks][cb][t2][lane=lhi*32+l31][j]: the conv wave's A-fragment
// load becomes lane-consecutive 16 B (one coalesced 1 KB burst).
__global__ __launch_bounds__(256) void k_wprep(
    const float* __restrict__ cwr, const float* __restrict__ cwi,
    unsigned short* __restrict__ Wt) {
  int gid = blockIdx.x * 256 + threadIdx.x;
  if (gid >= 9 * 128 * 128) return;
  int j = gid & 7;
  int lane = (gid >> 3) & 63;
  int t2 = (gid >> 9) & 1;
  int cb = (gid >> 10) & 1;
  int ks = (gid >> 11) & 3;
  int half = (gid >> 13) & 1;
  int tap = gid >> 14;
  int l31 = lane & 31, lhi = lane >> 5;
  int co = cb * 64 + t2 * 32 + l31;
  int c = half * 64 + ks * 16 + lhi * 8 + j;
  int kh = tap / 3, kw = tap - kh * 3;
  int dout = co & 63, cin = c & 63;
  int widx = ((dout * 64 + cin) * 3 + kh) * 3 + kw;
  float v;
  if (co < 64) v = (c < 64) ? cwr[widx] : -cwi[widx];
  else         v = (c < 64) ? cwi[widx] :  cwr[widx];
  Wt[gid] = f2b(v);
}

// ------- Kernel V: temporal GEMM weights, MFMA-B layout [kg=16][n=128][8] --
__global__ __launch_bounds__(256) void k_vprep(
    const float* __restrict__ Vre, const float* __restrict__ Vim,
    const float* __restrict__ Vire, const float* __restrict__ Viim,
    unsigned short* __restrict__ Wt1, unsigned short* __restrict__ Wt2) {
  int gid = blockIdx.x * 256 + threadIdx.x;   // 0..16383
  int j = gid & 7, n = (gid >> 3) & 127, kg = gid >> 10;
  int k = kg * 8 + j;
  int d = k & 63, dp = n & 63;
  float v1, v2;
  if (k < 64) {
    v1 = (n < 64) ? Vire[dp * 64 + d] : Viim[dp * 64 + d];
    v2 = (n < 64) ? Vre[dp * 64 + d] : Vim[dp * 64 + d];
  } else {
    v1 = (n < 64) ? -Viim[dp * 64 + d] : Vire[dp * 64 + d];
    v2 = (n < 64) ? -Vim[dp * 64 + d] : Vre[dp * 64 + d];
  }
  Wt1[gid] = f2b(v1); Wt2[gid] = f2b(v2);
}

// ------- Kernel M: MLP weight prep -> Wm1[2h][16kg][128n][8], Wm2 same -----
__global__ __launch_bounds__(256) void k_mprep(
    const float* __restrict__ w1, const float* __restrict__ w2,
    unsigned short* __restrict__ Wm) {
  int gid = blockIdx.x * 256 + threadIdx.x;  // 0..65535
  int j = gid & 7, n = (gid >> 3) & 127, kgh = (gid >> 10) & 31;
  int hh = kgh >> 4, kg = kgh & 15;
  float v;
  if (gid < 32768) v = w1[(kg * 8 + j) * 256 + hh * 128 + n];
  else             v = w2[(hh * 128 + kg * 8 + j) * 128 + n];
  Wm[gid] = f2b(v);
}

// ------- Kernel S: spectral weight pre-gather into fft consumption order ---
__global__ __launch_bounds__(256) void k_sprep(
    const float* __restrict__ swr, const float* __restrict__ swi,
    float2* __restrict__ Ps) {
  int gid = blockIdx.x * 256 + threadIdx.x;   // 0..262143
  int cy = gid & 63, j = (gid >> 6) & 15, p = (gid >> 10) & 3, ch = gid >> 12;
  int kap = ((p & 1) << 1) | (p >> 1);
  int fr = ((j & 3) << 4) | (((j >> 2) & 3) << 2) | kap;
  int addr = ch * 4096 + fr * 64 + rev4(cy);
  Ps[gid] = make_float2(swr[addr], swi[addr]);
}

// ------- Kernel A: spatial LN -> Xb [n][hw][c] AND Xc [slab][half][hw] -----
// Fuses the old k_xpose: phase 2 stages the bf16 tile in BOTH pixel-major
// (ost, feeds Xb) and channel-major (ost2, feeds Xc) LDS layouts; phase 4
// stores Xc rows (128 B contiguous per lane-pair) directly -- saves the
// xpose kernel's ~100 MB HBM round-trip.
__global__ __launch_bounds__(256) void k_ln_spatial(
    const float* __restrict__ xr, const float* __restrict__ xi,
    const float* __restrict__ w, const float* __restrict__ b,
    unsigned short* __restrict__ Xb, unsigned short* __restrict__ Xc) {
  __shared__ __align__(16) unsigned char smem[35840];
  float* Xe = (float*)smem;                     // [128c][68 pitch] (34,816 B)
  unsigned short* ost = (unsigned short*)smem;          // [64pix][136] 17,408 B
  unsigned short* ost2 = (unsigned short*)(smem + 17408); // [128c][72] 18,432 B
  int bid = xcd_swizzle(blockIdx.x, 2048);
  int bt = bid >> 6, tile = bid & 63;
  int hw0 = tile << 6;
  int tid = threadIdx.x;
  size_t base = (size_t)bt * DCH * HW + hw0;

#pragma unroll
  for (int q = 0; q < 8; ++q) {
    int item = q * 256 + tid;           // 2048 float4: (c, m4)
    int m4 = item & 15, c = item >> 4;
    int d = c & 63;
    const float* src = ((c >> 6) ? xi : xr) + base + (size_t)d * HW + m4 * 4;
    *(float4*)(Xe + c * 68 + m4 * 4) = *(const float4*)src;
  }
  __syncthreads();

  {
    int row = tid >> 2, seg = tid & 3;   // row = pixel in tile
    float xv[32];
    float s = 0.f, s2 = 0.f;
#pragma unroll
    for (int k = 0; k < 16; ++k) {
      int c = k * 8 + seg * 2;
      float v0 = Xe[c * 68 + row];
      float v1 = Xe[(c + 1) * 68 + row];
      xv[2 * k] = v0; xv[2 * k + 1] = v1;
      s += v0 + v1; s2 += v0 * v0 + v1 * v1;
    }
    s += __shfl_xor(s, 1); s2 += __shfl_xor(s2, 1);
    s += __shfl_xor(s, 2); s2 += __shfl_xor(s2, 2);
    float mu = s * (1.f / 128.f);
    float var = s2 * (1.f / 128.f) - mu * mu;
    float rs = rsqrtf(var + EPS);
    __syncthreads();                    // all Xe reads done; staging overlays
#pragma unroll
    for (int k = 0; k < 16; ++k) {
      int c = k * 8 + seg * 2;
      unsigned short h0 = f2b((xv[2 * k] - mu) * rs * w[c] + b[c]);
      unsigned short h1 = f2b((xv[2 * k + 1] - mu) * rs * w[c + 1] + b[c + 1]);
      unsigned pk = (unsigned)h0 | ((unsigned)h1 << 16);
      *(unsigned*)(ost + row * 136 + c) = pk;   // pix-major (conflict-free)
      ost2[c * 72 + row] = h0;                  // ch-major (~2-way)
      ost2[(c + 1) * 72 + row] = h1;
    }
  }
  __syncthreads();

#pragma unroll
  for (int q = 0; q < 4; ++q) {
    int item = q * 256 + tid;           // 1024 int4: (pix, cq) -> Xb
    int cq = item & 15, pix = item >> 4;
    int4 v = *(const int4*)(ost + pix * 136 + cq * 8);
    *(int4*)(Xb + (((size_t)bt * 4096 + hw0 + pix) << 7) + cq * 8) = v;
  }
  {
    int pair = tid >> 1, seg2 = tid & 1;   // pair = c index 0..127
    int ch = pair & 63, half = pair >> 6;
    const unsigned short* sp = ost2 + pair * 72 + seg2 * 32;
    unsigned short* dp = Xc + (((size_t)bt * 64 + ch) << 13) + (half << 12)
                       + hw0 + seg2 * 32;
#pragma unroll
    for (int q = 0; q < 4; ++q)
      *(int4*)(dp + q * 8) = *(const int4*)(sp + q * 8);
  }
}

// ---------------- Kernel B: implicit-GEMM MFMA conv ------------------------
__global__ __launch_bounds__(256, 4) void k_conv_mfma(
    const unsigned short* __restrict__ Xb,   // [n][hw][c=128]
    const unsigned short* __restrict__ Wt,   // fragment-ordered (see k_wprep)
    const float* __restrict__ br, const float* __restrict__ bi,
    unsigned short* __restrict__ Cb) {       // [n][co=128][hw]
  __shared__ unsigned short Xs[4 * 8 * 66 * 8];   // 33,792 B
  int bid = xcd_swizzle(blockIdx.x, 1024);   // same-n blocks share an XCD
  int rg = bid & 31, n = bid >> 5;
  int r0 = rg << 1;
  int tid = threadIdx.x;
  int lane = tid & 63, wv = tid >> 6;
  int l31 = lane & 31, lhi = lane >> 5;
  int cb = wv >> 1;
  int cobase = cb << 6;
  int prow = wv & 1;

  accv acc[4] = {accv{}, accv{}, accv{}, accv{}};

  for (int q = tid; q < 2112; q += 256)
    ((int4*)Xs)[q] = make_int4(0, 0, 0, 0);
  __syncthreads();

  for (int half = 0; half < 2; ++half) {
    for (int q = tid; q < 2048; q += 256) {
      int cs = q & 7, col = (q >> 3) & 63, j = q >> 9;
      int gr = r0 - 1 + j;
      if (gr >= 0 && gr < 64) {
        const int4 v = *(const int4*)(Xb + (((size_t)n * 4096 + gr * 64 + col) << 7)
                                      + (half << 6) + (cs << 3));
        *(int4*)(Xs + (((j * 8 + cs) * 66 + col + 1) << 3)) = v;
      }
    }
    __syncthreads();
#pragma unroll
    for (int tap = 0; tap < 9; ++tap) {
      int kh = tap / 3, kw = tap - kh * 3;
#pragma unroll
      for (int ks = 0; ks < 4; ++ks) {
        bfrag af[2], bfv[2];
        const unsigned short* wf =
            Wt + ((((((tap * 2 + half) * 4 + ks) * 2 + cb) * 2) * 64) + lane) * 8;
        af[0] = *(const bfrag*)wf;
        af[1] = *(const bfrag*)(wf + 512);
        const unsigned short* xrow = Xs + ((((prow + kh) * 8 + (ks * 2 + lhi)) * 66 + kw) << 3);
#pragma unroll
        for (int u = 0; u < 2; ++u)
          bfv[u] = *(const bfrag*)(xrow + ((u * 32 + l31) << 3));
#pragma unroll
        for (int t2 = 0; t2 < 2; ++t2)
#pragma unroll
          for (int u = 0; u < 2; ++u)
            acc[t2 * 2 + u] = __builtin_amdgcn_mfma_f32_32x32x16_bf16(
                af[t2], bfv[u], acc[t2 * 2 + u], 0, 0, 0);
      }
    }
    __syncthreads();
  }

#pragma unroll
  for (int t2 = 0; t2 < 2; ++t2) {
#pragma unroll
    for (int u = 0; u < 2; ++u) {
      accv A = acc[t2 * 2 + u];
      int hw = (r0 + prow) * 64 + u * 32 + l31;
#pragma unroll
      for (int rr = 0; rr < 16; ++rr) {
        int co = cobase + t2 * 32 + (rr & 3) + ((rr >> 2) << 3) + (lhi << 2);
        float bias = (co < 64) ? br[co] : bi[co & 63];
        Cb[(((size_t)n * 128 + co) << 12) + hw] = f2b(A[rr] + bias);
      }
    }
  }
}

// -------- Kernel C: register-resident radix-4 FFT2 -> wspec -> iFFT2 -------
// Plain (256): no min-waves hint (round-11: (256,4) forced a spill; (256,2)
// starved occupancy). LDS-bound at 4 blocks/CU.
__global__ __launch_bounds__(256) void k_fft_blend(
    float* __restrict__ Xr, float* __restrict__ Xi,        // W0 out
    const unsigned short* __restrict__ Xc,                 // [slab][half][4096]
    const unsigned short* __restrict__ Cb,                 // cliff   [n][co][hw]
    const float* __restrict__ rr_, const float* __restrict__ ri_,
    const float* __restrict__ swr, const float* __restrict__ swi,
    const float2* __restrict__ Ps,                         // prepped (or null)
    const float* __restrict__ gate) {
  __shared__ __align__(16) float2 sc[64 * 66];   // 33,792 B, pitch 66
  __shared__ float2 tw[64];                      // W64^j = (cos,sin)(2*pi*j/64)
  int bid = xcd_swizzle(blockIdx.x, 2048);   // same-n ch-blocks share an XCD
  int ch = bid & 63;
  int n = bid >> 6;
  int base = bid << 12;
  int tid = threadIdx.x;
  int lane = tid & 63, wv = tid >> 6;
  int l15 = lane & 15;
  int p = lane >> 4;                    // 16-block residue class, in-wave
  int kap = ((p & 1) << 1) | (p >> 1);  // pi(p): 2-bit reverse
  bool pswap = (p & 1), prot = (p & 2);
  float sA = prot ? -1.f : 1.f;         // sign for xor32-style round
  float sB = pswap ? -1.f : 1.f;        // sign for xor16-style round
  int r = wv * 16 + l15;                // line index for x-passes
  int cy = r;                           // column index for y-passes (same map)

  if (tid < 64) {
    float sv, cv;
    __sincosf(0.09817477042468103f * (float)tid, &sv, &cv);  // 2*pi/64
    tw[tid] = make_float2(cv, sv);
  }

  float2 x[16];
  // ---- coalesced load from Xc: thread owns row r, cols 16p..16p+15 ----
  {
    const unsigned short* xp = Xc + ((size_t)bid << 13) + r * 64 + 16 * p;
    int4 ra = *(const int4*)xp;
    int4 rb = *(const int4*)(xp + 8);
    int4 ia = *(const int4*)(xp + 4096);
    int4 ib = *(const int4*)(xp + 4104);
    const unsigned short* rap = (const unsigned short*)&ra;
    const unsigned short* rbp = (const unsigned short*)&rb;
    const unsigned short* iap = (const unsigned short*)&ia;
    const unsigned short* ibp = (const unsigned short*)&ib;
#pragma unroll
    for (int j = 0; j < 8; ++j) {
      x[j]     = make_float2(b2f(rap[j]), b2f(iap[j]));
      x[8 + j] = make_float2(b2f(rbp[j]), b2f(ibp[j]));
    }
  }
  __syncthreads();   // tw table ready

  // =================== forward x (DIF: q16 shfl, q4, q1) ===================
#pragma unroll
  for (int j = 0; j < 16; ++j) {        // q=16 stage across p, then twiddle
    float2 mine = x[j];
    float2 pr = shfl_xor2(mine, 32);
    float2 t = make_float2(pr.x + sA * mine.x, pr.y + sA * mine.y);
    float2 pr2 = shfl_xor2(t, 16);
    float2 low = pswap ? pr2 : t;
    float2 high = pswap ? t : pr2;
    float2 u = prot ? make_float2(high.y, -high.x) : high;   // -i*high
    float2 o = make_float2(low.x + sB * u.x, low.y + sB * u.y);
    x[j] = c_mul_conj(o, tw[kap * j]);
  }
#pragma unroll
  for (int b = 0; b < 4; ++b) {         // q=4
    float2 t0 = c_add(x[b], x[b + 8]), t1 = c_sub(x[b], x[b + 8]);
    float2 t2 = c_add(x[b + 4], x[b + 12]), t3 = c_sub(x[b + 4], x[b + 12]);
    x[b] = c_add(t0, t2);
    float2 u1 = make_float2(t1.x + t3.y, t1.y - t3.x);
    float2 u2 = c_sub(t0, t2);
    float2 u3 = make_float2(t1.x - t3.y, t1.y + t3.x);
    x[b + 4] = c_mul_conj(u1, tw[4 * b]);
    x[b + 8] = c_mul_conj(u2, tw[8 * b]);
    x[b + 12] = c_mul_conj(u3, tw[12 * b]);
  }
#pragma unroll
  for (int a = 0; a < 4; ++a) {         // q=1 (no twiddles)
    int a4 = 4 * a;
    float2 t0 = c_add(x[a4], x[a4 + 2]), t1 = c_sub(x[a4], x[a4 + 2]);
    float2 t2 = c_add(x[a4 + 1], x[a4 + 3]), t3 = c_sub(x[a4 + 1], x[a4 + 3]);
    x[a4] = c_add(t0, t2);
    x[a4 + 1] = make_float2(t1.x + t3.y, t1.y - t3.x);
    x[a4 + 2] = c_sub(t0, t2);
    x[a4 + 3] = make_float2(t1.x - t3.y, t1.y + t3.x);
  }
  // write row r, cols 16*kap.. (ownership permuted by pi)
#pragma unroll
  for (int q = 0; q < 8; ++q) {
    float4 v = make_float4(x[2 * q].x, x[2 * q].y, x[2 * q + 1].x, x[2 * q + 1].y);
    *(float4*)&sc[r * 66 + 16 * kap + 2 * q] = v;
  }
  __syncthreads();

  // =================== forward y (read natural block p) ====================
#pragma unroll
  for (int j = 0; j < 16; ++j)
    x[j] = sc[(16 * p + j) * 66 + cy];
#pragma unroll
  for (int j = 0; j < 16; ++j) {        // q=16 (identical to fwd-x)
    float2 mine = x[j];
    float2 pr = shfl_xor2(mine, 32);
    float2 t = make_float2(pr.x + sA * mine.x, pr.y + sA * mine.y);
    float2 pr2 = shfl_xor2(t, 16);
    float2 low = pswap ? pr2 : t;
    float2 high = pswap ? t : pr2;
    float2 u = prot ? make_float2(high.y, -high.x) : high;
    float2 o = make_float2(low.x + sB * u.x, low.y + sB * u.y);
    x[j] = c_mul_conj(o, tw[kap * j]);
  }
#pragma unroll
  for (int b = 0; b < 4; ++b) {
    float2 t0 = c_add(x[b], x[b + 8]), t1 = c_sub(x[b], x[b + 8]);
    float2 t2 = c_add(x[b + 4], x[b + 12]), t3 = c_sub(x[b + 4], x[b + 12]);
    x[b] = c_add(t0, t2);
    float2 u1 = make_float2(t1.x + t3.y, t1.y - t3.x);
    float2 u2 = c_sub(t0, t2);
    float2 u3 = make_float2(t1.x - t3.y, t1.y + t3.x);
    x[b + 4] = c_mul_conj(u1, tw[4 * b]);
    x[b + 8] = c_mul_conj(u2, tw[8 * b]);
    x[b + 12] = c_mul_conj(u3, tw[12 * b]);
  }
#pragma unroll
  for (int a = 0; a < 4; ++a) {
    int a4 = 4 * a;
    float2 t0 = c_add(x[a4], x[a4 + 2]), t1 = c_sub(x[a4], x[a4 + 2]);
    float2 t2 = c_add(x[a4 + 1], x[a4 + 3]), t3 = c_sub(x[a4 + 1], x[a4 + 3]);
    x[a4] = c_add(t0, t2);
    x[a4 + 1] = make_float2(t1.x + t3.y, t1.y - t3.x);
    x[a4 + 2] = c_sub(t0, t2);
    x[a4 + 3] = make_float2(t1.x - t3.y, t1.y + t3.x);
  }

  // ============ spectral multiply in registers (digit-reversed) ============
  if (Ps) {
    const float2* pp = Ps + (((size_t)(ch * 4 + p) * 16) << 6) + r;
#pragma unroll
    for (int j = 0; j < 16; ++j) {
      float2 w = pp[j * 64];
      float2 v = x[j];
      x[j] = make_float2(v.x * w.x - v.y * w.y, v.x * w.y + v.y * w.x);
    }
  } else {
    int fb = ch * 4096 + rev4(cy);      // + fr*64
#pragma unroll
    for (int j = 0; j < 16; ++j) {
      int fr = ((j & 3) << 4) | (((j >> 2) & 3) << 2) | kap;
      float wr = swr[fb + fr * 64];
      float wi = swi[fb + fr * 64];
      float2 v = x[j];
      x[j] = make_float2(v.x * wr - v.y * wi, v.x * wi + v.y * wr);
    }
  }

  // ====== inverse y (DIT: q1, q4, pre-twiddle, q16 shfl; own blk=pi(p)) ====
#pragma unroll
  for (int a = 0; a < 4; ++a) {         // q=1
    int a4 = 4 * a;
    float2 e0 = c_add(x[a4], x[a4 + 2]), e1 = c_sub(x[a4], x[a4 + 2]);
    float2 o0 = c_add(x[a4 + 1], x[a4 + 3]), o1 = c_sub(x[a4 + 1], x[a4 + 3]);
    x[a4] = c_add(e0, o0);
    x[a4 + 1] = make_float2(e1.x - o1.y, e1.y + o1.x);
    x[a4 + 2] = c_sub(e0, o0);
    x[a4 + 3] = make_float2(e1.x + o1.y, e1.y - o1.x);
  }
#pragma unroll
  for (int b = 0; b < 4; ++b) {         // q=4
    float2 v1 = c_mul_pos(x[b + 4], tw[4 * b]);
    float2 v2 = c_mul_pos(x[b + 8], tw[8 * b]);
    float2 v3 = c_mul_pos(x[b + 12], tw[12 * b]);
    float2 e0 = c_add(x[b], v2), e1 = c_sub(x[b], v2);
    float2 o0 = c_add(v1, v3), o1 = c_sub(v1, v3);
    x[b] = c_add(e0, o0);
    x[b + 4] = make_float2(e1.x - o1.y, e1.y + o1.x);
    x[b + 8] = c_sub(e0, o0);
    x[b + 12] = make_float2(e1.x + o1.y, e1.y - o1.x);
  }
#pragma unroll
  for (int j = 0; j < 16; ++j) {        // q=16, v = pi(p) ownership
    float2 mine = c_mul_pos(x[j], tw[kap * j]);
    float2 pr = shfl_xor2(mine, 16);
    float2 t = make_float2(pr.x + sB * mine.x, pr.y + sB * mine.y);
    float2 pr2 = shfl_xor2(t, 32);
    float2 low = prot ? pr2 : t;
    float2 high = prot ? t : pr2;
    float2 u = pswap ? make_float2(-high.y, high.x) : high;  // +i*high
    x[j] = make_float2(low.x + sA * u.x, low.y + sA * u.y);
  }
  // write natural rows 16p+j at column cy
#pragma unroll
  for (int j = 0; j < 16; ++j)
    sc[(16 * p + j) * 66 + cy] = x[j];
  __syncthreads();

  // ====== inverse x (read natural block p; q1, q4, pre-twiddle, q16) =======
#pragma unroll
  for (int q = 0; q < 8; ++q) {
    float4 v = *(const float4*)&sc[r * 66 + 16 * p + 2 * q];
    x[2 * q] = make_float2(v.x, v.y);
    x[2 * q + 1] = make_float2(v.z, v.w);
  }
#pragma unroll
  for (int a = 0; a < 4; ++a) {
    int a4 = 4 * a;
    float2 e0 = c_add(x[a4], x[a4 + 2]), e1 = c_sub(x[a4], x[a4 + 2]);
    float2 o0 = c_add(x[a4 + 1], x[a4 + 3]), o1 = c_sub(x[a4 + 1], x[a4 + 3]);
    x[a4] = c_add(e0, o0);
    x[a4 + 1] = make_float2(e1.x - o1.y, e1.y + o1.x);
    x[a4 + 2] = c_sub(e0, o0);
    x[a4 + 3] = make_float2(e1.x + o1.y, e1.y - o1.x);
  }
#pragma unroll
  for (int b = 0; b < 4; ++b) {
    float2 v1 = c_mul_pos(x[b + 4], tw[4 * b]);
    float2 v2 = c_mul_pos(x[b + 8], tw[8 * b]);
    float2 v3 = c_mul_pos(x[b + 12], tw[12 * b]);
    float2 e0 = c_add(x[b], v2), e1 = c_sub(x[b], v2);
    float2 o0 = c_add(v1, v3), o1 = c_sub(v1, v3);
    x[b] = c_add(e0, o0);
    x[b + 4] = make_float2(e1.x - o1.y, e1.y + o1.x);
    x[b + 8] = c_sub(e0, o0);
    x[b + 12] = make_float2(e1.x + o1.y, e1.y - o1.x);
  }
#pragma unroll
  for (int j = 0; j < 16; ++j) {        // q=16, v = p ownership -> blk pi(p)
    float2 mine = c_mul_pos(x[j], tw[p * j]);
    float2 pr = shfl_xor2(mine, 32);
    float2 t = make_float2(pr.x + sA * mine.x, pr.y + sA * mine.y);
    float2 pr2 = shfl_xor2(t, 16);
    float2 low = pswap ? pr2 : t;
    float2 high = pswap ? t : pr2;
    float2 u = prot ? make_float2(-high.y, high.x) : high;   // +i*high
    x[j] = make_float2(low.x + sB * u.x, low.y + sB * u.y);
  }
  __syncthreads();   // everyone done reading sc from inv-y transpose

  // stage final values to LDS: element (r, 16*kap + j) <- x[j]
#pragma unroll
  for (int q = 0; q < 8; ++q) {
    float4 v = make_float4(x[2 * q].x, x[2 * q].y, x[2 * q + 1].x, x[2 * q + 1].y);
    *(float4*)&sc[r * 66 + 16 * kap + 2 * q] = v;
  }
  __syncthreads();

  // ---- fully-coalesced blend with cliff + resid, store ----
  float g = gate[0];
  const float scale = 1.f / 4096.f;
  for (int idx = tid; idx < 4096; idx += 256) {
    int rr2 = idx >> 6, cc2 = idx & 63;
    float2 sp = sc[rr2 * 66 + cc2];
    int a = base + idx;
    float cr = b2f(Cb[(((size_t)n * 128 + ch) << 12) + idx]);
    float ci = b2f(Cb[(((size_t)n * 128 + 64 + ch) << 12) + idx]);
    Xr[a] = g * cr + (1.f - g) * sp.x * scale + rr_[a];
    Xi[a] = g * ci + (1.f - g) * sp.y * scale + ri_[a];
  }
}

// -------- Kernel D: fused temporal (LN -> GEMM1 -> scan -> GEMM2 -> +res) --
__global__ __launch_bounds__(256, 3) void k_temporal_mfma(
    float* __restrict__ Xr, float* __restrict__ Xi,   // W0 in/out
    const float* __restrict__ dt,
    const float* __restrict__ lnw, const float* __restrict__ lnb,
    const float* __restrict__ lam_re, const float* __restrict__ lam_im,
    const unsigned short* __restrict__ Wt1, const unsigned short* __restrict__ Wt2) {
  __shared__ unsigned short Asub[16 * 64 * 8];    // 16 KB
  __shared__ float Xe[64 * 129];                  // 33,024 B (padded)
  int bid = xcd_swizzle(blockIdx.x, 2048);
  int b = bid >> 10, tile = bid & 1023;
  int hw0 = tile * 4;
  int tid = threadIdx.x;
  int lane = tid & 63, wv = tid >> 6;
  int l31 = lane & 31, lhi = lane >> 5;
  size_t xbase = (size_t)b * TT * DCH * HW + hw0;

  float4 res[8];
#pragma unroll
  for (int q = 0; q < 8; ++q) {
    int item = tid + q * 256;          // t*128 + c
    int t = item >> 7, c = item & 127;
    int d = c & 63;
    const float* src = ((c >> 6) ? Xi : Xr) + xbase + ((size_t)t * 64 + d) * HW;
    float4 v = *(const float4*)src;
    res[q] = v;                        // residual stays in registers
    Xe[(t * 4 + 0) * 129 + c] = v.x;
    Xe[(t * 4 + 1) * 129 + c] = v.y;
    Xe[(t * 4 + 2) * 129 + c] = v.z;
    Xe[(t * 4 + 3) * 129 + c] = v.w;
  }
  __syncthreads();

  {
    int row = tid >> 2, seg = tid & 3;
    float s = 0.f, s2 = 0.f;
#pragma unroll
    for (int j = 0; j < 32; ++j) {
      float v = Xe[row * 129 + seg * 32 + j];
      s += v; s2 += v * v;
    }
    s += __shfl_xor(s, 1); s2 += __shfl_xor(s2, 1);
    s += __shfl_xor(s, 2); s2 += __shfl_xor(s2, 2);
    float mu = s * (1.f / 128.f);
    float var = s2 * (1.f / 128.f) - mu * mu;
    float rs = rsqrtf(var + EPS);
    // pack c = k*8 + seg*2, k=0..15: write bank = tid&31 (conflict-free)
#pragma unroll
    for (int k = 0; k < 16; ++k) {
      int c = k * 8 + seg * 2;
      float v0 = (Xe[row * 129 + c] - mu) * rs * lnw[c] + lnb[c];
      float v1 = (Xe[row * 129 + c + 1] - mu) * rs * lnw[c + 1] + lnb[c + 1];
      unsigned pk = (unsigned)f2b(v0) | ((unsigned)f2b(v1) << 16);
      *(unsigned*)(Asub + (k * 64 + row) * 8 + seg * 2) = pk;
    }
  }
  __syncthreads();

  int mt = wv & 1, ntb = (wv >> 1) << 1;
  accv acc0 = accv{}, acc1 = accv{};
#pragma unroll
  for (int ks = 0; ks < 8; ++ks) {
    int kg = ks * 2 + lhi;
    bfrag a = *(const bfrag*)(Asub + (kg * 64 + mt * 32 + l31) * 8);
    bfrag b0 = *(const bfrag*)(Wt1 + (kg * 128 + ntb * 32 + l31) * 8);
    bfrag b1 = *(const bfrag*)(Wt1 + (kg * 128 + (ntb + 1) * 32 + l31) * 8);
    acc0 = __builtin_amdgcn_mfma_f32_32x32x16_bf16(a, b0, acc0, 0, 0, 0);
    acc1 = __builtin_amdgcn_mfma_f32_32x32x16_bf16(a, b1, acc1, 0, 0, 0);
  }
  __syncthreads();

#pragma unroll
  for (int rr = 0; rr < 16; ++rr) {
    int mrow = mt * 32 + (rr & 3) + ((rr >> 2) << 3) + (lhi << 2);
    Xe[mrow * 129 + ntb * 32 + l31] = acc0[rr];
    Xe[mrow * 129 + (ntb + 1) * 32 + l31] = acc1[rr];
  }
  __syncthreads();

  {
    int px = tid & 3, dp = tid >> 2;   // r varies per-lane -> 4-way writes
    float x0 = lam_re[dp];
    float nl = -(x0 > 15.f ? x0 : log1pf(__expf(x0)));
    float li = lam_im[dp];
    float hr = 0.f, hi = 0.f;
    int cR = dp, cI = 64 + dp;
    for (int t = 0; t < TT; ++t) {
      float dtv = dt[b * 16 + t];
      float ea = __expf(nl * dtv);
      float sv, cv; __sincosf(li * dtv, &sv, &cv);
      float evr = ea * cv, evi = ea * sv;
      int r = t * 4 + px;
      float xr_ = Xe[r * 129 + cR], xi_ = Xe[r * 129 + cI];
      float nhr = evr * hr - evi * hi + xr_;
      float nhi = evr * hi + evi * hr + xi_;
      hr = nhr; hi = nhi;
      Asub[((cR >> 3) * 64 + r) * 8 + (cR & 7)] = f2b(hr);
      Asub[((cI >> 3) * 64 + r) * 8 + (cI & 7)] = f2b(hi);
    }
  }
  __syncthreads();

  acc0 = accv{}; acc1 = accv{};
#pragma unroll
  for (int ks = 0; ks < 8; ++ks) {
    int kg = ks * 2 + lhi;
    bfrag a = *(const bfrag*)(Asub + (kg * 64 + mt * 32 + l31) * 8);
    bfrag b0 = *(const bfrag*)(Wt2 + (kg * 128 + ntb * 32 + l31) * 8);
    bfrag b1 = *(const bfrag*)(Wt2 + (kg * 128 + (ntb + 1) * 32 + l31) * 8);
    acc0 = __builtin_amdgcn_mfma_f32_32x32x16_bf16(a, b0, acc0, 0, 0, 0);
    acc1 = __builtin_amdgcn_mfma_f32_32x32x16_bf16(a, b1, acc1, 0, 0, 0);
  }
  __syncthreads();

#pragma unroll
  for (int rr = 0; rr < 16; ++rr) {
    int mrow = mt * 32 + (rr & 3) + ((rr >> 2) << 3) + (lhi << 2);
    Xe[mrow * 129 + ntb * 32 + l31] = acc0[rr];
    Xe[mrow * 129 + (ntb + 1) * 32 + l31] = acc1[rr];
  }
  __syncthreads();

#pragma unroll
  for (int q = 0; q < 8; ++q) {
    int item = tid + q * 256;
    int t = item >> 7, c = item & 127;
    int d = c & 63;
    float* dst = ((c >> 6) ? Xi : Xr) + xbase + ((size_t)t * 64 + d) * HW;
    float4 o;
    o.x = Xe[(t * 4 + 0) * 129 + c] + res[q].x;
    o.y = Xe[(t * 4 + 1) * 129 + c] + res[q].y;
    o.z = Xe[(t * 4 + 2) * 129 + c] + res[q].z;
    o.w = Xe[(t * 4 + 3) * 129 + c] + res[q].w;
    *(float4*)dst = o;
  }
}

// -------- Kernel E2: MFMA MLP with prepped weights (B from global) ---------
__global__ __launch_bounds__(256, 4) void k_mlp_pre(
    const float* __restrict__ Xr, const float* __restrict__ Xi,
    const float* __restrict__ lnw, const float* __restrict__ lnb,
    const unsigned short* __restrict__ Wm1,   // [2h][16kg][128n][8]
    const unsigned short* __restrict__ Wm2,   // [2kh][16kg][128n][8]
    const float* __restrict__ b1, const float* __restrict__ b2,
    float* __restrict__ out) {
  __shared__ __align__(16) unsigned char smem[32768];
  float* Xe = (float*)smem;                               // [128c][64m]
  unsigned short* Asub = (unsigned short*)smem;           // [16kg][64m][8]
  unsigned short* mid  = (unsigned short*)(smem + 16384); // [16kg][64m][8]
  unsigned short* ost  = (unsigned short*)smem;           // [128ng][66]
  int bid = blockIdx.x;
  int bt = bid >> 6, tile = bid & 63;
  int hw0 = tile << 6;
  int tid = threadIdx.x;
  int lane = tid & 63, wv = tid >> 6;
  int l31 = lane & 31, lhi = lane >> 5;
  size_t base = (size_t)bt * DCH * HW + hw0;   // + d*HW + m

#pragma unroll
  for (int q = 0; q < 8; ++q) {
    int item = q * 256 + tid;           // 2048 float4
    int m4 = item & 15, c = item >> 4;
    int d = c & 63;
    const float* src = ((c >> 6) ? Xi : Xr) + base + (size_t)d * HW + m4 * 4;
    *(float4*)(Xe + c * 64 + m4 * 4) = *(const float4*)src;
  }
  __syncthreads();                      // (1) Xe ready

  // LN: values held in registers across the in-place Asub overwrite
  {
    int row = tid >> 2, seg = tid & 3;
    float xv[32];
    float s = 0.f, s2 = 0.f;
#pragma unroll
    for (int j = 0; j < 32; ++j) {
      float v = Xe[(seg * 32 + j) * 64 + row];
      xv[j] = v; s += v; s2 += v * v;
    }
    s += __shfl_xor(s, 1); s2 += __shfl_xor(s2, 1);
    s += __shfl_xor(s, 2); s2 += __shfl_xor(s2, 2);
    float mu = s * (1.f / 128.f);
    float var = s2 * (1.f / 128.f) - mu * mu;
    float rs = rsqrtf(var + EPS);
    __syncthreads();                    // (2) all Xe reads done
#pragma unroll
    for (int j = 0; j < 32; ++j) {
      int c = seg * 32 + j;
      Asub[((c >> 3) * 64 + row) * 8 + (c & 7)] =
          f2b((xv[j] - mu) * rs * lnw[c] + lnb[c]);
    }
  }
  __syncthreads();                      // (3) Asub ready

  int ng = wv * 32 + l31;
  accv c0 = accv{}, c1 = accv{};
#pragma unroll
  for (int h = 0; h < 2; ++h) {
    accv g0 = accv{}, g1 = accv{};
#pragma unroll
    for (int ks = 0; ks < 8; ++ks) {
      int kg = ks * 2 + lhi;
      bfrag bfr = *(const bfrag*)(Wm1 + (((h * 16 + kg) * 128) + ng) * 8);
      bfrag a0 = *(const bfrag*)(Asub + (kg * 64 + l31) * 8);
      bfrag a1 = *(const bfrag*)(Asub + (kg * 64 + 32 + l31) * 8);
      g0 = __builtin_amdgcn_mfma_f32_32x32x16_bf16(a0, bfr, g0, 0, 0, 0);
      g1 = __builtin_amdgcn_mfma_f32_32x32x16_bf16(a1, bfr, g1, 0, 0, 0);
    }
    if (h == 1) __syncthreads();        // (5) G2-kh0 mid reads done
    float b1v = b1[h * 128 + ng];
    int kgl = ng >> 3, jj = ng & 7;
#pragma unroll
    for (int rr = 0; rr < 16; ++rr) {
      int mr = (rr & 3) + ((rr >> 2) << 3) + (lhi << 2);
      mid[(kgl * 64 + mr) * 8 + jj] = f2b(gelu_f(g0[rr] + b1v));
      mid[(kgl * 64 + 32 + mr) * 8 + jj] = f2b(gelu_f(g1[rr] + b1v));
    }
    __syncthreads();                    // (4)/(6) mid ready
#pragma unroll
    for (int ks = 0; ks < 8; ++ks) {
      int kg = ks * 2 + lhi;
      bfrag bfr = *(const bfrag*)(Wm2 + (((h * 16 + kg) * 128) + ng) * 8);
      bfrag a0 = *(const bfrag*)(mid + (kg * 64 + l31) * 8);
      bfrag a1 = *(const bfrag*)(mid + (kg * 64 + 32 + l31) * 8);
      c0 = __builtin_amdgcn_mfma_f32_32x32x16_bf16(a0, bfr, c0, 0, 0, 0);
      c1 = __builtin_amdgcn_mfma_f32_32x32x16_bf16(a1, bfr, c1, 0, 0, 0);
    }
  }
  __syncthreads();                      // (7) all mid reads done

  {
    float b2v = b2[ng];
#pragma unroll
    for (int rr = 0; rr < 16; ++rr) {
      int mr = (rr & 3) + ((rr >> 2) << 3) + (lhi << 2);
      ost[ng * 66 + mr] = f2b(c0[rr] + b2v);
      ost[ng * 66 + 32 + mr] = f2b(c1[rr] + b2v);
    }
  }
  __syncthreads();                      // (8) ostage ready
#pragma unroll
  for (int q = 0; q < 4; ++q) {
    int item = q * 256 + tid;          // 1024: (d, m4)
    int m4 = item & 15, d = item >> 4;
    size_t xa = base + (size_t)d * HW + m4 * 4;
    float4 xr4 = *(const float4*)(Xr + xa);
    float4 xi4 = *(const float4*)(Xi + xa);
    int m = m4 * 4;
    float r0 = b2f(ost[d * 66 + m]),     i0 = b2f(ost[(64 + d) * 66 + m]);
    float r1 = b2f(ost[d * 66 + m + 1]), i1 = b2f(ost[(64 + d) * 66 + m + 1]);
    float r2 = b2f(ost[d * 66 + m + 2]), i2 = b2f(ost[(64 + d) * 66 + m + 2]);
    float r3 = b2f(ost[d * 66 + m + 3]), i3 = b2f(ost[(64 + d) * 66 + m + 3]);
    float4 o1, o2;
    o1.x = r0 + xr4.x; o1.y = i0 + xi4.x; o1.z = r1 + xr4.y; o1.w = i1 + xi4.y;
    o2.x = r2 + xr4.z; o2.y = i2 + xi4.z; o2.z = r3 + xr4.w; o2.w = i3 + xi4.w;
    *(float4*)(out + xa * 2) = o1;
    *(float4*)(out + xa * 2 + 4) = o2;
  }
}

extern "C" void kernel_launch(void* const* d_in, const int* in_sizes, int n_in,
                              void* d_out, int out_size, void* d_ws, size_t ws_size,
                              hipStream_t stream) {
  const float* x_real  = (const float*)d_in[0];
  const float* x_imag  = (const float*)d_in[1];
  const float* dt      = (const float*)d_in[2];
  const float* ln_s_w  = (const float*)d_in[3];
  const float* ln_s_b  = (const float*)d_in[4];
  const float* ln_t_w  = (const float*)d_in[5];
  const float* ln_t_b  = (const float*)d_in[6];
  const float* ln_m_w  = (const float*)d_in[7];
  const float* ln_m_b  = (const float*)d_in[8];
  const float* cw_r    = (const float*)d_in[9];
  const float* cw_i    = (const float*)d_in[10];
  const float* cb_r    = (const float*)d_in[11];
  const float* cb_i    = (const float*)d_in[12];
  const float* spec_wr = (const float*)d_in[13];
  const float* spec_wi = (const float*)d_in[14];
  const float* gate    = (const float*)d_in[15];
  const float* lam_re  = (const float*)d_in[16];
  const float* lam_im  = (const float*)d_in[17];
  const float* V_re    = (const float*)d_in[18];
  const float* V_im    = (const float*)d_in[19];
  const float* Vinv_re = (const float*)d_in[20];
  const float* Vinv_im = (const float*)d_in[21];
  const float* mlp_w1  = (const float*)d_in[22];
  const float* mlp_b1  = (const float*)d_in[23];
  const float* mlp_w2  = (const float*)d_in[24];
  const float* mlp_b2  = (const float*)d_in[25];

  float* out = (float*)d_out;
  unsigned short* Xb = (unsigned short*)d_out;
  unsigned short* Cb = Xb + (size_t)2 * NELEM;
  unsigned short* Wt1 = Xb;
  unsigned short* Wt2 = Xb + 16384;
  float* W0r = (float*)d_ws;
  float* W0i = W0r + NELEM;
  unsigned short* Wt = (unsigned short*)d_ws;
  // Xc (channel-major ln-out for the FFT) overlays W0i: each fft block reads
  // its Xc slab fully into registers before any of its W0i writes, and slabs
  // are block-disjoint with identical index <-> byte-range mapping.
  unsigned short* Xc = (unsigned short*)W0i;
  // MLP bf16 weights live past the 64 MB W0 region (ws_size-guarded; verified
  // large enough in rounds 6-13).
  size_t ws_used = (size_t)2 * NELEM * 4;
  unsigned short* Wm = (unsigned short*)((char*)d_ws + ws_used);
  // Spectral weight pre-gather (2 MB) past Wm, only if workspace permits.
  size_t ps_off = ws_used + 131072;
  bool sprep = ws_size >= ps_off + (size_t)262144 * 8;
  float2* Ps = sprep ? (float2*)((char*)d_ws + ps_off) : (float2*)nullptr;

  k_wprep<<<576, 256, 0, stream>>>(cw_r, cw_i, Wt);
  k_mprep<<<256, 256, 0, stream>>>(mlp_w1, mlp_w2, Wm);
  if (sprep) k_sprep<<<1024, 256, 0, stream>>>(spec_wr, spec_wi, Ps);
  k_ln_spatial<<<2048, 256, 0, stream>>>(x_real, x_imag, ln_s_w, ln_s_b,
                                         Xb, Xc);
  k_conv_mfma<<<1024, 256, 0, stream>>>(Xb, Wt, cb_r, cb_i, Cb);
  k_fft_blend<<<2048, 256, 0, stream>>>(W0r, W0i, Xc, Cb, x_real, x_imag,
                                        spec_wr, spec_wi, Ps, gate);
  k_vprep<<<64, 256, 0, stream>>>(V_re, V_im, Vinv_re, Vinv_im, Wt1, Wt2);
  k_temporal_mfma<<<2048, 256, 0, stream>>>(W0r, W0i, dt, ln_t_w, ln_t_b,
                                            lam_re, lam_im, Wt1, Wt2);
  k_mlp_pre<<<2048, 256, 0, stream>>>(W0r, W0i, ln_m_w, ln_m_b,
                                      Wm, Wm + 32768, mlp_b1, mlp_b2, out);
}